// Round 9
// baseline (729.445 us; speedup 1.0000x reference)
//
#include <hip/hip_runtime.h>
#include <hip/hip_bf16.h>
#include <math.h>

#define B_ 2
#define HEADS_ 16
#define HD_ 64
#define DIM_ 1024
#define TEXT_ 226
#define NC_ 8
#define FRAMES_ 4
#define PATCHES_ 384
#define IMG_ 1536
#define S_MAIN 1762
#define S2_ 1770
#define TD_ 512
#define FF_ 4096
#define ROWS_ (B_*S2_)   // 3540
#define VPAD_ 1792       // padded key dim for transposed V

// ---- workspace offsets (float slots) ----
#define OFF_S1   0L
#define OFF_S2   12288L
#define OFF_MISC 24576L
#define OFF_SIM  25600L
#define OFF_IMAP 222208L
#define OFF_AC   418816L
#define OFF_X    435200L
#define OFF_PROJ 4060160L
#define OFF_XN   7685120L
#define OFF_Q    11310080L
#define OFF_K    14935040L
#define OFF_V    18560000L
#define OFF_AO   22184960L
#define OFF_XNB  25809920L
// overlays (liveness-checked):
//   wqkvT bf16(3072x1024) @ OFF_PROJ   [step2 -> step4]
//   vb    bf16(B,H,64,1792) @ OFF_PROJ [step7b -> step8]
//   qb/kb bf16(B,H,S2,64) @ OFF_X      [step7 -> step8; X overwrites step12]
//   fixup partials fp32 2x(1536x1024) @ OFF_AO [step5 -> step5b; ao written step8b]
//   flash split-S partials: p0 fp32(2,16,1770,64) @ OFF_V  [step8 -> step8b; fw1T overwrites step13]
//                           p1 fp32(2,16,1770,64) @ OFF_XN [step8 -> step8b; proj z1 overwrites step11]
//                           pL fp32(2,2,16,1770)  @ OFF_SIM [step8 -> step8b; sim overwrites step9]
//   woT   bf16(1024x1024) @ OFF_AO+2e6 [step10.5 -> step11]
//   fw1T  bf16(4096x1024) @ OFF_V      [step13+]
//   fw2T  bf16(1024x4096) @ OFF_AO     [step13+]
//   ffh   bf16(3540x4096) @ OFF_Q      [step15+]
//   split-K partials: z0 @ OFF_PROJ, z1 @ OFF_XN (contiguous)

// ---- output offsets (floats) ----
#define O_H    0L
#define O_E    3145728L
#define O_C    3608576L
#define O_SELI 3624960L
#define O_ISUM 3637248L
#define O_CMAP 3649536L
#define O_XMAP 3661824L

// pbuf LDS stride (shorts): 72 -> 144B rows, 16B-aligned (b128 single-op).
// flash kt/vt: stride 64 + pre-swizzled-global XOR chunk (see k_flash).
// bgemm at/bt: [128][32]-short tiles, 64B rows; XOR-16B-chunk swizzle
// (chunk c of row r at c^(r&3)) applied BOTH sides: pre-swizzled global src
// for global_load_lds + XOR on ds_read -> breaks the 8-way read conflict.
// Triple-buffered with counted s_waitcnt vmcnt(4) (never 0 mid-loop).
#define PS_ 72

typedef __bf16 bf16x8_t __attribute__((ext_vector_type(8)));
typedef float  f32x4_t  __attribute__((ext_vector_type(4)));

__device__ __forceinline__ unsigned int pack2bf(float a, float b) {
    unsigned short ua = __builtin_bit_cast(unsigned short, (__bf16)a);
    unsigned short ub = __builtin_bit_cast(unsigned short, (__bf16)b);
    return (unsigned int)ua | ((unsigned int)ub << 16);
}

// async global->LDS 16B copy: per-lane global src, wave-uniform LDS base + lane*16
__device__ __forceinline__ void stage16(const unsigned short* g, unsigned short* l) {
    __builtin_amdgcn_global_load_lds(
        (const __attribute__((address_space(1))) unsigned int*)g,
        (__attribute__((address_space(3))) unsigned int*)l, 16, 0, 0);
}

// XCD-chunked bijective remap of a linear workgroup id (requires nwg % 8 == 0)
__device__ __forceinline__ int xcd_swz(int lin, int nwg) {
    if ((nwg & 7) == 0) { int q = nwg >> 3; lin = (lin & 7) * q + (lin >> 3); }
    return lin;
}

// s1/s2 = silu(temb) @ norm_w + norm_b (k-split x4)
__global__ __launch_bounds__(256) void k_silu_mod(
    const float* __restrict__ temb, const float* __restrict__ w1, const float* __restrict__ b1,
    const float* __restrict__ w2, const float* __restrict__ b2,
    float* __restrict__ s1, float* __restrict__ s2)
{
    int gout = blockIdx.x * 64 + (threadIdx.x & 63);   // < 24576
    int ks = threadIdx.x >> 6;
    int which = gout / 12288;
    int r = gout % 12288;
    int b = r / 6144, n = r % 6144;
    const float* w = which ? w2 : w1;
    const float* bb = which ? b2 : b1;
    const float* t = temb + b * TD_;
    float acc = 0.f;
    for (int k = ks*128; k < ks*128 + 128; ++k) {
        float tv = t[k];
        float sv = tv / (1.f + __expf(-tv));
        acc += sv * w[(long)k * 6144 + n];
    }
    __shared__ float red[256];
    red[threadIdx.x] = acc; __syncthreads();
    if (ks == 0) {
        int lt = threadIdx.x;
        float v = red[lt] + red[lt+64] + red[lt+128] + red[lt+192] + bb[n];
        (which ? s2 : s1)[b * 6144 + n] = v;
    }
}

// transpose + convert: src (K,N) fp32 -> dst (N,K) bf16
__global__ __launch_bounds__(256) void k_tcvt(
    const float* __restrict__ src, unsigned short* __restrict__ dst, int K, int N)
{
    __shared__ float t[32][33];
    int n0 = blockIdx.x * 32, k0 = blockIdx.y * 32;
    int tx = threadIdx.x & 31, ty = threadIdx.x >> 5;
    #pragma unroll
    for (int i = 0; i < 4; ++i)
        t[ty + 8*i][tx] = src[(size_t)(k0 + ty + 8*i) * N + n0 + tx];
    __syncthreads();
    #pragma unroll
    for (int i = 0; i < 4; ++i) {
        float v = t[tx][ty + 8*i];
        dst[(size_t)(n0 + ty + 8*i) * K + k0 + tx] =
            __builtin_bit_cast(unsigned short, (__bf16)v);
    }
}

// batched QKV transpose (z selects wq/wk/wv), 1024x1024 each
__global__ __launch_bounds__(256) void k_tcvt_qkv(
    const float* __restrict__ wq, const float* __restrict__ wk, const float* __restrict__ wv,
    unsigned short* __restrict__ dst)
{
    const float* src = (blockIdx.z == 0) ? wq : (blockIdx.z == 1) ? wk : wv;
    unsigned short* d = dst + (size_t)blockIdx.z * 1024 * 1024;
    __shared__ float t[32][33];
    int n0 = blockIdx.x * 32, k0 = blockIdx.y * 32;
    int tx = threadIdx.x & 31, ty = threadIdx.x >> 5;
    #pragma unroll
    for (int i = 0; i < 4; ++i)
        t[ty + 8*i][tx] = src[(size_t)(k0 + ty + 8*i) * 1024 + n0 + tx];
    __syncthreads();
    #pragma unroll
    for (int i = 0; i < 4; ++i) {
        float v = t[tx][ty + 8*i];
        d[(size_t)(n0 + ty + 8*i) * 1024 + k0 + tx] =
            __builtin_bit_cast(unsigned short, (__bf16)v);
    }
}

// V (B,H,S2,64) fp32 -> vb (B,H,64,VPAD) bf16 transposed
__global__ __launch_bounds__(256) void k_vtrans(
    const float* __restrict__ vh, unsigned short* __restrict__ vb)
{
    int bh = blockIdx.z;
    int d0 = blockIdx.y * 32;
    int s0 = blockIdx.x * 32;
    __shared__ float t[32][33];
    int tx = threadIdx.x & 31, ty = threadIdx.x >> 5;
    const float* src = vh + (size_t)bh * S2_ * 64;
    #pragma unroll
    for (int i = 0; i < 4; ++i) {
        int s = s0 + ty + 8*i; if (s >= S2_) s = S2_ - 1;
        t[ty + 8*i][tx] = src[(size_t)s*64 + d0 + tx];
    }
    __syncthreads();
    unsigned short* dst = vb + (size_t)bh * 64 * VPAD_;
    #pragma unroll
    for (int i = 0; i < 4; ++i) {
        int d = d0 + ty + 8*i;
        dst[(size_t)d * VPAD_ + s0 + tx] =
            __builtin_bit_cast(unsigned short, (__bf16)t[tx][ty + 8*i]);
    }
}

// fused layernorm + adaLN modulation -> optional fp32 out AND bf16 outb
__global__ __launch_bounds__(256) void k_ln_mod(
    const float* pe, long bse, const float* ph, long bsh, const float* pc, long bsc,
    const float* __restrict__ smod, const float* __restrict__ lnw, const float* __restrict__ lnb,
    float* __restrict__ out, unsigned short* __restrict__ outb)
{
    long row = blockIdx.x;
    int b = (int)(row / S2_), s = (int)(row % S2_);
    const float* src; int shiftB, scaleB;
    if (s < TEXT_)       { src = pe + (long)b*bse + (long)s*DIM_;          shiftB = 3072; scaleB = 4096; }
    else if (s < S_MAIN) { src = ph + (long)b*bsh + (long)(s-TEXT_)*DIM_;  shiftB = 0;    scaleB = 1024; }
    else                 { src = pc + (long)b*bsc + (long)(s-S_MAIN)*DIM_; shiftB = 3072; scaleB = 4096; }
    int tid = threadIdx.x;
    int col = tid * 4;
    float4 x = *(const float4*)(src + col);
    float lsum = x.x + x.y + x.z + x.w;
    float lsq  = x.x*x.x + x.y*x.y + x.z*x.z + x.w*x.w;
    __shared__ float r1[256], r2[256];
    r1[tid] = lsum; r2[tid] = lsq; __syncthreads();
    for (int st = 128; st; st >>= 1) {
        if (tid < st) { r1[tid] += r1[tid+st]; r2[tid] += r2[tid+st]; }
        __syncthreads();
    }
    float mu = r1[0] * (1.f / DIM_);
    float var = r2[0] * (1.f / DIM_) - mu * mu;
    float rstd = rsqrtf(var + 1e-5f);
    const float* sb = smod + (long)b * 6144;
    float xs[4] = {x.x, x.y, x.z, x.w};
    float res[4];
    #pragma unroll
    for (int i = 0; i < 4; ++i) {
        int cc = col + i;
        float yy = (xs[i] - mu) * rstd * lnw[cc] + lnb[cc];
        res[i] = yy * (1.f + sb[scaleB + cc]) + sb[shiftB + cc];
    }
    if (out)
        *(float4*)(out + row * DIM_ + col) = make_float4(res[0], res[1], res[2], res[3]);
    uint2 pk;
    pk.x = pack2bf(res[0], res[1]); pk.y = pack2bf(res[2], res[3]);
    *(uint2*)(outb + row * DIM_ + col) = pk;
}

// bf16 MFMA GEMM. Triple-buffered LDS staged via global_load_lds (16B async),
// counted vmcnt (never drains to 0 mid-loop), XOR-16B-chunk LDS swizzle
// (both sides: pre-swizzled global src + XOR on ds_read). Optional split-K
// via gridDim.z. XCD-chunked tile remap for L2 locality.
__global__ __launch_bounds__(256, 3) void k_bgemm(
    const unsigned short* __restrict__ A, const unsigned short* __restrict__ Wt,
    const float* __restrict__ bias, float* __restrict__ out_f,
    unsigned short* __restrict__ out_b, int M, int N, int K, int kz_len, int mode,
    float* __restrict__ q_out, float* __restrict__ k_out, float* __restrict__ v_out)
{
    __shared__ unsigned short at[3][128*32];
    __shared__ unsigned short bt[3][128*32];
    int tid = threadIdx.x;
    int w = tid >> 6, lane = tid & 63;
    int lr = lane & 15, lh = lane >> 4;
    int wm = w >> 1, wn = w & 1;
    int gx = gridDim.x;
    int lin = xcd_swz(blockIdx.y * gx + blockIdx.x, gx * gridDim.y);
    int m0 = (lin / gx) * 128, n0 = (lin % gx) * 128;
    int kbeg = blockIdx.z * kz_len;
    int nIt = kz_len >> 5;

    f32x4_t acc[4][4];
    #pragma unroll
    for (int i = 0; i < 4; ++i)
        #pragma unroll
        for (int j = 0; j < 4; ++j) { acc[i][j][0]=0.f; acc[i][j][1]=0.f; acc[i][j][2]=0.f; acc[i][j][3]=0.f; }

    // staging geometry: issue i (0,1) covers rows i*64 + (tid>>2); the 16B
    // chunk is PRE-SWIZZLED in the global source: chunk = (tid&3) ^ (row&3).
    // ((r4+64)&3 == r4&3, so one swizzle serves both issues.)
    int r4 = tid >> 2, c4 = tid & 3;
    int csw = (c4 ^ (r4 & 3)) << 3;   // shorts offset of source chunk
    int arow0 = m0 + r4;      if (arow0 >= M) arow0 = M - 1;
    int arow1 = m0 + 64 + r4; if (arow1 >= M) arow1 = M - 1;
    const unsigned short* ga0 = A + (size_t)arow0 * K + csw;
    const unsigned short* ga1 = A + (size_t)arow1 * K + csw;
    const unsigned short* gb0 = Wt + (size_t)(n0 + r4) * K + csw;
    const unsigned short* gb1 = Wt + (size_t)(n0 + 64 + r4) * K + csw;
    int lbase = w * 512;   // shorts; wave-uniform; HW adds lane*16B
    int rdsw = (lh ^ (lr & 3)) << 3;   // read-side swizzled chunk offset

    // prologue: stage buffers 0 and 1 (8 loads in flight)
    stage16(ga0 + kbeg, &at[0][lbase]);
    stage16(ga1 + kbeg, &at[0][lbase + 2048]);
    stage16(gb0 + kbeg, &bt[0][lbase]);
    stage16(gb1 + kbeg, &bt[0][lbase + 2048]);
    if (nIt > 1) {
        stage16(ga0 + kbeg + 32, &at[1][lbase]);
        stage16(ga1 + kbeg + 32, &at[1][lbase + 2048]);
        stage16(gb0 + kbeg + 32, &bt[1][lbase]);
        stage16(gb1 + kbeg + 32, &bt[1][lbase + 2048]);
    }
    int cur = 0, nx2 = 2;
    for (int t = 0; t < nIt; ++t) {
        // wait: current buffer's 4 loads complete; next buffer's may remain
        if (t + 1 < nIt) asm volatile("s_waitcnt vmcnt(4)" ::: "memory");
        else             asm volatile("s_waitcnt vmcnt(0)" ::: "memory");
        __builtin_amdgcn_s_barrier();
        __builtin_amdgcn_sched_barrier(0);
        if (t + 2 < nIt) {
            int k2 = kbeg + (t + 2) * 32;
            stage16(ga0 + k2, &at[nx2][lbase]);
            stage16(ga1 + k2, &at[nx2][lbase + 2048]);
            stage16(gb0 + k2, &bt[nx2][lbase]);
            stage16(gb1 + k2, &bt[nx2][lbase + 2048]);
        }
        int4 af[4], bf[4];
        #pragma unroll
        for (int tm = 0; tm < 4; ++tm)
            af[tm] = *(const int4*)&at[cur][(wm*64 + tm*16 + lr)*32 + rdsw];
        #pragma unroll
        for (int tn = 0; tn < 4; ++tn)
            bf[tn] = *(const int4*)&bt[cur][(wn*64 + tn*16 + lr)*32 + rdsw];
        #pragma unroll
        for (int tm = 0; tm < 4; ++tm) {
            bf16x8_t av = __builtin_bit_cast(bf16x8_t, af[tm]);
            #pragma unroll
            for (int tn = 0; tn < 4; ++tn)
                acc[tm][tn] = __builtin_amdgcn_mfma_f32_16x16x32_bf16(
                    av, __builtin_bit_cast(bf16x8_t, bf[tn]), acc[tm][tn], 0, 0, 0);
        }
        cur = (cur == 2) ? 0 : cur + 1;
        nx2 = (nx2 == 2) ? 0 : nx2 + 1;
    }
    float* of = out_f;
    if (mode == 1) of += (size_t)blockIdx.z * M * N;
    #pragma unroll
    for (int tm = 0; tm < 4; ++tm) {
        #pragma unroll
        for (int r = 0; r < 4; ++r) {
            int m = m0 + wm*64 + tm*16 + lh*4 + r;
            if (m >= M) continue;
            int b = m / S2_, s = m % S2_;
            #pragma unroll
            for (int tn = 0; tn < 4; ++tn) {
                int n = n0 + wn*64 + tn*16 + lr;
                float v = acc[tm][tn][r];
                if (mode == 0) {
                    int which = n >> 10, c = n & 1023;
                    int hh = c >> 6, d = c & 63;
                    float* dstp = (which == 0) ? q_out : (which == 1) ? k_out : v_out;
                    dstp[(((size_t)b*HEADS_ + hh)*S2_ + s)*64 + d] = v;
                } else if (mode == 1) {
                    of[(size_t)m * N + n] = v + (bias ? bias[n] : 0.f);
                } else {
                    float x = v + bias[n];
                    float u = 0.7978845608028654f * (x + 0.044715f*x*x*x);
                    float g = x / (1.f + __expf(-2.f*u));
                    out_b[(size_t)m * N + n] = __builtin_bit_cast(unsigned short, (__bf16)g);
                }
            }
        }
    }
}

// fp32 tiled GEMM (argmax fixups). If part != nullptr: write plain partial at
// part + z*M*N (split-K, K range [z*kz, (z+1)*kz)). Else headed/plain store.
__global__ __launch_bounds__(256) void k_gemm(
    const float* __restrict__ A, const float* __restrict__ W,
    float* __restrict__ C, int M, int N, int K, int kz_len, int headed, int row_off,
    float* __restrict__ part)
{
    __shared__ float As[16][68];
    __shared__ float Bs[16][68];
    int tid = threadIdx.x;
    int gx = gridDim.x;
    int lin = xcd_swz(blockIdx.y * gx + blockIdx.x, gx * gridDim.y);
    int bm = (lin / gx) * 64, bn = (lin % gx) * 64;
    int tr = tid >> 4, tc = tid & 15;
    int ar = tid >> 2, akk = (tid & 3) * 4;
    int bkk = tid >> 4, bn4 = (tid & 15) * 4;
    float acc[4][4] = {{0.f}};
    int garow = bm + ar;
    const float* Aptr = A + (size_t)garow * K + akk;
    const float* Wptr = W + (size_t)bkk * N + bn + bn4;
    int kbeg = blockIdx.z * kz_len;
    for (int k0 = kbeg; k0 < kbeg + kz_len; k0 += 16) {
        float4 av = make_float4(0.f, 0.f, 0.f, 0.f);
        if (garow < M) av = *(const float4*)(Aptr + k0);
        As[akk+0][ar] = av.x; As[akk+1][ar] = av.y; As[akk+2][ar] = av.z; As[akk+3][ar] = av.w;
        float4 bv = *(const float4*)(Wptr + (size_t)k0 * N);
        Bs[bkk][bn4+0] = bv.x; Bs[bkk][bn4+1] = bv.y; Bs[bkk][bn4+2] = bv.z; Bs[bkk][bn4+3] = bv.w;
        __syncthreads();
        #pragma unroll
        for (int kk = 0; kk < 16; ++kk) {
            float4 a = *(const float4*)&As[kk][tr*4];
            float4 bq = *(const float4*)&Bs[kk][tc*4];
            float avv[4] = {a.x, a.y, a.z, a.w};
            float bvv[4] = {bq.x, bq.y, bq.z, bq.w};
            #pragma unroll
            for (int i = 0; i < 4; ++i)
                #pragma unroll
                for (int j = 0; j < 4; ++j)
                    acc[i][j] += avv[i] * bvv[j];
        }
        __syncthreads();
    }
    #pragma unroll
    for (int i = 0; i < 4; ++i) {
        int r = bm + tr*4 + i;
        if (r >= M) continue;
        #pragma unroll
        for (int j = 0; j < 4; ++j) {
            int n = bn + tc*4 + j;
            float v = acc[i][j];
            if (part) {
                part[(size_t)blockIdx.z*M*N + (size_t)r*N + n] = v;
            } else if (headed) {
                int rg = r + row_off;
                int b = rg / S2_, s = rg % S2_;
                int hh = n >> 6, d = n & 63;
                C[(((size_t)b*HEADS_ + hh)*S2_ + s)*64 + d] = v;
            } else {
                C[(size_t)(r + row_off) * N + n] = v;
            }
        }
    }
}

// sum 2 fixup partials -> headed fp32 store into qh (batch1 img rows)
__global__ __launch_bounds__(256) void k_fixred(
    const float* __restrict__ pa, float* __restrict__ qh_out)
{
    long i = (long)blockIdx.x*256 + threadIdx.x;   // < 1536*1024
    int r = (int)(i >> 10), n = (int)(i & 1023);
    float v = pa[i] + pa[i + (long)IMG_*DIM_];
    int hh = n >> 6, d = n & 63;
    qh_out[(((size_t)HEADS_ + hh)*S2_ + TEXT_ + r)*64 + d] = v;
}

// per-head layernorm + RoPE: bf16 everywhere; fp32 write-back only for argmax rows
__global__ __launch_bounds__(256) void k_qk_prep(
    float* qh, float* kh, unsigned short* qbb, unsigned short* kbb,
    const float* __restrict__ nqw, const float* __restrict__ nqb,
    const float* __restrict__ nkw, const float* __restrict__ nkb,
    const float* __restrict__ rc, const float* __restrict__ rs)
{
    int which = blockIdx.y;
    int wid = threadIdx.x >> 6;
    int lane = threadIdx.x & 63;
    long row = (long)blockIdx.x * 4 + wid;   // (b*16+h)*S2 + s
    long s = row % S2_;
    bool b1 = row >= (long)HEADS_*S2_;
    float* base = (which ? kh : qh) + row * 64;
    const float* w  = which ? nkw : nqw;
    const float* bb = which ? nkb : nqb;
    float x = base[lane];
    float sum = x;
    for (int off = 1; off < 64; off <<= 1) sum += __shfl_xor(sum, off, 64);
    float mu = sum * (1.f / 64.f);
    float dx = x - mu;
    float v = dx * dx;
    for (int off = 1; off < 64; off <<= 1) v += __shfl_xor(v, off, 64);
    float rstd = rsqrtf(v * (1.f / 64.f) + 1e-6f);
    float y = dx * rstd * w[lane] + bb[lane];
    if (s >= TEXT_ && s < S_MAIN) {
        long p = s - TEXT_;
        float part = __shfl_xor(y, 1, 64);
        float rot = (lane & 1) ? part : -part;
        y = y * rc[p*64 + lane] + rot * rs[p*64 + lane];
    }
    bool needf = b1 && (which ? (s >= S_MAIN) : (s >= TEXT_ && s < S_MAIN));
    if (needf) base[lane] = y;
    (which ? kbb : qbb)[row * 64 + lane] = __builtin_bit_cast(unsigned short, (__bf16)y);
}

// MFMA flash attention with 2-way KV split (split-S). 128-q blocks, 4 waves.
// No-max softmax makes the split exactly associative: each split writes
// unnormalized O and L partials; k_fcomb does (O0+O1)/(L0+L1).
// K/V staged via global_load_lds: linear LDS dest (stride-64 rows, the exact
// wave-uniform+lane*16B layout the DMA writes) + pre-swizzled global source
// (content chunk j^(slot_row&7)); reads XOR the chunk with (row&7) ->
// conflict-free, 16B-aligned, no VGPR round-trip. Full-tile fast path skips
// the tail mask (only ~1 in 14 tiles is partial).
// XCD-chunked remap over the full 960-block grid (4 KV sets per XCD ~1.8MB L2).
__global__ __launch_bounds__(256) void k_flash(
    const unsigned short* __restrict__ qb, const unsigned short* __restrict__ kb,
    const unsigned short* __restrict__ vb,
    float* __restrict__ p0, float* __restrict__ p1, float* __restrict__ pl)
{
    int lin3 = (blockIdx.z * gridDim.y + blockIdx.y) * gridDim.x + blockIdx.x;
    lin3 = xcd_swz(lin3, gridDim.x * gridDim.y * gridDim.z);
    int bx = lin3 % 30;
    int rest = lin3 / 30;
    int h = rest & 15, b = rest >> 4;
    int qt, NQ, q_off, r0s, r0e, r1s, r1e, z;
    if (bx < 28) {
        z = bx & 1; int u = bx >> 1;
        qt = u*128; NQ = S_MAIN; q_off = 0;
        r0s = z ? 896 : 0; r0e = z ? S_MAIN : 896;
        r1s = 0; r1e = 0;
    } else {
        z = bx - 28;
        qt = 0; NQ = NC_; q_off = S_MAIN;
        if (z == 0) { r0s = S_MAIN;      r0e = S2_;    r1s = TEXT_; r1e = TEXT_ + 768; }
        else        { r0s = TEXT_ + 768; r0e = S_MAIN; r1s = 0;     r1e = 0; }
    }
    float* po = z ? p1 : p0;
    int tid = threadIdx.x;
    int w = tid >> 6, lane = tid & 63;
    int lr = lane & 15, lh = lane >> 4;
    int s7 = lr & 7;   // row&7 for all fragment rows 16g+lr
    __shared__ __align__(16) unsigned short kt[64*64];
    __shared__ __align__(16) unsigned short vt[64*64];
    __shared__ __align__(16) unsigned short pbuf[4*32*PS_];
    unsigned short* pw = pbuf + w*32*PS_;
    const unsigned short* qbase = qb + (((size_t)b*HEADS_ + h)*S2_ + q_off)*64;
    const unsigned short* kbase = kb + ((size_t)b*HEADS_ + h)*S2_*64;
    const unsigned short* vbase = vb + (size_t)(b*HEADS_ + h)*64*VPAD_;
    // staging geometry (per issue i=0,1): idx = tid + i*256; slot row idx>>3,
    // chunk idx&7; LDS dest is linear idx*16B (wave-uniform base + lane*16B);
    // global src chunk = (idx&7) ^ (slot_row & 7). srow1&7 == srow0&7.
    int srow0 = tid >> 3, schunk = tid & 7;
    int srow1 = srow0 + 32;
    int sc0 = (schunk ^ (srow0 & 7)) << 3;
    int ldst0 = (w * 64) * 8;                // shorts; wave-uniform
    int ldst1 = (256 + w * 64) * 8;
    bf16x8_t aq[2][2];
    #pragma unroll
    for (int t = 0; t < 2; ++t) {
        int qrow = qt + w*32 + t*16 + lr; if (qrow >= NQ) qrow = NQ - 1;
        const unsigned short* qsrc = qbase + (size_t)qrow*64 + lh*8;
        aq[t][0] = __builtin_bit_cast(bf16x8_t, *(const int4*)qsrc);
        aq[t][1] = __builtin_bit_cast(bf16x8_t, *(const int4*)(qsrc + 32));
    }
    int4 onesi = make_int4(0x3F803F80, 0x3F803F80, 0x3F803F80, 0x3F803F80);
    bf16x8_t bones = __builtin_bit_cast(bf16x8_t, onesi);
    f32x4_t O[2][4];
    f32x4_t Lacc[2];
    #pragma unroll
    for (int t = 0; t < 2; ++t) {
        Lacc[t][0]=0.f; Lacc[t][1]=0.f; Lacc[t][2]=0.f; Lacc[t][3]=0.f;
        #pragma unroll
        for (int g = 0; g < 4; ++g) { O[t][g][0]=0.f; O[t][g][1]=0.f; O[t][g][2]=0.f; O[t][g][3]=0.f; }
    }
    for (int rgi = 0; rgi < 2; ++rgi) {
        int rs = rgi ? r1s : r0s, re = rgi ? r1e : r0e;
        for (int j0 = rs; j0 < re; j0 += 64) {
            int cnt = min(64, re - j0);
            __syncthreads();
            {
                int kr0 = j0 + srow0; if (kr0 > re - 1) kr0 = re - 1;
                int kr1 = j0 + srow1; if (kr1 > re - 1) kr1 = re - 1;
                stage16(kbase + (size_t)kr0*64 + sc0, &kt[ldst0]);
                stage16(kbase + (size_t)kr1*64 + sc0, &kt[ldst1]);
                stage16(vbase + (size_t)srow0*VPAD_ + j0 + sc0, &vt[ldst0]);
                stage16(vbase + (size_t)srow1*VPAD_ + j0 + sc0, &vt[ldst1]);
            }
            __syncthreads();
            f32x4_t S[2][4];
            #pragma unroll
            for (int g = 0; g < 4; ++g) {
                const unsigned short* kr = &kt[(16*g + lr)*64];
                bf16x8_t b0 = __builtin_bit_cast(bf16x8_t, *(const int4*)(kr + ((lh ^ s7) << 3)));
                bf16x8_t b1 = __builtin_bit_cast(bf16x8_t, *(const int4*)(kr + (((lh + 4) ^ s7) << 3)));
                #pragma unroll
                for (int t = 0; t < 2; ++t) {
                    f32x4_t zz; zz[0]=0.f; zz[1]=0.f; zz[2]=0.f; zz[3]=0.f;
                    zz = __builtin_amdgcn_mfma_f32_16x16x32_bf16(aq[t][0], b0, zz, 0, 0, 0);
                    zz = __builtin_amdgcn_mfma_f32_16x16x32_bf16(aq[t][1], b1, zz, 0, 0, 0);
                    S[t][g] = zz;
                }
            }
            if (cnt == 64) {
                #pragma unroll
                for (int t = 0; t < 2; ++t)
                    #pragma unroll
                    for (int g = 0; g < 4; ++g)
                        #pragma unroll
                        for (int r = 0; r < 4; ++r) {
                            float p = __expf(S[t][g][r] * 0.125f);
                            pw[(t*16 + lh*4 + r)*PS_ + 16*g + lr] = __builtin_bit_cast(unsigned short, (__bf16)p);
                        }
            } else {
                #pragma unroll
                for (int t = 0; t < 2; ++t)
                    #pragma unroll
                    for (int g = 0; g < 4; ++g) {
                        bool vld = (16*g + lr) < cnt;
                        #pragma unroll
                        for (int r = 0; r < 4; ++r) {
                            float p = vld ? __expf(S[t][g][r] * 0.125f) : 0.f;
                            pw[(t*16 + lh*4 + r)*PS_ + 16*g + lr] = __builtin_bit_cast(unsigned short, (__bf16)p);
                        }
                    }
            }
            #pragma unroll
            for (int c = 0; c < 2; ++c) {
                bf16x8_t ap[2];
                #pragma unroll
                for (int t = 0; t < 2; ++t) {
                    ap[t] = __builtin_bit_cast(bf16x8_t,
                        *(const int4*)&pw[(t*16 + lr)*PS_ + c*32 + lh*8]);
                    Lacc[t] = __builtin_amdgcn_mfma_f32_16x16x32_bf16(ap[t], bones, Lacc[t], 0, 0, 0);
                }
                #pragma unroll
                for (int g = 0; g < 4; ++g) {
                    const unsigned short* vr = &vt[(16*g + lr)*64];
                    bf16x8_t bv = __builtin_bit_cast(bf16x8_t,
                        *(const int4*)(vr + (((c*4 + lh) ^ s7) << 3)));
                    #pragma unroll
                    for (int t = 0; t < 2; ++t)
                        O[t][g] = __builtin_amdgcn_mfma_f32_16x16x32_bf16(ap[t], bv, O[t][g], 0, 0, 0);
                }
            }
        }
    }
    #pragma unroll
    for (int t = 0; t < 2; ++t)
        #pragma unroll
        for (int r = 0; r < 4; ++r) {
            int gq = qt + w*32 + t*16 + lh*4 + r;
            if (gq < NQ) {
                long rrow = (long)(b*HEADS_ + h)*S2_ + q_off + gq;
                float* o = po + rrow*64 + lr;
                #pragma unroll
                for (int g = 0; g < 4; ++g) o[16*g] = O[t][g][r];
                if (lr == 0) pl[(long)z*(B_*HEADS_*S2_) + rrow] = Lacc[t][r];
            }
        }
}

// combine split-S partials: ao/ac = (p0+p1)/(l0+l1); also emit merged bf16 row
// layout (fuses the old k_merge): xo[(b*S2+s)*1024 + h*64+d]
__global__ __launch_bounds__(256) void k_fcomb(
    const float* __restrict__ p0, const float* __restrict__ p1,
    const float* __restrict__ pl,
    float* __restrict__ ao, float* __restrict__ ac, unsigned short* __restrict__ xo)
{
    long i = (long)blockIdx.x*256 + threadIdx.x;   // < 2*16*1770*64
    int d = (int)(i & 63);
    long rrow = i >> 6;                             // (b*16+h)*S2 + s
    int s = (int)(rrow % S2_);
    int bh = (int)(rrow / S2_);
    int b = bh >> 4, h = bh & 15;
    float l = pl[rrow] + pl[rrow + (long)B_*HEADS_*S2_];
    float v = (p0[i] + p1[i]) / l;
    if (s < S_MAIN) ao[((long)bh*S_MAIN + s)*64 + d] = v;
    else            ac[((long)bh*NC_ + (s - S_MAIN))*64 + d] = v;
    xo[((long)b*S2_ + s)*DIM_ + h*64 + d] = __builtin_bit_cast(unsigned short, (__bf16)v);
}

__global__ __launch_bounds__(256) void k_head_score(const float* __restrict__ ao, float* __restrict__ score)
{
    int h = blockIdx.x, tid = threadIdx.x;
    const float* base = ao + (((long)HEADS_ + h)*S_MAIN + TEXT_)*64;
    float sA = 0.f, sB = 0.f;
    for (int p = tid; p < IMG_; p += 256) {
        const float* r = base + (long)p*64;
        float mm = 0.f;
        for (int d = 0; d < 64; d += 4) {
            float4 v = *(const float4*)(r + d);
            mm += v.x + v.y + v.z + v.w;
        }
        mm *= (1.f / 64.f);
        sA += mm; sB += mm*mm;
    }
    __shared__ float r1[256], r2[256];
    r1[tid] = sA; r2[tid] = sB; __syncthreads();
    for (int st = 128; st; st >>= 1) {
        if (tid < st) { r1[tid] += r1[tid+st]; r2[tid] += r2[tid+st]; }
        __syncthreads();
    }
    if (tid == 0) {
        float mean = r1[0] / IMG_, ms = r2[0] / IMG_;
        score[h] = sqrtf(fmaxf(ms - mean*mean, 0.f));
    }
}

__global__ void k_top4(const float* __restrict__ score, int* __restrict__ sel)
{
    if (threadIdx.x == 0 && blockIdx.x == 0) {
        int used = 0;
        for (int k = 0; k < 4; ++k) {
            float best = -INFINITY; int bi = 0;
            for (int h2 = 0; h2 < 16; ++h2) {
                if (used & (1 << h2)) continue;
                if (score[h2] > best) { best = score[h2]; bi = h2; }
            }
            used |= 1 << bi; sel[k] = bi;
        }
    }
}

__global__ __launch_bounds__(512) void k_sim(
    const float* __restrict__ qh, const float* __restrict__ kh,
    float* __restrict__ sim, int* __restrict__ selvis)
{
    int blk = blockIdx.x;    // (h*8+t)*4+f
    int h = blk >> 5, t = (blk >> 2) & 7, f = blk & 3;
    int tid = threadIdx.x;
    __shared__ float ckv[64];
    if (tid < 64) ckv[tid] = kh[(((long)HEADS_ + h)*S2_ + S_MAIN + t)*64 + tid];
    __syncthreads();
    float val = -INFINITY; int idx = 0x7fffffff;
    if (tid < PATCHES_) {
        const float* qrow = qh + (((long)HEADS_ + h)*S2_ + TEXT_ + f*PATCHES_ + tid)*64;
        float acc = 0.f;
        for (int d = 0; d < 64; d += 4) {
            float4 qv = *(const float4*)(qrow + d);
            acc += qv.x*ckv[d] + qv.y*ckv[d+1] + qv.z*ckv[d+2] + qv.w*ckv[d+3];
        }
        sim[((long)h*NC_ + t)*IMG_ + f*PATCHES_ + tid] = acc;
        val = acc; idx = tid;
    }
    __shared__ float sv[512]; __shared__ int si[512];
    sv[tid] = val; si[tid] = idx; __syncthreads();
    for (int st = 256; st; st >>= 1) {
        if (tid < st) {
            float v2 = sv[tid+st]; int i2 = si[tid+st];
            if (v2 > sv[tid] || (v2 == sv[tid] && i2 < si[tid])) { sv[tid] = v2; si[tid] = i2; }
        }
        __syncthreads();
    }
    if (tid == 0) selvis[blk] = si[0];
}

__global__ __launch_bounds__(256) void k_cross(const float* __restrict__ sim, float* __restrict__ out)
{
    int i = blockIdx.x*256 + threadIdx.x;   // < 12288
    int c = i / IMG_, p = i % IMG_;
    float acc = 0.f;
    for (int h = 0; h < 16; ++h) acc += sim[((long)h*NC_ + c)*IMG_ + p];
    out[O_XMAP + i] = acc * (1.f / 16.f);
}

__global__ __launch_bounds__(256) void k_concept_maps(
    const float* __restrict__ ac, const float* __restrict__ ao, float* __restrict__ out)
{
    int i = blockIdx.x*256 + threadIdx.x;   // < 12288
    int c = i / IMG_, p = i % IMG_;
    float acc = 0.f;
    for (int h = 0; h < 16; ++h) {
        const float* a = ac + (((long)HEADS_ + h)*NC_ + c)*64;
        const float* g = ao + (((long)HEADS_ + h)*S_MAIN + TEXT_ + p)*64;
        for (int d = 0; d < 64; d += 4) {
            float4 av = *(const float4*)(a + d);
            float4 gv = *(const float4*)(g + d);
            acc += av.x*gv.x + av.y*gv.y + av.z*gv.z + av.w*gv.w;
        }
    }
    out[O_CMAP + i] = acc;
}

__global__ void k_imap_raw(const float* __restrict__ ao, const int* __restrict__ selvis,
                           float* __restrict__ imap)
{
    int blk = blockIdx.x;   // (h*8+t)*4+f
    int h = blk >> 5, t = (blk >> 2) & 7, f = blk & 3;
    int tid = threadIdx.x;  // 384
    __shared__ float sel[64];
    int pstar = selvis[blk];
    if (tid < 64) sel[tid] = ao[(((long)HEADS_ + h)*S_MAIN + TEXT_ + f*PATCHES_ + pstar)*64 + tid];
    __syncthreads();
    const float* g = ao + (((long)HEADS_ + h)*S_MAIN + TEXT_ + f*PATCHES_ + tid)*64;
    float acc = 0.f;
    for (int d = 0; d < 64; d += 4) {
        float4 gv = *(const float4*)(g + d);
        acc += gv.x*sel[d] + gv.y*sel[d+1] + gv.z*sel[d+2] + gv.w*sel[d+3];
    }
    imap[((long)h*NC_ + t)*IMG_ + f*PATCHES_ + tid] = acc;
}

__global__ __launch_bounds__(256) void k_imap_norm(float* __restrict__ imap)
{
    int i = blockIdx.x*256 + threadIdx.x;   // < 24576
    int h = i / IMG_, fp = i % IMG_;
    float v[8]; float mu = 0.f;
    #pragma unroll
    for (int t = 0; t < 8; ++t) { v[t] = imap[((long)h*NC_ + t)*IMG_ + fp]; mu += v[t]; }
    mu *= 0.125f;
    float var = 0.f;
    #pragma unroll
    for (int t = 0; t < 8; ++t) var += (v[t]-mu)*(v[t]-mu);
    float sd = sqrtf(var * (1.f / 7.f));
    float inv = 1.f / (sd + 1e-6f);
    #pragma unroll
    for (int t = 0; t < 8; ++t) imap[((long)h*NC_ + t)*IMG_ + fp] = (v[t]-mu)*inv;
}

__global__ __launch_bounds__(256) void k_imap_reduce(
    const float* __restrict__ imap, const int* __restrict__ sel, float* __restrict__ out)
{
    int i = blockIdx.x*256 + threadIdx.x;   // < 12288
    int t = i / IMG_, fp = i % IMG_;
    float sum = 0.f;
    for (int h = 0; h < 16; ++h) sum += imap[((long)h*NC_ + t)*IMG_ + fp];
    float ss = 0.f;
    for (int k = 0; k < 4; ++k) { int h = sel[k]; ss += imap[((long)h*NC_ + t)*IMG_ + fp]; }
    out[O_ISUM + i] = sum;
    out[O_SELI + i] = ss * 0.25f;
}

// residual with fused split-K reduce: X = orig + gate * (p0 + p1 + bo)
__global__ __launch_bounds__(256) void k_residual1(
    const float* __restrict__ pe, const float* __restrict__ ph, const float* __restrict__ pc,
    const float* __restrict__ p0, const float* __restrict__ p1, const float* __restrict__ bo,
    const float* __restrict__ s1, float* __restrict__ X)
{
    long i = (long)blockIdx.x*256 + threadIdx.x;
    int col = (int)(i & 1023);
    long row = i >> 10;
    int b = (int)(row / S2_), s = (int)(row % S2_);
    const float* sb = s1 + (long)b * 6144;
    float orig, gate;
    if (s < TEXT_)       { orig = pe[((long)b*TEXT_ + s)*DIM_ + col];            gate = sb[5120 + col]; }
    else if (s < S_MAIN) { orig = ph[((long)b*IMG_ + (s-TEXT_))*DIM_ + col];     gate = sb[2048 + col]; }
    else                 { orig = pc[((long)b*NC_ + (s-S_MAIN))*DIM_ + col];     gate = sb[5120 + col]; }
    X[i] = orig + gate * (p0[i] + p1[i] + bo[col]);
}

// final with fused split-K reduce: out = X + gate * (f0 + f1 + fb2)
__global__ __launch_bounds__(256) void k_final(
    const float* __restrict__ X, const float* __restrict__ f0, const float* __restrict__ f1,
    const float* __restrict__ fb2, const float* __restrict__ s2, float* __restrict__ out)
{
    long i = (long)blockIdx.x*256 + threadIdx.x;
    int col = (int)(i & 1023);
    long row = i >> 10;
    int b = (int)(row / S2_), s = (int)(row % S2_);
    const float* sb = s2 + (long)b * 6144;
    float gate; float* o;
    if (s < TEXT_)       { gate = sb[5120 + col]; o = out + O_E + ((long)b*TEXT_ + s)*DIM_ + col; }
    else if (s < S_MAIN) { gate = sb[2048 + col]; o = out + O_H + ((long)b*IMG_ + (s-TEXT_))*DIM_ + col; }
    else                 { gate = sb[5120 + col]; o = out + O_C + ((long)b*NC_ + (s-S_MAIN))*DIM_ + col; }
    *o = X[i] + gate * (f0[i] + f1[i] + fb2[col]);
}

extern "C" void kernel_launch(void* const* d_in, const int* in_sizes, int n_in,
                              void* d_out, int out_size, void* d_ws, size_t ws_size,
                              hipStream_t stream)
{
    (void)in_sizes; (void)n_in; (void)out_size; (void)ws_size;
    const float* h_in = (const float*)d_in[0];
    const float* e_in = (const float*)d_in[1];
    const float* c_in = (const float*)d_in[2];
    const float* temb = (const float*)d_in[3];
    const float* rcos = (const float*)d_in[4];
    const float* rsin = (const float*)d_in[5];
    const float* n1w  = (const float*)d_in[6];
    const float* n1b  = (const float*)d_in[7];
    const float* ln1w = (const float*)d_in[8];
    const float* ln1b = (const float*)d_in[9];
    const float* n2w  = (const float*)d_in[10];
    const float* n2b  = (const float*)d_in[11];
    const float* ln2w = (const float*)d_in[12];
    const float* ln2b = (const float*)d_in[13];
    const float* wq   = (const float*)d_in[14];
    const float* wk   = (const float*)d_in[15];
    const float* wv   = (const float*)d_in[16];
    const float* nqw  = (const float*)d_in[17];
    const float* nqb  = (const float*)d_in[18];
    const float* nkw  = (const float*)d_in[19];
    const float* nkb  = (const float*)d_in[20];
    const float* wo   = (const float*)d_in[21];
    const float* bo   = (const float*)d_in[22];
    const float* fw1  = (const float*)d_in[23];
    const float* fb1  = (const float*)d_in[24];
    const float* fw2  = (const float*)d_in[25];
    const float* fb2  = (const float*)d_in[26];

    float* ws  = (float*)d_ws;
    float* out = (float*)d_out;
    float* s1   = ws + OFF_S1;
    float* s2   = ws + OFF_S2;
    float* score  = ws + OFF_MISC;
    int*   selh   = (int*)(ws + OFF_MISC + 16);
    int*   selvis = (int*)(ws + OFF_MISC + 32);
    float* sim  = ws + OFF_SIM;
    float* imap = ws + OFF_IMAP;
    float* ac   = ws + OFF_AC;
    float* X    = ws + OFF_X;
    float* proj = ws + OFF_PROJ;
    float* xn   = ws + OFF_XN;
    float* qh   = ws + OFF_Q;
    float* kh   = ws + OFF_K;
    float* vh   = ws + OFF_V;
    float* ao   = ws + OFF_AO;
    float* ffo  = proj;
    float* fixp = ws + OFF_AO;             // fixup split-K partials (2 x 1536x1024)
    unsigned short* xnb   = (unsigned short*)(ws + OFF_XNB);
    unsigned short* wqkvT = (unsigned short*)(ws + OFF_PROJ);
    unsigned short* vb    = (unsigned short*)(ws + OFF_PROJ);
    unsigned short* qbb   = (unsigned short*)(ws + OFF_X);
    unsigned short* kbb   = qbb + (size_t)B_*HEADS_*S2_*64;
    unsigned short* woT   = (unsigned short*)(ws + OFF_AO + 2000000);
    unsigned short* fw1T  = (unsigned short*)(ws + OFF_V);
    unsigned short* fw2T  = (unsigned short*)(ws + OFF_AO);
    unsigned short* ffh   = (unsigned short*)(ws + OFF_Q);
    // flash split-S partial overlays (dead regions during step 8):
    float* fp0 = vh;    // OFF_V: vh dead after k_vtrans; fw1T arrives step 13
    float* fp1 = xn;    // OFF_XN: xn dead after step 6; proj z1 arrives step 11
    float* fpl = sim;   // OFF_SIM: sim written at step 9 k_sim (after combine)

    // 1. adaLN modulation vectors
    hipLaunchKernelGGL(k_silu_mod, dim3(384), dim3(256), 0, stream, temb, n1w, n1b, n2w, n2b, s1, s2);
    // 2. QKV weight transposes (batched z=3)
    hipLaunchKernelGGL(k_tcvt_qkv, dim3(32, 32, 3), dim3(256), 0, stream, wq, wk, wv, wqkvT);
    // 3. norm1 + modulation -> xn fp32 + xnb bf16
    hipLaunchKernelGGL(k_ln_mod, dim3(ROWS_), dim3(256), 0, stream,
        e_in, (long)TEXT_*DIM_, h_in, (long)IMG_*DIM_, c_in, (long)NC_*DIM_, s1, ln1w, ln1b, xn, xnb);
    // 4. fused QKV bf16 GEMM, headed fp32 scatter
    hipLaunchKernelGGL(k_bgemm, dim3(24, 28, 1), dim3(256), 0, stream,
        xnb, wqkvT, (const float*)nullptr, (float*)nullptr, (unsigned short*)nullptr,
        ROWS_, 3072, 1024, 1024, 0, qh, kh, vh);
    // 5. fp32 q-fixup split-K x2 -> partials, then reduce into headed qh
    hipLaunchKernelGGL(k_gemm, dim3(16, 24, 2), dim3(256), 0, stream,
        xn + (long)(S2_ + TEXT_)*DIM_, wq, (float*)nullptr, IMG_, DIM_, DIM_, 512, 0, 0, fixp);
    hipLaunchKernelGGL(k_fixred, dim3(6144), dim3(256), 0, stream, fixp, qh);
    // 6. fp32 k-fixup (8 concept rows, batch 1) headed
    hipLaunchKernelGGL(k_gemm, dim3(16, 1, 1), dim3(256), 0, stream,
        xn + (long)(S2_ + S_MAIN)*DIM_, wk, kh, NC_, DIM_, DIM_, 1024, 1, S2_ + S_MAIN, (float*)nullptr);
    // 7. QK layernorm + RoPE; V transpose to bf16
    hipLaunchKernelGGL(k_qk_prep, dim3(14160, 2), dim3(256), 0, stream,
        qh, kh, qbb, kbb, nqw, nqb, nkw, nkb, rcos, rsin);
    hipLaunchKernelGGL(k_vtrans, dim3(56, 2, 32), dim3(256), 0, stream, vh, vb);
    // 8. attention: split-S x2, XCD-chunked (bx<28: main u=bx>>1/z=bx&1; bx 28,29: concept z)
    hipLaunchKernelGGL(k_flash, dim3(30, 16, 2), dim3(256), 0, stream,
        qbb, kbb, vb, fp0, fp1, fpl);
    // 8b. combine partials -> ao/ac + merged bf16 (fused old k_merge)
    hipLaunchKernelGGL(k_fcomb, dim3(14160), dim3(256), 0, stream, fp0, fp1, fpl, ao, ac, xnb);
    // 9. maps (batch 1)
    hipLaunchKernelGGL(k_head_score, dim3(16), dim3(256), 0, stream, ao, score);
    hipLaunchKernelGGL(k_top4, dim3(1), dim3(64), 0, stream, score, selh);
    hipLaunchKernelGGL(k_sim, dim3(512), dim3(512), 0, stream, qh, kh, sim, selvis);
    hipLaunchKernelGGL(k_cross, dim3(48), dim3(256), 0, stream, sim, out);
    hipLaunchKernelGGL(k_concept_maps, dim3(48), dim3(256), 0, stream, ac, ao, out);
    hipLaunchKernelGGL(k_imap_raw, dim3(512), dim3(384), 0, stream, ao, selvis, imap);
    hipLaunchKernelGGL(k_imap_norm, dim3(96), dim3(256), 0, stream, imap);
    hipLaunchKernelGGL(k_imap_reduce, dim3(48), dim3(256), 0, stream, imap, selh, out);
    // 10. wo transpose into dead ao region (merge now fused into fcomb)
    hipLaunchKernelGGL(k_tcvt, dim3(32, 32), dim3(256), 0, stream, wo, woT, 1024, 1024);
    // 11. wo GEMM split-K x2 (partials at PROJ / XN)
    hipLaunchKernelGGL(k_bgemm, dim3(8, 28, 2), dim3(256), 0, stream,
        xnb, woT, (const float*)nullptr, proj, (unsigned short*)nullptr, ROWS_, DIM_, 1024, 512, 1,
        (float*)nullptr, (float*)nullptr, (float*)nullptr);
    // 12. residual1 (fused reduce + bias) -> X
    hipLaunchKernelGGL(k_residual1, dim3(14160), dim3(256), 0, stream,
        e_in, h_in, c_in, proj, proj + (size_t)ROWS_*DIM_, bo, s1, X);
    // 13. FF weight transposes
    hipLaunchKernelGGL(k_tcvt, dim3(128, 32), dim3(256), 0, stream, fw1, fw1T, 1024, 4096);
    hipLaunchKernelGGL(k_tcvt, dim3(32, 128), dim3(256), 0, stream, fw2, fw2T, 4096, 1024);
    // 14. norm2 -> xnb bf16 only
    hipLaunchKernelGGL(k_ln_mod, dim3(ROWS_), dim3(256), 0, stream,
        X, (long)S2_*DIM_, X + (long)TEXT_*DIM_, (long)S2_*DIM_, X + (long)S_MAIN*DIM_, (long)S2_*DIM_,
        s2, ln2w, ln2b, (float*)nullptr, xnb);
    // 15. ff1 (gelu fused, bf16 out)
    hipLaunchKernelGGL(k_bgemm, dim3(32, 28, 1), dim3(256), 0, stream,
        xnb, fw1T, fb1, (float*)nullptr, ffh, ROWS_, FF_, 1024, 1024, 2,
        (float*)nullptr, (float*)nullptr, (float*)nullptr);
    // 16. ff2 split-K x2 (partials at PROJ / XN)
    hipLaunchKernelGGL(k_bgemm, dim3(8, 28, 2), dim3(256), 0, stream,
        ffh, fw2T, (const float*)nullptr, ffo, (unsigned short*)nullptr, ROWS_, DIM_, FF_, 2048, 1,
        (float*)nullptr, (float*)nullptr, (float*)nullptr);
    // 17. final (fused reduce + bias) -> outputs
    hipLaunchKernelGGL(k_final, dim3(14160), dim3(256), 0, stream,
        X, ffo, ffo + (size_t)ROWS_*DIM_, fb2, s2, out);
}

// Round 10
// 711.783 us; speedup vs baseline: 1.0248x; 1.0248x over previous
//
#include <hip/hip_runtime.h>
#include <hip/hip_bf16.h>
#include <math.h>

#define B_ 2
#define HEADS_ 16
#define HD_ 64
#define DIM_ 1024
#define TEXT_ 226
#define NC_ 8
#define FRAMES_ 4
#define PATCHES_ 384
#define IMG_ 1536
#define S_MAIN 1762
#define S2_ 1770
#define TD_ 512
#define FF_ 4096
#define ROWS_ (B_*S2_)   // 3540
#define VPAD_ 1792       // padded key dim for transposed V

// ---- workspace offsets (float slots) ----
#define OFF_S1   0L
#define OFF_S2   12288L
#define OFF_MISC 24576L
#define OFF_SIM  25600L
#define OFF_IMAP 222208L
#define OFF_AC   418816L
#define OFF_X    435200L
#define OFF_PROJ 4060160L
#define OFF_XN   7685120L
#define OFF_Q    11310080L
#define OFF_K    14935040L
#define OFF_V    18560000L
#define OFF_AO   22184960L
#define OFF_XNB  25809920L
// overlays (liveness-checked):
//   wqkvT bf16(3072x1024) @ OFF_PROJ   [step2 -> step4]
//   vb    bf16(B,H,64,1792) @ OFF_PROJ [step7b -> step8]
//   qb/kb bf16(B,H,S2,64) @ OFF_X      [step7 -> step8; X overwrites step12]
//   fixup partials fp32 2x(1536x1024) @ OFF_AO [step5 -> step5b; ao written step8b]
//   flash split-S partials: p0 fp32(2,16,1770,64) @ OFF_V  [step8 -> step8b; fw1T overwrites step13]
//                           p1 fp32(2,16,1770,64) @ OFF_XN [step8 -> step8b; proj z1 overwrites step11]
//                           pL fp32(2,2,16,1770)  @ OFF_SIM [step8 -> step8b; sim overwrites step9]
//   woT   bf16(1024x1024) @ OFF_AO+2e6 [step10.5 -> step11]
//   fw1T  bf16(4096x1024) @ OFF_V      [step13+]
//   fw2T  bf16(1024x4096) @ OFF_AO     [step13+]
//   ffh   bf16(3540x4096) @ OFF_Q      [step15+]
//   split-K partials: z0 @ OFF_PROJ, z1 @ OFF_XN (contiguous)

// ---- output offsets (floats) ----
#define O_H    0L
#define O_E    3145728L
#define O_C    3608576L
#define O_SELI 3624960L
#define O_ISUM 3637248L
#define O_CMAP 3649536L
#define O_XMAP 3661824L

// pbuf LDS stride (shorts): 72 -> 144B rows, 16B-aligned (b128 single-op).
// kt/vt: stride 64 (128B rows, linear — global_load_lds writes base+lane*16B)
// with PRE-SWIZZLED GLOBAL SOURCE: LDS slot (row r, chunk j) holds global
// chunk j^(r&7). Reads XOR the chunk index with (row&7): conflict-free
// (2 lanes/bank) and 16B-aligned on both sides.
#define PS_ 72

typedef __bf16 bf16x8_t __attribute__((ext_vector_type(8)));
typedef float  f32x4_t  __attribute__((ext_vector_type(4)));

__device__ __forceinline__ unsigned int pack2bf(float a, float b) {
    unsigned short ua = __builtin_bit_cast(unsigned short, (__bf16)a);
    unsigned short ub = __builtin_bit_cast(unsigned short, (__bf16)b);
    return (unsigned int)ua | ((unsigned int)ub << 16);
}

// async global->LDS 16B copy: per-lane global src, wave-uniform LDS base + lane*16
__device__ __forceinline__ void stage16(const unsigned short* g, unsigned short* l) {
    __builtin_amdgcn_global_load_lds(
        (const __attribute__((address_space(1))) unsigned int*)g,
        (__attribute__((address_space(3))) unsigned int*)l, 16, 0, 0);
}

// XCD-chunked bijective remap of a linear workgroup id (requires nwg % 8 == 0)
__device__ __forceinline__ int xcd_swz(int lin, int nwg) {
    if ((nwg & 7) == 0) { int q = nwg >> 3; lin = (lin & 7) * q + (lin >> 3); }
    return lin;
}

// s1/s2 = silu(temb) @ norm_w + norm_b (k-split x4)
__global__ __launch_bounds__(256) void k_silu_mod(
    const float* __restrict__ temb, const float* __restrict__ w1, const float* __restrict__ b1,
    const float* __restrict__ w2, const float* __restrict__ b2,
    float* __restrict__ s1, float* __restrict__ s2)
{
    int gout = blockIdx.x * 64 + (threadIdx.x & 63);   // < 24576
    int ks = threadIdx.x >> 6;
    int which = gout / 12288;
    int r = gout % 12288;
    int b = r / 6144, n = r % 6144;
    const float* w = which ? w2 : w1;
    const float* bb = which ? b2 : b1;
    const float* t = temb + b * TD_;
    float acc = 0.f;
    for (int k = ks*128; k < ks*128 + 128; ++k) {
        float tv = t[k];
        float sv = tv / (1.f + __expf(-tv));
        acc += sv * w[(long)k * 6144 + n];
    }
    __shared__ float red[256];
    red[threadIdx.x] = acc; __syncthreads();
    if (ks == 0) {
        int lt = threadIdx.x;
        float v = red[lt] + red[lt+64] + red[lt+128] + red[lt+192] + bb[n];
        (which ? s2 : s1)[b * 6144 + n] = v;
    }
}

// transpose + convert: src (K,N) fp32 -> dst (N,K) bf16
__global__ __launch_bounds__(256) void k_tcvt(
    const float* __restrict__ src, unsigned short* __restrict__ dst, int K, int N)
{
    __shared__ float t[32][33];
    int n0 = blockIdx.x * 32, k0 = blockIdx.y * 32;
    int tx = threadIdx.x & 31, ty = threadIdx.x >> 5;
    #pragma unroll
    for (int i = 0; i < 4; ++i)
        t[ty + 8*i][tx] = src[(size_t)(k0 + ty + 8*i) * N + n0 + tx];
    __syncthreads();
    #pragma unroll
    for (int i = 0; i < 4; ++i) {
        float v = t[tx][ty + 8*i];
        dst[(size_t)(n0 + ty + 8*i) * K + k0 + tx] =
            __builtin_bit_cast(unsigned short, (__bf16)v);
    }
}

// batched QKV transpose (z selects wq/wk/wv), 1024x1024 each
__global__ __launch_bounds__(256) void k_tcvt_qkv(
    const float* __restrict__ wq, const float* __restrict__ wk, const float* __restrict__ wv,
    unsigned short* __restrict__ dst)
{
    const float* src = (blockIdx.z == 0) ? wq : (blockIdx.z == 1) ? wk : wv;
    unsigned short* d = dst + (size_t)blockIdx.z * 1024 * 1024;
    __shared__ float t[32][33];
    int n0 = blockIdx.x * 32, k0 = blockIdx.y * 32;
    int tx = threadIdx.x & 31, ty = threadIdx.x >> 5;
    #pragma unroll
    for (int i = 0; i < 4; ++i)
        t[ty + 8*i][tx] = src[(size_t)(k0 + ty + 8*i) * 1024 + n0 + tx];
    __syncthreads();
    #pragma unroll
    for (int i = 0; i < 4; ++i) {
        float v = t[tx][ty + 8*i];
        d[(size_t)(n0 + ty + 8*i) * 1024 + k0 + tx] =
            __builtin_bit_cast(unsigned short, (__bf16)v);
    }
}

// V (B,H,S2,64) fp32 -> vb (B,H,64,VPAD) bf16 transposed
__global__ __launch_bounds__(256) void k_vtrans(
    const float* __restrict__ vh, unsigned short* __restrict__ vb)
{
    int bh = blockIdx.z;
    int d0 = blockIdx.y * 32;
    int s0 = blockIdx.x * 32;
    __shared__ float t[32][33];
    int tx = threadIdx.x & 31, ty = threadIdx.x >> 5;
    const float* src = vh + (size_t)bh * S2_ * 64;
    #pragma unroll
    for (int i = 0; i < 4; ++i) {
        int s = s0 + ty + 8*i; if (s >= S2_) s = S2_ - 1;
        t[ty + 8*i][tx] = src[(size_t)s*64 + d0 + tx];
    }
    __syncthreads();
    unsigned short* dst = vb + (size_t)bh * 64 * VPAD_;
    #pragma unroll
    for (int i = 0; i < 4; ++i) {
        int d = d0 + ty + 8*i;
        dst[(size_t)d * VPAD_ + s0 + tx] =
            __builtin_bit_cast(unsigned short, (__bf16)t[tx][ty + 8*i]);
    }
}

// fused layernorm + adaLN modulation -> optional fp32 out AND bf16 outb
__global__ __launch_bounds__(256) void k_ln_mod(
    const float* pe, long bse, const float* ph, long bsh, const float* pc, long bsc,
    const float* __restrict__ smod, const float* __restrict__ lnw, const float* __restrict__ lnb,
    float* __restrict__ out, unsigned short* __restrict__ outb)
{
    long row = blockIdx.x;
    int b = (int)(row / S2_), s = (int)(row % S2_);
    const float* src; int shiftB, scaleB;
    if (s < TEXT_)       { src = pe + (long)b*bse + (long)s*DIM_;          shiftB = 3072; scaleB = 4096; }
    else if (s < S_MAIN) { src = ph + (long)b*bsh + (long)(s-TEXT_)*DIM_;  shiftB = 0;    scaleB = 1024; }
    else                 { src = pc + (long)b*bsc + (long)(s-S_MAIN)*DIM_; shiftB = 3072; scaleB = 4096; }
    int tid = threadIdx.x;
    int col = tid * 4;
    float4 x = *(const float4*)(src + col);
    float lsum = x.x + x.y + x.z + x.w;
    float lsq  = x.x*x.x + x.y*x.y + x.z*x.z + x.w*x.w;
    __shared__ float r1[256], r2[256];
    r1[tid] = lsum; r2[tid] = lsq; __syncthreads();
    for (int st = 128; st; st >>= 1) {
        if (tid < st) { r1[tid] += r1[tid+st]; r2[tid] += r2[tid+st]; }
        __syncthreads();
    }
    float mu = r1[0] * (1.f / DIM_);
    float var = r2[0] * (1.f / DIM_) - mu * mu;
    float rstd = rsqrtf(var + 1e-5f);
    const float* sb = smod + (long)b * 6144;
    float xs[4] = {x.x, x.y, x.z, x.w};
    float res[4];
    #pragma unroll
    for (int i = 0; i < 4; ++i) {
        int cc = col + i;
        float yy = (xs[i] - mu) * rstd * lnw[cc] + lnb[cc];
        res[i] = yy * (1.f + sb[scaleB + cc]) + sb[shiftB + cc];
    }
    if (out)
        *(float4*)(out + row * DIM_ + col) = make_float4(res[0], res[1], res[2], res[3]);
    uint2 pk;
    pk.x = pack2bf(res[0], res[1]); pk.y = pack2bf(res[2], res[3]);
    *(uint2*)(outb + row * DIM_ + col) = pk;
}

// bf16 MFMA GEMM, double-buffered LDS staged via global_load_lds (16B, async),
// optional split-K via gridDim.z. Linear LDS [128][32] per tile (no pad).
// XCD-chunked tile remap for L2 locality.
__global__ __launch_bounds__(256, 4) void k_bgemm(
    const unsigned short* __restrict__ A, const unsigned short* __restrict__ Wt,
    const float* __restrict__ bias, float* __restrict__ out_f,
    unsigned short* __restrict__ out_b, int M, int N, int K, int kz_len, int mode,
    float* __restrict__ q_out, float* __restrict__ k_out, float* __restrict__ v_out)
{
    __shared__ unsigned short at[2][128*32];
    __shared__ unsigned short bt[2][128*32];
    int tid = threadIdx.x;
    int w = tid >> 6, lane = tid & 63;
    int lr = lane & 15, lh = lane >> 4;
    int wm = w >> 1, wn = w & 1;
    int gx = gridDim.x;
    int lin = xcd_swz(blockIdx.y * gx + blockIdx.x, gx * gridDim.y);
    int m0 = (lin / gx) * 128, n0 = (lin % gx) * 128;
    int kbeg = blockIdx.z * kz_len, kend = kbeg + kz_len;

    f32x4_t acc[4][4];
    #pragma unroll
    for (int i = 0; i < 4; ++i)
        #pragma unroll
        for (int j = 0; j < 4; ++j) { acc[i][j][0]=0.f; acc[i][j][1]=0.f; acc[i][j][2]=0.f; acc[i][j][3]=0.f; }

    // staging geometry: issue i (0,1) covers rows i*64 + (tid>>2), 16B chunk (tid&3)
    int r4 = tid >> 2, c4 = tid & 3;
    int arow0 = m0 + r4;      if (arow0 >= M) arow0 = M - 1;
    int arow1 = m0 + 64 + r4; if (arow1 >= M) arow1 = M - 1;
    const unsigned short* ga0 = A + (size_t)arow0 * K + c4 * 8;
    const unsigned short* ga1 = A + (size_t)arow1 * K + c4 * 8;
    const unsigned short* gb0 = Wt + (size_t)(n0 + r4) * K + c4 * 8;
    const unsigned short* gb1 = Wt + (size_t)(n0 + 64 + r4) * K + c4 * 8;
    int lbase = w * 512;   // shorts; wave-uniform; HW adds lane*16B

    // prologue: stage buf 0
    stage16(ga0 + kbeg, &at[0][lbase]);
    stage16(ga1 + kbeg, &at[0][lbase + 2048]);
    stage16(gb0 + kbeg, &bt[0][lbase]);
    stage16(gb1 + kbeg, &bt[0][lbase + 2048]);
    __syncthreads();
    int buf = 0;
    for (int k0 = kbeg; k0 < kend; k0 += 32) {
        bool more = (k0 + 32) < kend;
        if (more) {
            int nb = buf ^ 1;
            stage16(ga0 + k0 + 32, &at[nb][lbase]);
            stage16(ga1 + k0 + 32, &at[nb][lbase + 2048]);
            stage16(gb0 + k0 + 32, &bt[nb][lbase]);
            stage16(gb1 + k0 + 32, &bt[nb][lbase + 2048]);
        }
        int4 af[4], bf[4];
        #pragma unroll
        for (int tm = 0; tm < 4; ++tm)
            af[tm] = *(const int4*)&at[buf][(wm*64 + tm*16 + lr)*32 + lh*8];
        #pragma unroll
        for (int tn = 0; tn < 4; ++tn)
            bf[tn] = *(const int4*)&bt[buf][(wn*64 + tn*16 + lr)*32 + lh*8];
        #pragma unroll
        for (int tm = 0; tm < 4; ++tm) {
            bf16x8_t av = __builtin_bit_cast(bf16x8_t, af[tm]);
            #pragma unroll
            for (int tn = 0; tn < 4; ++tn)
                acc[tm][tn] = __builtin_amdgcn_mfma_f32_16x16x32_bf16(
                    av, __builtin_bit_cast(bf16x8_t, bf[tn]), acc[tm][tn], 0, 0, 0);
        }
        __syncthreads();
        buf ^= 1;
    }
    float* of = out_f;
    if (mode == 1) of += (size_t)blockIdx.z * M * N;
    #pragma unroll
    for (int tm = 0; tm < 4; ++tm) {
        #pragma unroll
        for (int r = 0; r < 4; ++r) {
            int m = m0 + wm*64 + tm*16 + lh*4 + r;
            if (m >= M) continue;
            int b = m / S2_, s = m % S2_;
            #pragma unroll
            for (int tn = 0; tn < 4; ++tn) {
                int n = n0 + wn*64 + tn*16 + lr;
                float v = acc[tm][tn][r];
                if (mode == 0) {
                    int which = n >> 10, c = n & 1023;
                    int hh = c >> 6, d = c & 63;
                    float* dstp = (which == 0) ? q_out : (which == 1) ? k_out : v_out;
                    dstp[(((size_t)b*HEADS_ + hh)*S2_ + s)*64 + d] = v;
                } else if (mode == 1) {
                    of[(size_t)m * N + n] = v + (bias ? bias[n] : 0.f);
                } else {
                    float x = v + bias[n];
                    float u = 0.7978845608028654f * (x + 0.044715f*x*x*x);
                    float g = x / (1.f + __expf(-2.f*u));
                    out_b[(size_t)m * N + n] = __builtin_bit_cast(unsigned short, (__bf16)g);
                }
            }
        }
    }
}

// fp32 tiled GEMM (argmax fixups). If part != nullptr: write plain partial at
// part + z*M*N (split-K, K range [z*kz, (z+1)*kz)). Else headed/plain store.
__global__ __launch_bounds__(256) void k_gemm(
    const float* __restrict__ A, const float* __restrict__ W,
    float* __restrict__ C, int M, int N, int K, int kz_len, int headed, int row_off,
    float* __restrict__ part)
{
    __shared__ float As[16][68];
    __shared__ float Bs[16][68];
    int tid = threadIdx.x;
    int gx = gridDim.x;
    int lin = xcd_swz(blockIdx.y * gx + blockIdx.x, gx * gridDim.y);
    int bm = (lin / gx) * 64, bn = (lin % gx) * 64;
    int tr = tid >> 4, tc = tid & 15;
    int ar = tid >> 2, akk = (tid & 3) * 4;
    int bkk = tid >> 4, bn4 = (tid & 15) * 4;
    float acc[4][4] = {{0.f}};
    int garow = bm + ar;
    const float* Aptr = A + (size_t)garow * K + akk;
    const float* Wptr = W + (size_t)bkk * N + bn + bn4;
    int kbeg = blockIdx.z * kz_len;
    for (int k0 = kbeg; k0 < kbeg + kz_len; k0 += 16) {
        float4 av = make_float4(0.f, 0.f, 0.f, 0.f);
        if (garow < M) av = *(const float4*)(Aptr + k0);
        As[akk+0][ar] = av.x; As[akk+1][ar] = av.y; As[akk+2][ar] = av.z; As[akk+3][ar] = av.w;
        float4 bv = *(const float4*)(Wptr + (size_t)k0 * N);
        Bs[bkk][bn4+0] = bv.x; Bs[bkk][bn4+1] = bv.y; Bs[bkk][bn4+2] = bv.z; Bs[bkk][bn4+3] = bv.w;
        __syncthreads();
        #pragma unroll
        for (int kk = 0; kk < 16; ++kk) {
            float4 a = *(const float4*)&As[kk][tr*4];
            float4 bq = *(const float4*)&Bs[kk][tc*4];
            float avv[4] = {a.x, a.y, a.z, a.w};
            float bvv[4] = {bq.x, bq.y, bq.z, bq.w};
            #pragma unroll
            for (int i = 0; i < 4; ++i)
                #pragma unroll
                for (int j = 0; j < 4; ++j)
                    acc[i][j] += avv[i] * bvv[j];
        }
        __syncthreads();
    }
    #pragma unroll
    for (int i = 0; i < 4; ++i) {
        int r = bm + tr*4 + i;
        if (r >= M) continue;
        #pragma unroll
        for (int j = 0; j < 4; ++j) {
            int n = bn + tc*4 + j;
            float v = acc[i][j];
            if (part) {
                part[(size_t)blockIdx.z*M*N + (size_t)r*N + n] = v;
            } else if (headed) {
                int rg = r + row_off;
                int b = rg / S2_, s = rg % S2_;
                int hh = n >> 6, d = n & 63;
                C[(((size_t)b*HEADS_ + hh)*S2_ + s)*64 + d] = v;
            } else {
                C[(size_t)(r + row_off) * N + n] = v;
            }
        }
    }
}

// sum 2 fixup partials -> headed fp32 store into qh (batch1 img rows)
__global__ __launch_bounds__(256) void k_fixred(
    const float* __restrict__ pa, float* __restrict__ qh_out)
{
    long i = (long)blockIdx.x*256 + threadIdx.x;   // < 1536*1024
    int r = (int)(i >> 10), n = (int)(i & 1023);
    float v = pa[i] + pa[i + (long)IMG_*DIM_];
    int hh = n >> 6, d = n & 63;
    qh_out[(((size_t)HEADS_ + hh)*S2_ + TEXT_ + r)*64 + d] = v;
}

// per-head layernorm + RoPE: bf16 everywhere; fp32 write-back only for argmax rows
__global__ __launch_bounds__(256) void k_qk_prep(
    float* qh, float* kh, unsigned short* qbb, unsigned short* kbb,
    const float* __restrict__ nqw, const float* __restrict__ nqb,
    const float* __restrict__ nkw, const float* __restrict__ nkb,
    const float* __restrict__ rc, const float* __restrict__ rs)
{
    int which = blockIdx.y;
    int wid = threadIdx.x >> 6;
    int lane = threadIdx.x & 63;
    long row = (long)blockIdx.x * 4 + wid;   // (b*16+h)*S2 + s
    long s = row % S2_;
    bool b1 = row >= (long)HEADS_*S2_;
    float* base = (which ? kh : qh) + row * 64;
    const float* w  = which ? nkw : nqw;
    const float* bb = which ? nkb : nqb;
    float x = base[lane];
    float sum = x;
    for (int off = 1; off < 64; off <<= 1) sum += __shfl_xor(sum, off, 64);
    float mu = sum * (1.f / 64.f);
    float dx = x - mu;
    float v = dx * dx;
    for (int off = 1; off < 64; off <<= 1) v += __shfl_xor(v, off, 64);
    float rstd = rsqrtf(v * (1.f / 64.f) + 1e-6f);
    float y = dx * rstd * w[lane] + bb[lane];
    if (s >= TEXT_ && s < S_MAIN) {
        long p = s - TEXT_;
        float part = __shfl_xor(y, 1, 64);
        float rot = (lane & 1) ? part : -part;
        y = y * rc[p*64 + lane] + rot * rs[p*64 + lane];
    }
    bool needf = b1 && (which ? (s >= S_MAIN) : (s >= TEXT_ && s < S_MAIN));
    if (needf) base[lane] = y;
    (which ? kbb : qbb)[row * 64 + lane] = __builtin_bit_cast(unsigned short, (__bf16)y);
}

// MFMA flash attention with 2-way KV split (split-S). 128-q blocks, 4 waves.
// No-max softmax makes the split exactly associative: each split writes
// unnormalized O and L partials; k_fcomb does (O0+O1)/(L0+L1).
// K/V staged via global_load_lds: linear LDS dest (stride-64 rows, the exact
// wave-uniform+lane*16B layout the DMA writes) + pre-swizzled global source
// (content chunk j^(slot_row&7)); reads XOR the chunk with (row&7) ->
// conflict-free, 16B-aligned, no VGPR round-trip. Full-tile fast path skips
// the tail mask (only ~1 in 14 tiles is partial).
// XCD-chunked remap over the full 960-block grid (4 KV sets per XCD ~1.8MB L2).
__global__ __launch_bounds__(256) void k_flash(
    const unsigned short* __restrict__ qb, const unsigned short* __restrict__ kb,
    const unsigned short* __restrict__ vb,
    float* __restrict__ p0, float* __restrict__ p1, float* __restrict__ pl)
{
    int lin3 = (blockIdx.z * gridDim.y + blockIdx.y) * gridDim.x + blockIdx.x;
    lin3 = xcd_swz(lin3, gridDim.x * gridDim.y * gridDim.z);
    int bx = lin3 % 30;
    int rest = lin3 / 30;
    int h = rest & 15, b = rest >> 4;
    int qt, NQ, q_off, r0s, r0e, r1s, r1e, z;
    if (bx < 28) {
        z = bx & 1; int u = bx >> 1;
        qt = u*128; NQ = S_MAIN; q_off = 0;
        r0s = z ? 896 : 0; r0e = z ? S_MAIN : 896;
        r1s = 0; r1e = 0;
    } else {
        z = bx - 28;
        qt = 0; NQ = NC_; q_off = S_MAIN;
        if (z == 0) { r0s = S_MAIN;      r0e = S2_;    r1s = TEXT_; r1e = TEXT_ + 768; }
        else        { r0s = TEXT_ + 768; r0e = S_MAIN; r1s = 0;     r1e = 0; }
    }
    float* po = z ? p1 : p0;
    int tid = threadIdx.x;
    int w = tid >> 6, lane = tid & 63;
    int lr = lane & 15, lh = lane >> 4;
    int s7 = lr & 7;   // row&7 for all fragment rows 16g+lr
    __shared__ __align__(16) unsigned short kt[64*64];
    __shared__ __align__(16) unsigned short vt[64*64];
    __shared__ __align__(16) unsigned short pbuf[4*32*PS_];
    unsigned short* pw = pbuf + w*32*PS_;
    const unsigned short* qbase = qb + (((size_t)b*HEADS_ + h)*S2_ + q_off)*64;
    const unsigned short* kbase = kb + ((size_t)b*HEADS_ + h)*S2_*64;
    const unsigned short* vbase = vb + (size_t)(b*HEADS_ + h)*64*VPAD_;
    // staging geometry (per issue i=0,1): idx = tid + i*256; slot row idx>>3,
    // chunk idx&7; LDS dest is linear idx*16B (wave-uniform base + lane*16B);
    // global src chunk = (idx&7) ^ (slot_row & 7). srow1&7 == srow0&7.
    int srow0 = tid >> 3, schunk = tid & 7;
    int srow1 = srow0 + 32;
    int sc0 = (schunk ^ (srow0 & 7)) << 3;
    int ldst0 = (w * 64) * 8;                // shorts; wave-uniform
    int ldst1 = (256 + w * 64) * 8;
    bf16x8_t aq[2][2];
    #pragma unroll
    for (int t = 0; t < 2; ++t) {
        int qrow = qt + w*32 + t*16 + lr; if (qrow >= NQ) qrow = NQ - 1;
        const unsigned short* qsrc = qbase + (size_t)qrow*64 + lh*8;
        aq[t][0] = __builtin_bit_cast(bf16x8_t, *(const int4*)qsrc);
        aq[t][1] = __builtin_bit_cast(bf16x8_t, *(const int4*)(qsrc + 32));
    }
    int4 onesi = make_int4(0x3F803F80, 0x3F803F80, 0x3F803F80, 0x3F803F80);
    bf16x8_t bones = __builtin_bit_cast(bf16x8_t, onesi);
    f32x4_t O[2][4];
    f32x4_t Lacc[2];
    #pragma unroll
    for (int t = 0; t < 2; ++t) {
        Lacc[t][0]=0.f; Lacc[t][1]=0.f; Lacc[t][2]=0.f; Lacc[t][3]=0.f;
        #pragma unroll
        for (int g = 0; g < 4; ++g) { O[t][g][0]=0.f; O[t][g][1]=0.f; O[t][g][2]=0.f; O[t][g][3]=0.f; }
    }
    for (int rgi = 0; rgi < 2; ++rgi) {
        int rs = rgi ? r1s : r0s, re = rgi ? r1e : r0e;
        for (int j0 = rs; j0 < re; j0 += 64) {
            int cnt = min(64, re - j0);
            __syncthreads();
            {
                int kr0 = j0 + srow0; if (kr0 > re - 1) kr0 = re - 1;
                int kr1 = j0 + srow1; if (kr1 > re - 1) kr1 = re - 1;
                stage16(kbase + (size_t)kr0*64 + sc0, &kt[ldst0]);
                stage16(kbase + (size_t)kr1*64 + sc0, &kt[ldst1]);
                stage16(vbase + (size_t)srow0*VPAD_ + j0 + sc0, &vt[ldst0]);
                stage16(vbase + (size_t)srow1*VPAD_ + j0 + sc0, &vt[ldst1]);
            }
            __syncthreads();
            f32x4_t S[2][4];
            #pragma unroll
            for (int g = 0; g < 4; ++g) {
                const unsigned short* kr = &kt[(16*g + lr)*64];
                bf16x8_t b0 = __builtin_bit_cast(bf16x8_t, *(const int4*)(kr + ((lh ^ s7) << 3)));
                bf16x8_t b1 = __builtin_bit_cast(bf16x8_t, *(const int4*)(kr + (((lh + 4) ^ s7) << 3)));
                #pragma unroll
                for (int t = 0; t < 2; ++t) {
                    f32x4_t zz; zz[0]=0.f; zz[1]=0.f; zz[2]=0.f; zz[3]=0.f;
                    zz = __builtin_amdgcn_mfma_f32_16x16x32_bf16(aq[t][0], b0, zz, 0, 0, 0);
                    zz = __builtin_amdgcn_mfma_f32_16x16x32_bf16(aq[t][1], b1, zz, 0, 0, 0);
                    S[t][g] = zz;
                }
            }
            if (cnt == 64) {
                #pragma unroll
                for (int t = 0; t < 2; ++t)
                    #pragma unroll
                    for (int g = 0; g < 4; ++g)
                        #pragma unroll
                        for (int r = 0; r < 4; ++r) {
                            float p = __expf(S[t][g][r] * 0.125f);
                            pw[(t*16 + lh*4 + r)*PS_ + 16*g + lr] = __builtin_bit_cast(unsigned short, (__bf16)p);
                        }
            } else {
                #pragma unroll
                for (int t = 0; t < 2; ++t)
                    #pragma unroll
                    for (int g = 0; g < 4; ++g) {
                        bool vld = (16*g + lr) < cnt;
                        #pragma unroll
                        for (int r = 0; r < 4; ++r) {
                            float p = vld ? __expf(S[t][g][r] * 0.125f) : 0.f;
                            pw[(t*16 + lh*4 + r)*PS_ + 16*g + lr] = __builtin_bit_cast(unsigned short, (__bf16)p);
                        }
                    }
            }
            #pragma unroll
            for (int c = 0; c < 2; ++c) {
                bf16x8_t ap[2];
                #pragma unroll
                for (int t = 0; t < 2; ++t) {
                    ap[t] = __builtin_bit_cast(bf16x8_t,
                        *(const int4*)&pw[(t*16 + lr)*PS_ + c*32 + lh*8]);
                    Lacc[t] = __builtin_amdgcn_mfma_f32_16x16x32_bf16(ap[t], bones, Lacc[t], 0, 0, 0);
                }
                #pragma unroll
                for (int g = 0; g < 4; ++g) {
                    const unsigned short* vr = &vt[(16*g + lr)*64];
                    bf16x8_t bv = __builtin_bit_cast(bf16x8_t,
                        *(const int4*)(vr + (((c*4 + lh) ^ s7) << 3)));
                    #pragma unroll
                    for (int t = 0; t < 2; ++t)
                        O[t][g] = __builtin_amdgcn_mfma_f32_16x16x32_bf16(ap[t], bv, O[t][g], 0, 0, 0);
                }
            }
        }
    }
    #pragma unroll
    for (int t = 0; t < 2; ++t)
        #pragma unroll
        for (int r = 0; r < 4; ++r) {
            int gq = qt + w*32 + t*16 + lh*4 + r;
            if (gq < NQ) {
                long rrow = (long)(b*HEADS_ + h)*S2_ + q_off + gq;
                float* o = po + rrow*64 + lr;
                #pragma unroll
                for (int g = 0; g < 4; ++g) o[16*g] = O[t][g][r];
                if (lr == 0) pl[(long)z*(B_*HEADS_*S2_) + rrow] = Lacc[t][r];
            }
        }
}

// combine split-S partials: ao/ac = (p0+p1)/(l0+l1); also emit merged bf16 row
// layout (fuses the old k_merge): xo[(b*S2+s)*1024 + h*64+d]
__global__ __launch_bounds__(256) void k_fcomb(
    const float* __restrict__ p0, const float* __restrict__ p1,
    const float* __restrict__ pl,
    float* __restrict__ ao, float* __restrict__ ac, unsigned short* __restrict__ xo)
{
    long i = (long)blockIdx.x*256 + threadIdx.x;   // < 2*16*1770*64
    int d = (int)(i & 63);
    long rrow = i >> 6;                             // (b*16+h)*S2 + s
    int s = (int)(rrow % S2_);
    int bh = (int)(rrow / S2_);
    int b = bh >> 4, h = bh & 15;
    float l = pl[rrow] + pl[rrow + (long)B_*HEADS_*S2_];
    float v = (p0[i] + p1[i]) / l;
    if (s < S_MAIN) ao[((long)bh*S_MAIN + s)*64 + d] = v;
    else            ac[((long)bh*NC_ + (s - S_MAIN))*64 + d] = v;
    xo[((long)b*S2_ + s)*DIM_ + h*64 + d] = __builtin_bit_cast(unsigned short, (__bf16)v);
}

__global__ __launch_bounds__(256) void k_head_score(const float* __restrict__ ao, float* __restrict__ score)
{
    int h = blockIdx.x, tid = threadIdx.x;
    const float* base = ao + (((long)HEADS_ + h)*S_MAIN + TEXT_)*64;
    float sA = 0.f, sB = 0.f;
    for (int p = tid; p < IMG_; p += 256) {
        const float* r = base + (long)p*64;
        float mm = 0.f;
        for (int d = 0; d < 64; d += 4) {
            float4 v = *(const float4*)(r + d);
            mm += v.x + v.y + v.z + v.w;
        }
        mm *= (1.f / 64.f);
        sA += mm; sB += mm*mm;
    }
    __shared__ float r1[256], r2[256];
    r1[tid] = sA; r2[tid] = sB; __syncthreads();
    for (int st = 128; st; st >>= 1) {
        if (tid < st) { r1[tid] += r1[tid+st]; r2[tid] += r2[tid+st]; }
        __syncthreads();
    }
    if (tid == 0) {
        float mean = r1[0] / IMG_, ms = r2[0] / IMG_;
        score[h] = sqrtf(fmaxf(ms - mean*mean, 0.f));
    }
}

__global__ void k_top4(const float* __restrict__ score, int* __restrict__ sel)
{
    if (threadIdx.x == 0 && blockIdx.x == 0) {
        int used = 0;
        for (int k = 0; k < 4; ++k) {
            float best = -INFINITY; int bi = 0;
            for (int h2 = 0; h2 < 16; ++h2) {
                if (used & (1 << h2)) continue;
                if (score[h2] > best) { best = score[h2]; bi = h2; }
            }
            used |= 1 << bi; sel[k] = bi;
        }
    }
}

__global__ __launch_bounds__(512) void k_sim(
    const float* __restrict__ qh, const float* __restrict__ kh,
    float* __restrict__ sim, int* __restrict__ selvis)
{
    int blk = blockIdx.x;    // (h*8+t)*4+f
    int h = blk >> 5, t = (blk >> 2) & 7, f = blk & 3;
    int tid = threadIdx.x;
    __shared__ float ckv[64];
    if (tid < 64) ckv[tid] = kh[(((long)HEADS_ + h)*S2_ + S_MAIN + t)*64 + tid];
    __syncthreads();
    float val = -INFINITY; int idx = 0x7fffffff;
    if (tid < PATCHES_) {
        const float* qrow = qh + (((long)HEADS_ + h)*S2_ + TEXT_ + f*PATCHES_ + tid)*64;
        float acc = 0.f;
        for (int d = 0; d < 64; d += 4) {
            float4 qv = *(const float4*)(qrow + d);
            acc += qv.x*ckv[d] + qv.y*ckv[d+1] + qv.z*ckv[d+2] + qv.w*ckv[d+3];
        }
        sim[((long)h*NC_ + t)*IMG_ + f*PATCHES_ + tid] = acc;
        val = acc; idx = tid;
    }
    __shared__ float sv[512]; __shared__ int si[512];
    sv[tid] = val; si[tid] = idx; __syncthreads();
    for (int st = 256; st; st >>= 1) {
        if (tid < st) {
            float v2 = sv[tid+st]; int i2 = si[tid+st];
            if (v2 > sv[tid] || (v2 == sv[tid] && i2 < si[tid])) { sv[tid] = v2; si[tid] = i2; }
        }
        __syncthreads();
    }
    if (tid == 0) selvis[blk] = si[0];
}

__global__ __launch_bounds__(256) void k_cross(const float* __restrict__ sim, float* __restrict__ out)
{
    int i = blockIdx.x*256 + threadIdx.x;   // < 12288
    int c = i / IMG_, p = i % IMG_;
    float acc = 0.f;
    for (int h = 0; h < 16; ++h) acc += sim[((long)h*NC_ + c)*IMG_ + p];
    out[O_XMAP + i] = acc * (1.f / 16.f);
}

__global__ __launch_bounds__(256) void k_concept_maps(
    const float* __restrict__ ac, const float* __restrict__ ao, float* __restrict__ out)
{
    int i = blockIdx.x*256 + threadIdx.x;   // < 12288
    int c = i / IMG_, p = i % IMG_;
    float acc = 0.f;
    for (int h = 0; h < 16; ++h) {
        const float* a = ac + (((long)HEADS_ + h)*NC_ + c)*64;
        const float* g = ao + (((long)HEADS_ + h)*S_MAIN + TEXT_ + p)*64;
        for (int d = 0; d < 64; d += 4) {
            float4 av = *(const float4*)(a + d);
            float4 gv = *(const float4*)(g + d);
            acc += av.x*gv.x + av.y*gv.y + av.z*gv.z + av.w*gv.w;
        }
    }
    out[O_CMAP + i] = acc;
}

__global__ void k_imap_raw(const float* __restrict__ ao, const int* __restrict__ selvis,
                           float* __restrict__ imap)
{
    int blk = blockIdx.x;   // (h*8+t)*4+f
    int h = blk >> 5, t = (blk >> 2) & 7, f = blk & 3;
    int tid = threadIdx.x;  // 384
    __shared__ float sel[64];
    int pstar = selvis[blk];
    if (tid < 64) sel[tid] = ao[(((long)HEADS_ + h)*S_MAIN + TEXT_ + f*PATCHES_ + pstar)*64 + tid];
    __syncthreads();
    const float* g = ao + (((long)HEADS_ + h)*S_MAIN + TEXT_ + f*PATCHES_ + tid)*64;
    float acc = 0.f;
    for (int d = 0; d < 64; d += 4) {
        float4 gv = *(const float4*)(g + d);
        acc += gv.x*sel[d] + gv.y*sel[d+1] + gv.z*sel[d+2] + gv.w*sel[d+3];
    }
    imap[((long)h*NC_ + t)*IMG_ + f*PATCHES_ + tid] = acc;
}

__global__ __launch_bounds__(256) void k_imap_norm(float* __restrict__ imap)
{
    int i = blockIdx.x*256 + threadIdx.x;   // < 24576
    int h = i / IMG_, fp = i % IMG_;
    float v[8]; float mu = 0.f;
    #pragma unroll
    for (int t = 0; t < 8; ++t) { v[t] = imap[((long)h*NC_ + t)*IMG_ + fp]; mu += v[t]; }
    mu *= 0.125f;
    float var = 0.f;
    #pragma unroll
    for (int t = 0; t < 8; ++t) var += (v[t]-mu)*(v[t]-mu);
    float sd = sqrtf(var * (1.f / 7.f));
    float inv = 1.f / (sd + 1e-6f);
    #pragma unroll
    for (int t = 0; t < 8; ++t) imap[((long)h*NC_ + t)*IMG_ + fp] = (v[t]-mu)*inv;
}

__global__ __launch_bounds__(256) void k_imap_reduce(
    const float* __restrict__ imap, const int* __restrict__ sel, float* __restrict__ out)
{
    int i = blockIdx.x*256 + threadIdx.x;   // < 12288
    int t = i / IMG_, fp = i % IMG_;
    float sum = 0.f;
    for (int h = 0; h < 16; ++h) sum += imap[((long)h*NC_ + t)*IMG_ + fp];
    float ss = 0.f;
    for (int k = 0; k < 4; ++k) { int h = sel[k]; ss += imap[((long)h*NC_ + t)*IMG_ + fp]; }
    out[O_ISUM + i] = sum;
    out[O_SELI + i] = ss * 0.25f;
}

// residual with fused split-K reduce: X = orig + gate * (p0 + p1 + bo)
__global__ __launch_bounds__(256) void k_residual1(
    const float* __restrict__ pe, const float* __restrict__ ph, const float* __restrict__ pc,
    const float* __restrict__ p0, const float* __restrict__ p1, const float* __restrict__ bo,
    const float* __restrict__ s1, float* __restrict__ X)
{
    long i = (long)blockIdx.x*256 + threadIdx.x;
    int col = (int)(i & 1023);
    long row = i >> 10;
    int b = (int)(row / S2_), s = (int)(row % S2_);
    const float* sb = s1 + (long)b * 6144;
    float orig, gate;
    if (s < TEXT_)       { orig = pe[((long)b*TEXT_ + s)*DIM_ + col];            gate = sb[5120 + col]; }
    else if (s < S_MAIN) { orig = ph[((long)b*IMG_ + (s-TEXT_))*DIM_ + col];     gate = sb[2048 + col]; }
    else                 { orig = pc[((long)b*NC_ + (s-S_MAIN))*DIM_ + col];     gate = sb[5120 + col]; }
    X[i] = orig + gate * (p0[i] + p1[i] + bo[col]);
}

// final with fused split-K reduce: out = X + gate * (f0 + f1 + fb2)
__global__ __launch_bounds__(256) void k_final(
    const float* __restrict__ X, const float* __restrict__ f0, const float* __restrict__ f1,
    const float* __restrict__ fb2, const float* __restrict__ s2, float* __restrict__ out)
{
    long i = (long)blockIdx.x*256 + threadIdx.x;
    int col = (int)(i & 1023);
    long row = i >> 10;
    int b = (int)(row / S2_), s = (int)(row % S2_);
    const float* sb = s2 + (long)b * 6144;
    float gate; float* o;
    if (s < TEXT_)       { gate = sb[5120 + col]; o = out + O_E + ((long)b*TEXT_ + s)*DIM_ + col; }
    else if (s < S_MAIN) { gate = sb[2048 + col]; o = out + O_H + ((long)b*IMG_ + (s-TEXT_))*DIM_ + col; }
    else                 { gate = sb[5120 + col]; o = out + O_C + ((long)b*NC_ + (s-S_MAIN))*DIM_ + col; }
    *o = X[i] + gate * (f0[i] + f1[i] + fb2[col]);
}

extern "C" void kernel_launch(void* const* d_in, const int* in_sizes, int n_in,
                              void* d_out, int out_size, void* d_ws, size_t ws_size,
                              hipStream_t stream)
{
    (void)in_sizes; (void)n_in; (void)out_size; (void)ws_size;
    const float* h_in = (const float*)d_in[0];
    const float* e_in = (const float*)d_in[1];
    const float* c_in = (const float*)d_in[2];
    const float* temb = (const float*)d_in[3];
    const float* rcos = (const float*)d_in[4];
    const float* rsin = (const float*)d_in[5];
    const float* n1w  = (const float*)d_in[6];
    const float* n1b  = (const float*)d_in[7];
    const float* ln1w = (const float*)d_in[8];
    const float* ln1b = (const float*)d_in[9];
    const float* n2w  = (const float*)d_in[10];
    const float* n2b  = (const float*)d_in[11];
    const float* ln2w = (const float*)d_in[12];
    const float* ln2b = (const float*)d_in[13];
    const float* wq   = (const float*)d_in[14];
    const float* wk   = (const float*)d_in[15];
    const float* wv   = (const float*)d_in[16];
    const float* nqw  = (const float*)d_in[17];
    const float* nqb  = (const float*)d_in[18];
    const float* nkw  = (const float*)d_in[19];
    const float* nkb  = (const float*)d_in[20];
    const float* wo   = (const float*)d_in[21];
    const float* bo   = (const float*)d_in[22];
    const float* fw1  = (const float*)d_in[23];
    const float* fb1  = (const float*)d_in[24];
    const float* fw2  = (const float*)d_in[25];
    const float* fb2  = (const float*)d_in[26];

    float* ws  = (float*)d_ws;
    float* out = (float*)d_out;
    float* s1   = ws + OFF_S1;
    float* s2   = ws + OFF_S2;
    float* score  = ws + OFF_MISC;
    int*   selh   = (int*)(ws + OFF_MISC + 16);
    int*   selvis = (int*)(ws + OFF_MISC + 32);
    float* sim  = ws + OFF_SIM;
    float* imap = ws + OFF_IMAP;
    float* ac   = ws + OFF_AC;
    float* X    = ws + OFF_X;
    float* proj = ws + OFF_PROJ;
    float* xn   = ws + OFF_XN;
    float* qh   = ws + OFF_Q;
    float* kh   = ws + OFF_K;
    float* vh   = ws + OFF_V;
    float* ao   = ws + OFF_AO;
    float* ffo  = proj;
    float* fixp = ws + OFF_AO;             // fixup split-K partials (2 x 1536x1024)
    unsigned short* xnb   = (unsigned short*)(ws + OFF_XNB);
    unsigned short* wqkvT = (unsigned short*)(ws + OFF_PROJ);
    unsigned short* vb    = (unsigned short*)(ws + OFF_PROJ);
    unsigned short* qbb   = (unsigned short*)(ws + OFF_X);
    unsigned short* kbb   = qbb + (size_t)B_*HEADS_*S2_*64;
    unsigned short* woT   = (unsigned short*)(ws + OFF_AO + 2000000);
    unsigned short* fw1T  = (unsigned short*)(ws + OFF_V);
    unsigned short* fw2T  = (unsigned short*)(ws + OFF_AO);
    unsigned short* ffh   = (unsigned short*)(ws + OFF_Q);
    // flash split-S partial overlays (dead regions during step 8):
    float* fp0 = vh;    // OFF_V: vh dead after k_vtrans; fw1T arrives step 13
    float* fp1 = xn;    // OFF_XN: xn dead after step 6; proj z1 arrives step 11
    float* fpl = sim;   // OFF_SIM: sim written at step 9 k_sim (after combine)

    // 1. adaLN modulation vectors
    hipLaunchKernelGGL(k_silu_mod, dim3(384), dim3(256), 0, stream, temb, n1w, n1b, n2w, n2b, s1, s2);
    // 2. QKV weight transposes (batched z=3)
    hipLaunchKernelGGL(k_tcvt_qkv, dim3(32, 32, 3), dim3(256), 0, stream, wq, wk, wv, wqkvT);
    // 3. norm1 + modulation -> xn fp32 + xnb bf16
    hipLaunchKernelGGL(k_ln_mod, dim3(ROWS_), dim3(256), 0, stream,
        e_in, (long)TEXT_*DIM_, h_in, (long)IMG_*DIM_, c_in, (long)NC_*DIM_, s1, ln1w, ln1b, xn, xnb);
    // 4. fused QKV bf16 GEMM, headed fp32 scatter
    hipLaunchKernelGGL(k_bgemm, dim3(24, 28, 1), dim3(256), 0, stream,
        xnb, wqkvT, (const float*)nullptr, (float*)nullptr, (unsigned short*)nullptr,
        ROWS_, 3072, 1024, 1024, 0, qh, kh, vh);
    // 5. fp32 q-fixup split-K x2 -> partials, then reduce into headed qh
    hipLaunchKernelGGL(k_gemm, dim3(16, 24, 2), dim3(256), 0, stream,
        xn + (long)(S2_ + TEXT_)*DIM_, wq, (float*)nullptr, IMG_, DIM_, DIM_, 512, 0, 0, fixp);
    hipLaunchKernelGGL(k_fixred, dim3(6144), dim3(256), 0, stream, fixp, qh);
    // 6. fp32 k-fixup (8 concept rows, batch 1) headed
    hipLaunchKernelGGL(k_gemm, dim3(16, 1, 1), dim3(256), 0, stream,
        xn + (long)(S2_ + S_MAIN)*DIM_, wk, kh, NC_, DIM_, DIM_, 1024, 1, S2_ + S_MAIN, (float*)nullptr);
    // 7. QK layernorm + RoPE; V transpose to bf16
    hipLaunchKernelGGL(k_qk_prep, dim3(14160, 2), dim3(256), 0, stream,
        qh, kh, qbb, kbb, nqw, nqb, nkw, nkb, rcos, rsin);
    hipLaunchKernelGGL(k_vtrans, dim3(56, 2, 32), dim3(256), 0, stream, vh, vb);
    // 8. attention: split-S x2, XCD-chunked (bx<28: main u=bx>>1/z=bx&1; bx 28,29: concept z)
    hipLaunchKernelGGL(k_flash, dim3(30, 16, 2), dim3(256), 0, stream,
        qbb, kbb, vb, fp0, fp1, fpl);
    // 8b. combine partials -> ao/ac + merged bf16 (fused old k_merge)
    hipLaunchKernelGGL(k_fcomb, dim3(14160), dim3(256), 0, stream, fp0, fp1, fpl, ao, ac, xnb);
    // 9. maps (batch 1)
    hipLaunchKernelGGL(k_head_score, dim3(16), dim3(256), 0, stream, ao, score);
    hipLaunchKernelGGL(k_top4, dim3(1), dim3(64), 0, stream, score, selh);
    hipLaunchKernelGGL(k_sim, dim3(512), dim3(512), 0, stream, qh, kh, sim, selvis);
    hipLaunchKernelGGL(k_cross, dim3(48), dim3(256), 0, stream, sim, out);
    hipLaunchKernelGGL(k_concept_maps, dim3(48), dim3(256), 0, stream, ac, ao, out);
    hipLaunchKernelGGL(k_imap_raw, dim3(512), dim3(384), 0, stream, ao, selvis, imap);
    hipLaunchKernelGGL(k_imap_norm, dim3(96), dim3(256), 0, stream, imap);
    hipLaunchKernelGGL(k_imap_reduce, dim3(48), dim3(256), 0, stream, imap, selh, out);
    // 10. wo transpose into dead ao region (merge now fused into fcomb)
    hipLaunchKernelGGL(k_tcvt, dim3(32, 32), dim3(256), 0, stream, wo, woT, 1024, 1024);
    // 11. wo GEMM split-K x2 (partials at PROJ / XN)
    hipLaunchKernelGGL(k_bgemm, dim3(8, 28, 2), dim3(256), 0, stream,
        xnb, woT, (const float*)nullptr, proj, (unsigned short*)nullptr, ROWS_, DIM_, 1024, 512, 1,
        (float*)nullptr, (float*)nullptr, (float*)nullptr);
    // 12. residual1 (fused reduce + bias) -> X
    hipLaunchKernelGGL(k_residual1, dim3(14160), dim3(256), 0, stream,
        e_in, h_in, c_in, proj, proj + (size_t)ROWS_*DIM_, bo, s1, X);
    // 13. FF weight transposes
    hipLaunchKernelGGL(k_tcvt, dim3(128, 32), dim3(256), 0, stream, fw1, fw1T, 1024, 4096);
    hipLaunchKernelGGL(k_tcvt, dim3(32, 128), dim3(256), 0, stream, fw2, fw2T, 4096, 1024);
    // 14. norm2 -> xnb bf16 only
    hipLaunchKernelGGL(k_ln_mod, dim3(ROWS_), dim3(256), 0, stream,
        X, (long)S2_*DIM_, X + (long)TEXT_*DIM_, (long)S2_*DIM_, X + (long)S_MAIN*DIM_, (long)S2_*DIM_,
        s2, ln2w, ln2b, (float*)nullptr, xnb);
    // 15. ff1 (gelu fused, bf16 out)
    hipLaunchKernelGGL(k_bgemm, dim3(32, 28, 1), dim3(256), 0, stream,
        xnb, fw1T, fb1, (float*)nullptr, ffh, ROWS_, FF_, 1024, 1024, 2,
        (float*)nullptr, (float*)nullptr, (float*)nullptr);
    // 16. ff2 split-K x2 (partials at PROJ / XN)
    hipLaunchKernelGGL(k_bgemm, dim3(8, 28, 2), dim3(256), 0, stream,
        ffh, fw2T, (const float*)nullptr, ffo, (unsigned short*)nullptr, ROWS_, DIM_, FF_, 2048, 1,
        (float*)nullptr, (float*)nullptr, (float*)nullptr);
    // 17. final (fused reduce + bias) -> outputs
    hipLaunchKernelGGL(k_final, dim3(14160), dim3(256), 0, stream,
        X, ffo, ffo + (size_t)ROWS_*DIM_, fb2, s2, out);
}

// Round 11
// 677.649 us; speedup vs baseline: 1.0764x; 1.0504x over previous
//
#include <hip/hip_runtime.h>
#include <hip/hip_bf16.h>
#include <math.h>

#define B_ 2
#define HEADS_ 16
#define HD_ 64
#define DIM_ 1024
#define TEXT_ 226
#define NC_ 8
#define FRAMES_ 4
#define PATCHES_ 384
#define IMG_ 1536
#define S_MAIN 1762
#define S2_ 1770
#define TD_ 512
#define FF_ 4096
#define ROWS_ (B_*S2_)   // 3540
#define VPAD_ 1792       // padded key dim for transposed V

// ---- workspace offsets (float slots) ----
#define OFF_S1   0L
#define OFF_S2   12288L
#define OFF_MISC 24576L
#define OFF_SIM  25600L
#define OFF_IMAP 222208L
#define OFF_AC   418816L
#define OFF_X    435200L
#define OFF_PROJ 4060160L
#define OFF_XN   7685120L
#define OFF_Q    11310080L
#define OFF_K    14935040L
#define OFF_V    18560000L
#define OFF_AO   22184960L
#define OFF_XNB  25809920L
// overlays (liveness-checked):
//   silu partials fp32 4x24576 @ OFF_X  [step1 -> step1b; qbb overwrites step7]
//   wqkvT bf16(3072x1024) @ OFF_PROJ   [step2 -> step4]
//   vb    bf16(B,H,64,1792) @ OFF_PROJ [step7b -> step8]
//   qb/kb bf16(B,H,S2,64) @ OFF_X      [step7 -> step8; X overwrites step12]
//   fixup partials fp32 2x(1536x1024) @ OFF_AO [step5 -> step5b; ao written step8b]
//   flash split-S partials: p0 fp32(2,16,1770,64) @ OFF_V  [step8 -> step8b; fw1T overwrites step13]
//                           p1 fp32(2,16,1770,64) @ OFF_XN [step8 -> step8b; proj z1 overwrites step11]
//                           pL fp32(2,2,16,1770)  @ OFF_SIM [step8 -> step8b; sim overwrites step9]
//   woT   bf16(1024x1024) @ OFF_AO+2e6 [step10.5 -> step11]
//   fw1T  bf16(4096x1024) @ OFF_V      [step13+]
//   fw2T  bf16(1024x4096) @ OFF_AO     [step13+]
//   ffh   bf16(3540x4096) @ OFF_Q      [step15+]
//   split-K partials: z0 @ OFF_PROJ, z1 @ OFF_XN (contiguous)

// ---- output offsets (floats) ----
#define O_H    0L
#define O_E    3145728L
#define O_C    3608576L
#define O_SELI 3624960L
#define O_ISUM 3637248L
#define O_CMAP 3649536L
#define O_XMAP 3661824L

// pbuf LDS stride (shorts): 72 -> 144B rows, 16B-aligned (b128 single-op).
// kt/vt: stride 64 (128B rows, linear — global_load_lds writes base+lane*16B)
// with PRE-SWIZZLED GLOBAL SOURCE: LDS slot (row r, chunk j) holds global
// chunk j^(r&7). Reads XOR the chunk index with (row&7): conflict-free
// (2 lanes/bank) and 16B-aligned on both sides.
#define PS_ 72

typedef __bf16 bf16x8_t __attribute__((ext_vector_type(8)));
typedef float  f32x4_t  __attribute__((ext_vector_type(4)));

__device__ __forceinline__ unsigned int pack2bf(float a, float b) {
    unsigned short ua = __builtin_bit_cast(unsigned short, (__bf16)a);
    unsigned short ub = __builtin_bit_cast(unsigned short, (__bf16)b);
    return (unsigned int)ua | ((unsigned int)ub << 16);
}

// async global->LDS 16B copy: per-lane global src, wave-uniform LDS base + lane*16
__device__ __forceinline__ void stage16(const unsigned short* g, unsigned short* l) {
    __builtin_amdgcn_global_load_lds(
        (const __attribute__((address_space(1))) unsigned int*)g,
        (__attribute__((address_space(3))) unsigned int*)l, 16, 0, 0);
}

// XCD-chunked bijective remap of a linear workgroup id (requires nwg % 8 == 0)
__device__ __forceinline__ int xcd_swz(int lin, int nwg) {
    if ((nwg & 7) == 0) { int q = nwg >> 3; lin = (lin & 7) * q + (lin >> 3); }
    return lin;
}

// silu(temb) @ norm_w partials. Grid (24, 2, 4): bx = 256-col chunk, by = which
// (w1/w2), bz = k-chunk of 128. Both batches computed in ONE pass over the
// weights (each weight element read exactly once, float4 / 1KB-per-wave
// coalesced). Per-block k-sub x4 LDS reduce; partials at part + bz*24576.
__global__ __launch_bounds__(256) void k_silu_mod(
    const float* __restrict__ temb, const float* __restrict__ w1,
    const float* __restrict__ w2, float* __restrict__ part)
{
    int bx = blockIdx.x, which = blockIdx.y, kz = blockIdx.z;
    const float* w = which ? w2 : w1;
    int tid = threadIdx.x;
    __shared__ float sv[2][512];
    for (int i = tid; i < 1024; i += 256) {
        int b = i >> 9, k = i & 511;
        float tv = temb[b*TD_ + k];
        sv[b][k] = tv / (1.f + __expf(-tv));
    }
    __syncthreads();
    int n4 = tid & 63;        // float4 column within chunk (wave-contiguous)
    int ksub = tid >> 6;      // 0..3
    int ncol = bx*256 + n4*4;
    int k0 = kz*128 + ksub*32;
    float a0x=0.f,a0y=0.f,a0z=0.f,a0w=0.f, a1x=0.f,a1y=0.f,a1z=0.f,a1w=0.f;
    for (int k = k0; k < k0 + 32; ++k) {
        float4 wv = *(const float4*)(w + (size_t)k*6144 + ncol);
        float s0 = sv[0][k], s1 = sv[1][k];
        a0x += s0*wv.x; a0y += s0*wv.y; a0z += s0*wv.z; a0w += s0*wv.w;
        a1x += s1*wv.x; a1y += s1*wv.y; a1z += s1*wv.z; a1w += s1*wv.w;
    }
    __shared__ float red[2][256][4];
    red[0][tid][0]=a0x; red[0][tid][1]=a0y; red[0][tid][2]=a0z; red[0][tid][3]=a0w;
    red[1][tid][0]=a1x; red[1][tid][1]=a1y; red[1][tid][2]=a1z; red[1][tid][3]=a1w;
    __syncthreads();
    if (ksub == 0) {
        #pragma unroll
        for (int s = 1; s < 4; ++s) {
            a0x += red[0][tid+64*s][0]; a0y += red[0][tid+64*s][1];
            a0z += red[0][tid+64*s][2]; a0w += red[0][tid+64*s][3];
            a1x += red[1][tid+64*s][0]; a1y += red[1][tid+64*s][1];
            a1z += red[1][tid+64*s][2]; a1w += red[1][tid+64*s][3];
        }
        long base = (long)kz*24576 + (long)which*12288;
        *(float4*)(part + base + ncol)        = make_float4(a0x,a0y,a0z,a0w);
        *(float4*)(part + base + 6144 + ncol) = make_float4(a1x,a1y,a1z,a1w);
    }
}

// reduce 4 k-partials + bias -> s1/s2
__global__ __launch_bounds__(256) void k_silu_red(
    const float* __restrict__ part, const float* __restrict__ b1,
    const float* __restrict__ b2, float* __restrict__ s1, float* __restrict__ s2)
{
    int i = blockIdx.x*256 + threadIdx.x;   // < 24576
    float v = part[i] + part[i+24576] + part[i+49152] + part[i+73728];
    int which = i / 12288, r = i % 12288, n = r % 6144;
    v += (which ? b2 : b1)[n];
    (which ? s2 : s1)[r] = v;
}

// transpose + convert: src (K,N) fp32 -> dst (N,K) bf16
__global__ __launch_bounds__(256) void k_tcvt(
    const float* __restrict__ src, unsigned short* __restrict__ dst, int K, int N)
{
    __shared__ float t[32][33];
    int n0 = blockIdx.x * 32, k0 = blockIdx.y * 32;
    int tx = threadIdx.x & 31, ty = threadIdx.x >> 5;
    #pragma unroll
    for (int i = 0; i < 4; ++i)
        t[ty + 8*i][tx] = src[(size_t)(k0 + ty + 8*i) * N + n0 + tx];
    __syncthreads();
    #pragma unroll
    for (int i = 0; i < 4; ++i) {
        float v = t[tx][ty + 8*i];
        dst[(size_t)(n0 + ty + 8*i) * K + k0 + tx] =
            __builtin_bit_cast(unsigned short, (__bf16)v);
    }
}

// batched QKV transpose (z selects wq/wk/wv), 1024x1024 each
__global__ __launch_bounds__(256) void k_tcvt_qkv(
    const float* __restrict__ wq, const float* __restrict__ wk, const float* __restrict__ wv,
    unsigned short* __restrict__ dst)
{
    const float* src = (blockIdx.z == 0) ? wq : (blockIdx.z == 1) ? wk : wv;
    unsigned short* d = dst + (size_t)blockIdx.z * 1024 * 1024;
    __shared__ float t[32][33];
    int n0 = blockIdx.x * 32, k0 = blockIdx.y * 32;
    int tx = threadIdx.x & 31, ty = threadIdx.x >> 5;
    #pragma unroll
    for (int i = 0; i < 4; ++i)
        t[ty + 8*i][tx] = src[(size_t)(k0 + ty + 8*i) * 1024 + n0 + tx];
    __syncthreads();
    #pragma unroll
    for (int i = 0; i < 4; ++i) {
        float v = t[tx][ty + 8*i];
        d[(size_t)(n0 + ty + 8*i) * 1024 + k0 + tx] =
            __builtin_bit_cast(unsigned short, (__bf16)v);
    }
}

// V (B,H,S2,64) fp32 -> vb (B,H,64,VPAD) bf16 transposed
__global__ __launch_bounds__(256) void k_vtrans(
    const float* __restrict__ vh, unsigned short* __restrict__ vb)
{
    int bh = blockIdx.z;
    int d0 = blockIdx.y * 32;
    int s0 = blockIdx.x * 32;
    __shared__ float t[32][33];
    int tx = threadIdx.x & 31, ty = threadIdx.x >> 5;
    const float* src = vh + (size_t)bh * S2_ * 64;
    #pragma unroll
    for (int i = 0; i < 4; ++i) {
        int s = s0 + ty + 8*i; if (s >= S2_) s = S2_ - 1;
        t[ty + 8*i][tx] = src[(size_t)s*64 + d0 + tx];
    }
    __syncthreads();
    unsigned short* dst = vb + (size_t)bh * 64 * VPAD_;
    #pragma unroll
    for (int i = 0; i < 4; ++i) {
        int d = d0 + ty + 8*i;
        dst[(size_t)d * VPAD_ + s0 + tx] =
            __builtin_bit_cast(unsigned short, (__bf16)t[tx][ty + 8*i]);
    }
}

// fused layernorm + adaLN modulation -> optional fp32 out AND bf16 outb
__global__ __launch_bounds__(256) void k_ln_mod(
    const float* pe, long bse, const float* ph, long bsh, const float* pc, long bsc,
    const float* __restrict__ smod, const float* __restrict__ lnw, const float* __restrict__ lnb,
    float* __restrict__ out, unsigned short* __restrict__ outb)
{
    long row = blockIdx.x;
    int b = (int)(row / S2_), s = (int)(row % S2_);
    const float* src; int shiftB, scaleB;
    if (s < TEXT_)       { src = pe + (long)b*bse + (long)s*DIM_;          shiftB = 3072; scaleB = 4096; }
    else if (s < S_MAIN) { src = ph + (long)b*bsh + (long)(s-TEXT_)*DIM_;  shiftB = 0;    scaleB = 1024; }
    else                 { src = pc + (long)b*bsc + (long)(s-S_MAIN)*DIM_; shiftB = 3072; scaleB = 4096; }
    int tid = threadIdx.x;
    int col = tid * 4;
    float4 x = *(const float4*)(src + col);
    float lsum = x.x + x.y + x.z + x.w;
    float lsq  = x.x*x.x + x.y*x.y + x.z*x.z + x.w*x.w;
    __shared__ float r1[256], r2[256];
    r1[tid] = lsum; r2[tid] = lsq; __syncthreads();
    for (int st = 128; st; st >>= 1) {
        if (tid < st) { r1[tid] += r1[tid+st]; r2[tid] += r2[tid+st]; }
        __syncthreads();
    }
    float mu = r1[0] * (1.f / DIM_);
    float var = r2[0] * (1.f / DIM_) - mu * mu;
    float rstd = rsqrtf(var + 1e-5f);
    const float* sb = smod + (long)b * 6144;
    float xs[4] = {x.x, x.y, x.z, x.w};
    float res[4];
    #pragma unroll
    for (int i = 0; i < 4; ++i) {
        int cc = col + i;
        float yy = (xs[i] - mu) * rstd * lnw[cc] + lnb[cc];
        res[i] = yy * (1.f + sb[scaleB + cc]) + sb[shiftB + cc];
    }
    if (out)
        *(float4*)(out + row * DIM_ + col) = make_float4(res[0], res[1], res[2], res[3]);
    uint2 pk;
    pk.x = pack2bf(res[0], res[1]); pk.y = pack2bf(res[2], res[3]);
    *(uint2*)(outb + row * DIM_ + col) = pk;
}

// bf16 MFMA GEMM, double-buffered LDS staged via global_load_lds (16B, async),
// optional split-K via gridDim.z. Linear LDS [128][32] per tile (no pad).
// XCD-chunked tile remap for L2 locality.
__global__ __launch_bounds__(256, 4) void k_bgemm(
    const unsigned short* __restrict__ A, const unsigned short* __restrict__ Wt,
    const float* __restrict__ bias, float* __restrict__ out_f,
    unsigned short* __restrict__ out_b, int M, int N, int K, int kz_len, int mode,
    float* __restrict__ q_out, float* __restrict__ k_out, float* __restrict__ v_out)
{
    __shared__ unsigned short at[2][128*32];
    __shared__ unsigned short bt[2][128*32];
    int tid = threadIdx.x;
    int w = tid >> 6, lane = tid & 63;
    int lr = lane & 15, lh = lane >> 4;
    int wm = w >> 1, wn = w & 1;
    int gx = gridDim.x;
    int lin = xcd_swz(blockIdx.y * gx + blockIdx.x, gx * gridDim.y);
    int m0 = (lin / gx) * 128, n0 = (lin % gx) * 128;
    int kbeg = blockIdx.z * kz_len, kend = kbeg + kz_len;

    f32x4_t acc[4][4];
    #pragma unroll
    for (int i = 0; i < 4; ++i)
        #pragma unroll
        for (int j = 0; j < 4; ++j) { acc[i][j][0]=0.f; acc[i][j][1]=0.f; acc[i][j][2]=0.f; acc[i][j][3]=0.f; }

    // staging geometry: issue i (0,1) covers rows i*64 + (tid>>2), 16B chunk (tid&3)
    int r4 = tid >> 2, c4 = tid & 3;
    int arow0 = m0 + r4;      if (arow0 >= M) arow0 = M - 1;
    int arow1 = m0 + 64 + r4; if (arow1 >= M) arow1 = M - 1;
    const unsigned short* ga0 = A + (size_t)arow0 * K + c4 * 8;
    const unsigned short* ga1 = A + (size_t)arow1 * K + c4 * 8;
    const unsigned short* gb0 = Wt + (size_t)(n0 + r4) * K + c4 * 8;
    const unsigned short* gb1 = Wt + (size_t)(n0 + 64 + r4) * K + c4 * 8;
    int lbase = w * 512;   // shorts; wave-uniform; HW adds lane*16B

    // prologue: stage buf 0
    stage16(ga0 + kbeg, &at[0][lbase]);
    stage16(ga1 + kbeg, &at[0][lbase + 2048]);
    stage16(gb0 + kbeg, &bt[0][lbase]);
    stage16(gb1 + kbeg, &bt[0][lbase + 2048]);
    __syncthreads();
    int buf = 0;
    for (int k0 = kbeg; k0 < kend; k0 += 32) {
        bool more = (k0 + 32) < kend;
        if (more) {
            int nb = buf ^ 1;
            stage16(ga0 + k0 + 32, &at[nb][lbase]);
            stage16(ga1 + k0 + 32, &at[nb][lbase + 2048]);
            stage16(gb0 + k0 + 32, &bt[nb][lbase]);
            stage16(gb1 + k0 + 32, &bt[nb][lbase + 2048]);
        }
        int4 af[4], bf[4];
        #pragma unroll
        for (int tm = 0; tm < 4; ++tm)
            af[tm] = *(const int4*)&at[buf][(wm*64 + tm*16 + lr)*32 + lh*8];
        #pragma unroll
        for (int tn = 0; tn < 4; ++tn)
            bf[tn] = *(const int4*)&bt[buf][(wn*64 + tn*16 + lr)*32 + lh*8];
        #pragma unroll
        for (int tm = 0; tm < 4; ++tm) {
            bf16x8_t av = __builtin_bit_cast(bf16x8_t, af[tm]);
            #pragma unroll
            for (int tn = 0; tn < 4; ++tn)
                acc[tm][tn] = __builtin_amdgcn_mfma_f32_16x16x32_bf16(
                    av, __builtin_bit_cast(bf16x8_t, bf[tn]), acc[tm][tn], 0, 0, 0);
        }
        __syncthreads();
        buf ^= 1;
    }
    float* of = out_f;
    if (mode == 1) of += (size_t)blockIdx.z * M * N;
    #pragma unroll
    for (int tm = 0; tm < 4; ++tm) {
        #pragma unroll
        for (int r = 0; r < 4; ++r) {
            int m = m0 + wm*64 + tm*16 + lh*4 + r;
            if (m >= M) continue;
            int b = m / S2_, s = m % S2_;
            #pragma unroll
            for (int tn = 0; tn < 4; ++tn) {
                int n = n0 + wn*64 + tn*16 + lr;
                float v = acc[tm][tn][r];
                if (mode == 0) {
                    int which = n >> 10, c = n & 1023;
                    int hh = c >> 6, d = c & 63;
                    float* dstp = (which == 0) ? q_out : (which == 1) ? k_out : v_out;
                    dstp[(((size_t)b*HEADS_ + hh)*S2_ + s)*64 + d] = v;
                } else if (mode == 1) {
                    of[(size_t)m * N + n] = v + (bias ? bias[n] : 0.f);
                } else {
                    float x = v + bias[n];
                    float u = 0.7978845608028654f * (x + 0.044715f*x*x*x);
                    float g = x / (1.f + __expf(-2.f*u));
                    out_b[(size_t)m * N + n] = __builtin_bit_cast(unsigned short, (__bf16)g);
                }
            }
        }
    }
}

// fp32 tiled GEMM (argmax fixups). If part != nullptr: write plain partial at
// part + z*M*N (split-K, K range [z*kz, (z+1)*kz)). Else headed/plain store.
__global__ __launch_bounds__(256) void k_gemm(
    const float* __restrict__ A, const float* __restrict__ W,
    float* __restrict__ C, int M, int N, int K, int kz_len, int headed, int row_off,
    float* __restrict__ part)
{
    __shared__ float As[16][68];
    __shared__ float Bs[16][68];
    int tid = threadIdx.x;
    int gx = gridDim.x;
    int lin = xcd_swz(blockIdx.y * gx + blockIdx.x, gx * gridDim.y);
    int bm = (lin / gx) * 64, bn = (lin % gx) * 64;
    int tr = tid >> 4, tc = tid & 15;
    int ar = tid >> 2, akk = (tid & 3) * 4;
    int bkk = tid >> 4, bn4 = (tid & 15) * 4;
    float acc[4][4] = {{0.f}};
    int garow = bm + ar;
    const float* Aptr = A + (size_t)garow * K + akk;
    const float* Wptr = W + (size_t)bkk * N + bn + bn4;
    int kbeg = blockIdx.z * kz_len;
    for (int k0 = kbeg; k0 < kbeg + kz_len; k0 += 16) {
        float4 av = make_float4(0.f, 0.f, 0.f, 0.f);
        if (garow < M) av = *(const float4*)(Aptr + k0);
        As[akk+0][ar] = av.x; As[akk+1][ar] = av.y; As[akk+2][ar] = av.z; As[akk+3][ar] = av.w;
        float4 bv = *(const float4*)(Wptr + (size_t)k0 * N);
        Bs[bkk][bn4+0] = bv.x; Bs[bkk][bn4+1] = bv.y; Bs[bkk][bn4+2] = bv.z; Bs[bkk][bn4+3] = bv.w;
        __syncthreads();
        #pragma unroll
        for (int kk = 0; kk < 16; ++kk) {
            float4 a = *(const float4*)&As[kk][tr*4];
            float4 bq = *(const float4*)&Bs[kk][tc*4];
            float avv[4] = {a.x, a.y, a.z, a.w};
            float bvv[4] = {bq.x, bq.y, bq.z, bq.w};
            #pragma unroll
            for (int i = 0; i < 4; ++i)
                #pragma unroll
                for (int j = 0; j < 4; ++j)
                    acc[i][j] += avv[i] * bvv[j];
        }
        __syncthreads();
    }
    #pragma unroll
    for (int i = 0; i < 4; ++i) {
        int r = bm + tr*4 + i;
        if (r >= M) continue;
        #pragma unroll
        for (int j = 0; j < 4; ++j) {
            int n = bn + tc*4 + j;
            float v = acc[i][j];
            if (part) {
                part[(size_t)blockIdx.z*M*N + (size_t)r*N + n] = v;
            } else if (headed) {
                int rg = r + row_off;
                int b = rg / S2_, s = rg % S2_;
                int hh = n >> 6, d = n & 63;
                C[(((size_t)b*HEADS_ + hh)*S2_ + s)*64 + d] = v;
            } else {
                C[(size_t)(r + row_off) * N + n] = v;
            }
        }
    }
}

// sum 2 fixup partials -> headed fp32 store into qh (batch1 img rows)
__global__ __launch_bounds__(256) void k_fixred(
    const float* __restrict__ pa, float* __restrict__ qh_out)
{
    long i = (long)blockIdx.x*256 + threadIdx.x;   // < 1536*1024
    int r = (int)(i >> 10), n = (int)(i & 1023);
    float v = pa[i] + pa[i + (long)IMG_*DIM_];
    int hh = n >> 6, d = n & 63;
    qh_out[(((size_t)HEADS_ + hh)*S2_ + TEXT_ + r)*64 + d] = v;
}

// per-head layernorm + RoPE: bf16 everywhere; fp32 write-back only for argmax rows
__global__ __launch_bounds__(256) void k_qk_prep(
    float* qh, float* kh, unsigned short* qbb, unsigned short* kbb,
    const float* __restrict__ nqw, const float* __restrict__ nqb,
    const float* __restrict__ nkw, const float* __restrict__ nkb,
    const float* __restrict__ rc, const float* __restrict__ rs)
{
    int which = blockIdx.y;
    int wid = threadIdx.x >> 6;
    int lane = threadIdx.x & 63;
    long row = (long)blockIdx.x * 4 + wid;   // (b*16+h)*S2 + s
    long s = row % S2_;
    bool b1 = row >= (long)HEADS_*S2_;
    float* base = (which ? kh : qh) + row * 64;
    const float* w  = which ? nkw : nqw;
    const float* bb = which ? nkb : nqb;
    float x = base[lane];
    float sum = x;
    for (int off = 1; off < 64; off <<= 1) sum += __shfl_xor(sum, off, 64);
    float mu = sum * (1.f / 64.f);
    float dx = x - mu;
    float v = dx * dx;
    for (int off = 1; off < 64; off <<= 1) v += __shfl_xor(v, off, 64);
    float rstd = rsqrtf(v * (1.f / 64.f) + 1e-6f);
    float y = dx * rstd * w[lane] + bb[lane];
    if (s >= TEXT_ && s < S_MAIN) {
        long p = s - TEXT_;
        float part = __shfl_xor(y, 1, 64);
        float rot = (lane & 1) ? part : -part;
        y = y * rc[p*64 + lane] + rot * rs[p*64 + lane];
    }
    bool needf = b1 && (which ? (s >= S_MAIN) : (s >= TEXT_ && s < S_MAIN));
    if (needf) base[lane] = y;
    (which ? kbb : qbb)[row * 64 + lane] = __builtin_bit_cast(unsigned short, (__bf16)y);
}

// MFMA flash attention with 2-way KV split (split-S). 128-q blocks, 4 waves.
// No-max softmax makes the split exactly associative: each split writes
// unnormalized O and L partials; k_fcomb does (O0+O1)/(L0+L1).
// K/V staged via global_load_lds: linear LDS dest (stride-64 rows, the exact
// wave-uniform+lane*16B layout the DMA writes) + pre-swizzled global source
// (content chunk j^(slot_row&7)); reads XOR the chunk with (row&7) ->
// conflict-free, 16B-aligned, no VGPR round-trip. Full-tile fast path skips
// the tail mask (only ~1 in 14 tiles is partial).
// XCD-chunked remap over the full 960-block grid (4 KV sets per XCD ~1.8MB L2).
__global__ __launch_bounds__(256) void k_flash(
    const unsigned short* __restrict__ qb, const unsigned short* __restrict__ kb,
    const unsigned short* __restrict__ vb,
    float* __restrict__ p0, float* __restrict__ p1, float* __restrict__ pl)
{
    int lin3 = (blockIdx.z * gridDim.y + blockIdx.y) * gridDim.x + blockIdx.x;
    lin3 = xcd_swz(lin3, gridDim.x * gridDim.y * gridDim.z);
    int bx = lin3 % 30;
    int rest = lin3 / 30;
    int h = rest & 15, b = rest >> 4;
    int qt, NQ, q_off, r0s, r0e, r1s, r1e, z;
    if (bx < 28) {
        z = bx & 1; int u = bx >> 1;
        qt = u*128; NQ = S_MAIN; q_off = 0;
        r0s = z ? 896 : 0; r0e = z ? S_MAIN : 896;
        r1s = 0; r1e = 0;
    } else {
        z = bx - 28;
        qt = 0; NQ = NC_; q_off = S_MAIN;
        if (z == 0) { r0s = S_MAIN;      r0e = S2_;    r1s = TEXT_; r1e = TEXT_ + 768; }
        else        { r0s = TEXT_ + 768; r0e = S_MAIN; r1s = 0;     r1e = 0; }
    }
    float* po = z ? p1 : p0;
    int tid = threadIdx.x;
    int w = tid >> 6, lane = tid & 63;
    int lr = lane & 15, lh = lane >> 4;
    int s7 = lr & 7;   // row&7 for all fragment rows 16g+lr
    __shared__ __align__(16) unsigned short kt[64*64];
    __shared__ __align__(16) unsigned short vt[64*64];
    __shared__ __align__(16) unsigned short pbuf[4*32*PS_];
    unsigned short* pw = pbuf + w*32*PS_;
    const unsigned short* qbase = qb + (((size_t)b*HEADS_ + h)*S2_ + q_off)*64;
    const unsigned short* kbase = kb + ((size_t)b*HEADS_ + h)*S2_*64;
    const unsigned short* vbase = vb + (size_t)(b*HEADS_ + h)*64*VPAD_;
    // staging geometry (per issue i=0,1): idx = tid + i*256; slot row idx>>3,
    // chunk idx&7; LDS dest is linear idx*16B (wave-uniform base + lane*16B);
    // global src chunk = (idx&7) ^ (slot_row & 7). srow1&7 == srow0&7.
    int srow0 = tid >> 3, schunk = tid & 7;
    int srow1 = srow0 + 32;
    int sc0 = (schunk ^ (srow0 & 7)) << 3;
    int ldst0 = (w * 64) * 8;                // shorts; wave-uniform
    int ldst1 = (256 + w * 64) * 8;
    bf16x8_t aq[2][2];
    #pragma unroll
    for (int t = 0; t < 2; ++t) {
        int qrow = qt + w*32 + t*16 + lr; if (qrow >= NQ) qrow = NQ - 1;
        const unsigned short* qsrc = qbase + (size_t)qrow*64 + lh*8;
        aq[t][0] = __builtin_bit_cast(bf16x8_t, *(const int4*)qsrc);
        aq[t][1] = __builtin_bit_cast(bf16x8_t, *(const int4*)(qsrc + 32));
    }
    int4 onesi = make_int4(0x3F803F80, 0x3F803F80, 0x3F803F80, 0x3F803F80);
    bf16x8_t bones = __builtin_bit_cast(bf16x8_t, onesi);
    f32x4_t O[2][4];
    f32x4_t Lacc[2];
    #pragma unroll
    for (int t = 0; t < 2; ++t) {
        Lacc[t][0]=0.f; Lacc[t][1]=0.f; Lacc[t][2]=0.f; Lacc[t][3]=0.f;
        #pragma unroll
        for (int g = 0; g < 4; ++g) { O[t][g][0]=0.f; O[t][g][1]=0.f; O[t][g][2]=0.f; O[t][g][3]=0.f; }
    }
    for (int rgi = 0; rgi < 2; ++rgi) {
        int rs = rgi ? r1s : r0s, re = rgi ? r1e : r0e;
        for (int j0 = rs; j0 < re; j0 += 64) {
            int cnt = min(64, re - j0);
            __syncthreads();
            {
                int kr0 = j0 + srow0; if (kr0 > re - 1) kr0 = re - 1;
                int kr1 = j0 + srow1; if (kr1 > re - 1) kr1 = re - 1;
                stage16(kbase + (size_t)kr0*64 + sc0, &kt[ldst0]);
                stage16(kbase + (size_t)kr1*64 + sc0, &kt[ldst1]);
                stage16(vbase + (size_t)srow0*VPAD_ + j0 + sc0, &vt[ldst0]);
                stage16(vbase + (size_t)srow1*VPAD_ + j0 + sc0, &vt[ldst1]);
            }
            __syncthreads();
            f32x4_t S[2][4];
            #pragma unroll
            for (int g = 0; g < 4; ++g) {
                const unsigned short* kr = &kt[(16*g + lr)*64];
                bf16x8_t b0 = __builtin_bit_cast(bf16x8_t, *(const int4*)(kr + ((lh ^ s7) << 3)));
                bf16x8_t b1 = __builtin_bit_cast(bf16x8_t, *(const int4*)(kr + (((lh + 4) ^ s7) << 3)));
                #pragma unroll
                for (int t = 0; t < 2; ++t) {
                    f32x4_t zz; zz[0]=0.f; zz[1]=0.f; zz[2]=0.f; zz[3]=0.f;
                    zz = __builtin_amdgcn_mfma_f32_16x16x32_bf16(aq[t][0], b0, zz, 0, 0, 0);
                    zz = __builtin_amdgcn_mfma_f32_16x16x32_bf16(aq[t][1], b1, zz, 0, 0, 0);
                    S[t][g] = zz;
                }
            }
            if (cnt == 64) {
                #pragma unroll
                for (int t = 0; t < 2; ++t)
                    #pragma unroll
                    for (int g = 0; g < 4; ++g)
                        #pragma unroll
                        for (int r = 0; r < 4; ++r) {
                            float p = __expf(S[t][g][r] * 0.125f);
                            pw[(t*16 + lh*4 + r)*PS_ + 16*g + lr] = __builtin_bit_cast(unsigned short, (__bf16)p);
                        }
            } else {
                #pragma unroll
                for (int t = 0; t < 2; ++t)
                    #pragma unroll
                    for (int g = 0; g < 4; ++g) {
                        bool vld = (16*g + lr) < cnt;
                        #pragma unroll
                        for (int r = 0; r < 4; ++r) {
                            float p = vld ? __expf(S[t][g][r] * 0.125f) : 0.f;
                            pw[(t*16 + lh*4 + r)*PS_ + 16*g + lr] = __builtin_bit_cast(unsigned short, (__bf16)p);
                        }
                    }
            }
            #pragma unroll
            for (int c = 0; c < 2; ++c) {
                bf16x8_t ap[2];
                #pragma unroll
                for (int t = 0; t < 2; ++t) {
                    ap[t] = __builtin_bit_cast(bf16x8_t,
                        *(const int4*)&pw[(t*16 + lr)*PS_ + c*32 + lh*8]);
                    Lacc[t] = __builtin_amdgcn_mfma_f32_16x16x32_bf16(ap[t], bones, Lacc[t], 0, 0, 0);
                }
                #pragma unroll
                for (int g = 0; g < 4; ++g) {
                    const unsigned short* vr = &vt[(16*g + lr)*64];
                    bf16x8_t bv = __builtin_bit_cast(bf16x8_t,
                        *(const int4*)(vr + (((c*4 + lh) ^ s7) << 3)));
                    #pragma unroll
                    for (int t = 0; t < 2; ++t)
                        O[t][g] = __builtin_amdgcn_mfma_f32_16x16x32_bf16(ap[t], bv, O[t][g], 0, 0, 0);
                }
            }
        }
    }
    #pragma unroll
    for (int t = 0; t < 2; ++t)
        #pragma unroll
        for (int r = 0; r < 4; ++r) {
            int gq = qt + w*32 + t*16 + lh*4 + r;
            if (gq < NQ) {
                long rrow = (long)(b*HEADS_ + h)*S2_ + q_off + gq;
                float* o = po + rrow*64 + lr;
                #pragma unroll
                for (int g = 0; g < 4; ++g) o[16*g] = O[t][g][r];
                if (lr == 0) pl[(long)z*(B_*HEADS_*S2_) + rrow] = Lacc[t][r];
            }
        }
}

// combine split-S partials: ao/ac = (p0+p1)/(l0+l1); also emit merged bf16 row
// layout (fuses the old k_merge): xo[(b*S2+s)*1024 + h*64+d]
__global__ __launch_bounds__(256) void k_fcomb(
    const float* __restrict__ p0, const float* __restrict__ p1,
    const float* __restrict__ pl,
    float* __restrict__ ao, float* __restrict__ ac, unsigned short* __restrict__ xo)
{
    long i = (long)blockIdx.x*256 + threadIdx.x;   // < 2*16*1770*64
    int d = (int)(i & 63);
    long rrow = i >> 6;                             // (b*16+h)*S2 + s
    int s = (int)(rrow % S2_);
    int bh = (int)(rrow / S2_);
    int b = bh >> 4, h = bh & 15;
    float l = pl[rrow] + pl[rrow + (long)B_*HEADS_*S2_];
    float v = (p0[i] + p1[i]) / l;
    if (s < S_MAIN) ao[((long)bh*S_MAIN + s)*64 + d] = v;
    else            ac[((long)bh*NC_ + (s - S_MAIN))*64 + d] = v;
    xo[((long)b*S2_ + s)*DIM_ + h*64 + d] = __builtin_bit_cast(unsigned short, (__bf16)v);
}

__global__ __launch_bounds__(256) void k_head_score(const float* __restrict__ ao, float* __restrict__ score)
{
    int h = blockIdx.x, tid = threadIdx.x;
    const float* base = ao + (((long)HEADS_ + h)*S_MAIN + TEXT_)*64;
    float sA = 0.f, sB = 0.f;
    for (int p = tid; p < IMG_; p += 256) {
        const float* r = base + (long)p*64;
        float mm = 0.f;
        for (int d = 0; d < 64; d += 4) {
            float4 v = *(const float4*)(r + d);
            mm += v.x + v.y + v.z + v.w;
        }
        mm *= (1.f / 64.f);
        sA += mm; sB += mm*mm;
    }
    __shared__ float r1[256], r2[256];
    r1[tid] = sA; r2[tid] = sB; __syncthreads();
    for (int st = 128; st; st >>= 1) {
        if (tid < st) { r1[tid] += r1[tid+st]; r2[tid] += r2[tid+st]; }
        __syncthreads();
    }
    if (tid == 0) {
        float mean = r1[0] / IMG_, ms = r2[0] / IMG_;
        score[h] = sqrtf(fmaxf(ms - mean*mean, 0.f));
    }
}

__global__ void k_top4(const float* __restrict__ score, int* __restrict__ sel)
{
    if (threadIdx.x == 0 && blockIdx.x == 0) {
        int used = 0;
        for (int k = 0; k < 4; ++k) {
            float best = -INFINITY; int bi = 0;
            for (int h2 = 0; h2 < 16; ++h2) {
                if (used & (1 << h2)) continue;
                if (score[h2] > best) { best = score[h2]; bi = h2; }
            }
            used |= 1 << bi; sel[k] = bi;
        }
    }
}

__global__ __launch_bounds__(512) void k_sim(
    const float* __restrict__ qh, const float* __restrict__ kh,
    float* __restrict__ sim, int* __restrict__ selvis)
{
    int blk = blockIdx.x;    // (h*8+t)*4+f
    int h = blk >> 5, t = (blk >> 2) & 7, f = blk & 3;
    int tid = threadIdx.x;
    __shared__ float ckv[64];
    if (tid < 64) ckv[tid] = kh[(((long)HEADS_ + h)*S2_ + S_MAIN + t)*64 + tid];
    __syncthreads();
    float val = -INFINITY; int idx = 0x7fffffff;
    if (tid < PATCHES_) {
        const float* qrow = qh + (((long)HEADS_ + h)*S2_ + TEXT_ + f*PATCHES_ + tid)*64;
        float acc = 0.f;
        for (int d = 0; d < 64; d += 4) {
            float4 qv = *(const float4*)(qrow + d);
            acc += qv.x*ckv[d] + qv.y*ckv[d+1] + qv.z*ckv[d+2] + qv.w*ckv[d+3];
        }
        sim[((long)h*NC_ + t)*IMG_ + f*PATCHES_ + tid] = acc;
        val = acc; idx = tid;
    }
    __shared__ float sv[512]; __shared__ int si[512];
    sv[tid] = val; si[tid] = idx; __syncthreads();
    for (int st = 256; st; st >>= 1) {
        if (tid < st) {
            float v2 = sv[tid+st]; int i2 = si[tid+st];
            if (v2 > sv[tid] || (v2 == sv[tid] && i2 < si[tid])) { sv[tid] = v2; si[tid] = i2; }
        }
        __syncthreads();
    }
    if (tid == 0) selvis[blk] = si[0];
}

__global__ __launch_bounds__(256) void k_cross(const float* __restrict__ sim, float* __restrict__ out)
{
    int i = blockIdx.x*256 + threadIdx.x;   // < 12288
    int c = i / IMG_, p = i % IMG_;
    float acc = 0.f;
    for (int h = 0; h < 16; ++h) acc += sim[((long)h*NC_ + c)*IMG_ + p];
    out[O_XMAP + i] = acc * (1.f / 16.f);
}

__global__ __launch_bounds__(256) void k_concept_maps(
    const float* __restrict__ ac, const float* __restrict__ ao, float* __restrict__ out)
{
    int i = blockIdx.x*256 + threadIdx.x;   // < 12288
    int c = i / IMG_, p = i % IMG_;
    float acc = 0.f;
    for (int h = 0; h < 16; ++h) {
        const float* a = ac + (((long)HEADS_ + h)*NC_ + c)*64;
        const float* g = ao + (((long)HEADS_ + h)*S_MAIN + TEXT_ + p)*64;
        for (int d = 0; d < 64; d += 4) {
            float4 av = *(const float4*)(a + d);
            float4 gv = *(const float4*)(g + d);
            acc += av.x*gv.x + av.y*gv.y + av.z*gv.z + av.w*gv.w;
        }
    }
    out[O_CMAP + i] = acc;
}

__global__ void k_imap_raw(const float* __restrict__ ao, const int* __restrict__ selvis,
                           float* __restrict__ imap)
{
    int blk = blockIdx.x;   // (h*8+t)*4+f
    int h = blk >> 5, t = (blk >> 2) & 7, f = blk & 3;
    int tid = threadIdx.x;  // 384
    __shared__ float sel[64];
    int pstar = selvis[blk];
    if (tid < 64) sel[tid] = ao[(((long)HEADS_ + h)*S_MAIN + TEXT_ + f*PATCHES_ + pstar)*64 + tid];
    __syncthreads();
    const float* g = ao + (((long)HEADS_ + h)*S_MAIN + TEXT_ + f*PATCHES_ + tid)*64;
    float acc = 0.f;
    for (int d = 0; d < 64; d += 4) {
        float4 gv = *(const float4*)(g + d);
        acc += gv.x*sel[d] + gv.y*sel[d+1] + gv.z*sel[d+2] + gv.w*sel[d+3];
    }
    imap[((long)h*NC_ + t)*IMG_ + f*PATCHES_ + tid] = acc;
}

__global__ __launch_bounds__(256) void k_imap_norm(float* __restrict__ imap)
{
    int i = blockIdx.x*256 + threadIdx.x;   // < 24576
    int h = i / IMG_, fp = i % IMG_;
    float v[8]; float mu = 0.f;
    #pragma unroll
    for (int t = 0; t < 8; ++t) { v[t] = imap[((long)h*NC_ + t)*IMG_ + fp]; mu += v[t]; }
    mu *= 0.125f;
    float var = 0.f;
    #pragma unroll
    for (int t = 0; t < 8; ++t) var += (v[t]-mu)*(v[t]-mu);
    float sd = sqrtf(var * (1.f / 7.f));
    float inv = 1.f / (sd + 1e-6f);
    #pragma unroll
    for (int t = 0; t < 8; ++t) imap[((long)h*NC_ + t)*IMG_ + fp] = (v[t]-mu)*inv;
}

__global__ __launch_bounds__(256) void k_imap_reduce(
    const float* __restrict__ imap, const int* __restrict__ sel, float* __restrict__ out)
{
    int i = blockIdx.x*256 + threadIdx.x;   // < 12288
    int t = i / IMG_, fp = i % IMG_;
    float sum = 0.f;
    for (int h = 0; h < 16; ++h) sum += imap[((long)h*NC_ + t)*IMG_ + fp];
    float ss = 0.f;
    for (int k = 0; k < 4; ++k) { int h = sel[k]; ss += imap[((long)h*NC_ + t)*IMG_ + fp]; }
    out[O_ISUM + i] = sum;
    out[O_SELI + i] = ss * 0.25f;
}

// residual with fused split-K reduce: X = orig + gate * (p0 + p1 + bo)
__global__ __launch_bounds__(256) void k_residual1(
    const float* __restrict__ pe, const float* __restrict__ ph, const float* __restrict__ pc,
    const float* __restrict__ p0, const float* __restrict__ p1, const float* __restrict__ bo,
    const float* __restrict__ s1, float* __restrict__ X)
{
    long i = (long)blockIdx.x*256 + threadIdx.x;
    int col = (int)(i & 1023);
    long row = i >> 10;
    int b = (int)(row / S2_), s = (int)(row % S2_);
    const float* sb = s1 + (long)b * 6144;
    float orig, gate;
    if (s < TEXT_)       { orig = pe[((long)b*TEXT_ + s)*DIM_ + col];            gate = sb[5120 + col]; }
    else if (s < S_MAIN) { orig = ph[((long)b*IMG_ + (s-TEXT_))*DIM_ + col];     gate = sb[2048 + col]; }
    else                 { orig = pc[((long)b*NC_ + (s-S_MAIN))*DIM_ + col];     gate = sb[5120 + col]; }
    X[i] = orig + gate * (p0[i] + p1[i] + bo[col]);
}

// final with fused split-K reduce: out = X + gate * (f0 + f1 + fb2)
__global__ __launch_bounds__(256) void k_final(
    const float* __restrict__ X, const float* __restrict__ f0, const float* __restrict__ f1,
    const float* __restrict__ fb2, const float* __restrict__ s2, float* __restrict__ out)
{
    long i = (long)blockIdx.x*256 + threadIdx.x;
    int col = (int)(i & 1023);
    long row = i >> 10;
    int b = (int)(row / S2_), s = (int)(row % S2_);
    const float* sb = s2 + (long)b * 6144;
    float gate; float* o;
    if (s < TEXT_)       { gate = sb[5120 + col]; o = out + O_E + ((long)b*TEXT_ + s)*DIM_ + col; }
    else if (s < S_MAIN) { gate = sb[2048 + col]; o = out + O_H + ((long)b*IMG_ + (s-TEXT_))*DIM_ + col; }
    else                 { gate = sb[5120 + col]; o = out + O_C + ((long)b*NC_ + (s-S_MAIN))*DIM_ + col; }
    *o = X[i] + gate * (f0[i] + f1[i] + fb2[col]);
}

extern "C" void kernel_launch(void* const* d_in, const int* in_sizes, int n_in,
                              void* d_out, int out_size, void* d_ws, size_t ws_size,
                              hipStream_t stream)
{
    (void)in_sizes; (void)n_in; (void)out_size; (void)ws_size;
    const float* h_in = (const float*)d_in[0];
    const float* e_in = (const float*)d_in[1];
    const float* c_in = (const float*)d_in[2];
    const float* temb = (const float*)d_in[3];
    const float* rcos = (const float*)d_in[4];
    const float* rsin = (const float*)d_in[5];
    const float* n1w  = (const float*)d_in[6];
    const float* n1b  = (const float*)d_in[7];
    const float* ln1w = (const float*)d_in[8];
    const float* ln1b = (const float*)d_in[9];
    const float* n2w  = (const float*)d_in[10];
    const float* n2b  = (const float*)d_in[11];
    const float* ln2w = (const float*)d_in[12];
    const float* ln2b = (const float*)d_in[13];
    const float* wq   = (const float*)d_in[14];
    const float* wk   = (const float*)d_in[15];
    const float* wv   = (const float*)d_in[16];
    const float* nqw  = (const float*)d_in[17];
    const float* nqb  = (const float*)d_in[18];
    const float* nkw  = (const float*)d_in[19];
    const float* nkb  = (const float*)d_in[20];
    const float* wo   = (const float*)d_in[21];
    const float* bo   = (const float*)d_in[22];
    const float* fw1  = (const float*)d_in[23];
    const float* fb1  = (const float*)d_in[24];
    const float* fw2  = (const float*)d_in[25];
    const float* fb2  = (const float*)d_in[26];

    float* ws  = (float*)d_ws;
    float* out = (float*)d_out;
    float* s1   = ws + OFF_S1;
    float* s2   = ws + OFF_S2;
    float* score  = ws + OFF_MISC;
    int*   selh   = (int*)(ws + OFF_MISC + 16);
    int*   selvis = (int*)(ws + OFF_MISC + 32);
    float* sim  = ws + OFF_SIM;
    float* imap = ws + OFF_IMAP;
    float* ac   = ws + OFF_AC;
    float* X    = ws + OFF_X;
    float* proj = ws + OFF_PROJ;
    float* xn   = ws + OFF_XN;
    float* qh   = ws + OFF_Q;
    float* kh   = ws + OFF_K;
    float* vh   = ws + OFF_V;
    float* ao   = ws + OFF_AO;
    float* ffo  = proj;
    float* fixp = ws + OFF_AO;             // fixup split-K partials (2 x 1536x1024)
    float* sp   = ws + OFF_X;              // silu partials (4 x 24576) [step1 -> step1b]
    unsigned short* xnb   = (unsigned short*)(ws + OFF_XNB);
    unsigned short* wqkvT = (unsigned short*)(ws + OFF_PROJ);
    unsigned short* vb    = (unsigned short*)(ws + OFF_PROJ);
    unsigned short* qbb   = (unsigned short*)(ws + OFF_X);
    unsigned short* kbb   = qbb + (size_t)B_*HEADS_*S2_*64;
    unsigned short* woT   = (unsigned short*)(ws + OFF_AO + 2000000);
    unsigned short* fw1T  = (unsigned short*)(ws + OFF_V);
    unsigned short* fw2T  = (unsigned short*)(ws + OFF_AO);
    unsigned short* ffh   = (unsigned short*)(ws + OFF_Q);
    // flash split-S partial overlays (dead regions during step 8):
    float* fp0 = vh;    // OFF_V: vh dead after k_vtrans; fw1T arrives step 13
    float* fp1 = xn;    // OFF_XN: xn dead after step 6; proj z1 arrives step 11
    float* fpl = sim;   // OFF_SIM: sim written at step 9 k_sim (after combine)

    // 1. adaLN modulation vectors (split-K x4 partials + reduce)
    hipLaunchKernelGGL(k_silu_mod, dim3(24, 2, 4), dim3(256), 0, stream, temb, n1w, n2w, sp);
    hipLaunchKernelGGL(k_silu_red, dim3(96), dim3(256), 0, stream, sp, n1b, n2b, s1, s2);
    // 2. QKV weight transposes (batched z=3)
    hipLaunchKernelGGL(k_tcvt_qkv, dim3(32, 32, 3), dim3(256), 0, stream, wq, wk, wv, wqkvT);
    // 3. norm1 + modulation -> xn fp32 + xnb bf16
    hipLaunchKernelGGL(k_ln_mod, dim3(ROWS_), dim3(256), 0, stream,
        e_in, (long)TEXT_*DIM_, h_in, (long)IMG_*DIM_, c_in, (long)NC_*DIM_, s1, ln1w, ln1b, xn, xnb);
    // 4. fused QKV bf16 GEMM, headed fp32 scatter
    hipLaunchKernelGGL(k_bgemm, dim3(24, 28, 1), dim3(256), 0, stream,
        xnb, wqkvT, (const float*)nullptr, (float*)nullptr, (unsigned short*)nullptr,
        ROWS_, 3072, 1024, 1024, 0, qh, kh, vh);
    // 5. fp32 q-fixup split-K x2 -> partials, then reduce into headed qh
    hipLaunchKernelGGL(k_gemm, dim3(16, 24, 2), dim3(256), 0, stream,
        xn + (long)(S2_ + TEXT_)*DIM_, wq, (float*)nullptr, IMG_, DIM_, DIM_, 512, 0, 0, fixp);
    hipLaunchKernelGGL(k_fixred, dim3(6144), dim3(256), 0, stream, fixp, qh);
    // 6. fp32 k-fixup (8 concept rows, batch 1) headed
    hipLaunchKernelGGL(k_gemm, dim3(16, 1, 1), dim3(256), 0, stream,
        xn + (long)(S2_ + S_MAIN)*DIM_, wk, kh, NC_, DIM_, DIM_, 1024, 1, S2_ + S_MAIN, (float*)nullptr);
    // 7. QK layernorm + RoPE; V transpose to bf16
    hipLaunchKernelGGL(k_qk_prep, dim3(14160, 2), dim3(256), 0, stream,
        qh, kh, qbb, kbb, nqw, nqb, nkw, nkb, rcos, rsin);
    hipLaunchKernelGGL(k_vtrans, dim3(56, 2, 32), dim3(256), 0, stream, vh, vb);
    // 8. attention: split-S x2, XCD-chunked (bx<28: main u=bx>>1/z=bx&1; bx 28,29: concept z)
    hipLaunchKernelGGL(k_flash, dim3(30, 16, 2), dim3(256), 0, stream,
        qbb, kbb, vb, fp0, fp1, fpl);
    // 8b. combine partials -> ao/ac + merged bf16 (fused old k_merge)
    hipLaunchKernelGGL(k_fcomb, dim3(14160), dim3(256), 0, stream, fp0, fp1, fpl, ao, ac, xnb);
    // 9. maps (batch 1)
    hipLaunchKernelGGL(k_head_score, dim3(16), dim3(256), 0, stream, ao, score);
    hipLaunchKernelGGL(k_top4, dim3(1), dim3(64), 0, stream, score, selh);
    hipLaunchKernelGGL(k_sim, dim3(512), dim3(512), 0, stream, qh, kh, sim, selvis);
    hipLaunchKernelGGL(k_cross, dim3(48), dim3(256), 0, stream, sim, out);
    hipLaunchKernelGGL(k_concept_maps, dim3(48), dim3(256), 0, stream, ac, ao, out);
    hipLaunchKernelGGL(k_imap_raw, dim3(512), dim3(384), 0, stream, ao, selvis, imap);
    hipLaunchKernelGGL(k_imap_norm, dim3(96), dim3(256), 0, stream, imap);
    hipLaunchKernelGGL(k_imap_reduce, dim3(48), dim3(256), 0, stream, imap, selh, out);
    // 10. wo transpose into dead ao region (merge now fused into fcomb)
    hipLaunchKernelGGL(k_tcvt, dim3(32, 32), dim3(256), 0, stream, wo, woT, 1024, 1024);
    // 11. wo GEMM split-K x2 (partials at PROJ / XN)
    hipLaunchKernelGGL(k_bgemm, dim3(8, 28, 2), dim3(256), 0, stream,
        xnb, woT, (const float*)nullptr, proj, (unsigned short*)nullptr, ROWS_, DIM_, 1024, 512, 1,
        (float*)nullptr, (float*)nullptr, (float*)nullptr);
    // 12. residual1 (fused reduce + bias) -> X
    hipLaunchKernelGGL(k_residual1, dim3(14160), dim3(256), 0, stream,
        e_in, h_in, c_in, proj, proj + (size_t)ROWS_*DIM_, bo, s1, X);
    // 13. FF weight transposes
    hipLaunchKernelGGL(k_tcvt, dim3(128, 32), dim3(256), 0, stream, fw1, fw1T, 1024, 4096);
    hipLaunchKernelGGL(k_tcvt, dim3(32, 128), dim3(256), 0, stream, fw2, fw2T, 4096, 1024);
    // 14. norm2 -> xnb bf16 only
    hipLaunchKernelGGL(k_ln_mod, dim3(ROWS_), dim3(256), 0, stream,
        X, (long)S2_*DIM_, X + (long)TEXT_*DIM_, (long)S2_*DIM_, X + (long)S_MAIN*DIM_, (long)S2_*DIM_,
        s2, ln2w, ln2b, (float*)nullptr, xnb);
    // 15. ff1 (gelu fused, bf16 out)
    hipLaunchKernelGGL(k_bgemm, dim3(32, 28, 1), dim3(256), 0, stream,
        xnb, fw1T, fb1, (float*)nullptr, ffh, ROWS_, FF_, 1024, 1024, 2,
        (float*)nullptr, (float*)nullptr, (float*)nullptr);
    // 16. ff2 split-K x2 (partials at PROJ / XN)
    hipLaunchKernelGGL(k_bgemm, dim3(8, 28, 2), dim3(256), 0, stream,
        ffh, fw2T, (const float*)nullptr, ffo, (unsigned short*)nullptr, ROWS_, DIM_, FF_, 2048, 1,
        (float*)nullptr, (float*)nullptr, (float*)nullptr);
    // 17. final (fused reduce + bias) -> outputs
    hipLaunchKernelGGL(k_final, dim3(14160), dim3(256), 0, stream,
        X, ffo, ffo + (size_t)ROWS_*DIM_, fb2, s2, out);
}

// Round 12
// 675.653 us; speedup vs baseline: 1.0796x; 1.0030x over previous
//
#include <hip/hip_runtime.h>
#include <hip/hip_bf16.h>
#include <math.h>

#define B_ 2
#define HEADS_ 16
#define HD_ 64
#define DIM_ 1024
#define TEXT_ 226
#define NC_ 8
#define FRAMES_ 4
#define PATCHES_ 384
#define IMG_ 1536
#define S_MAIN 1762
#define S2_ 1770
#define TD_ 512
#define FF_ 4096
#define ROWS_ (B_*S2_)   // 3540
#define VPAD_ 1792       // padded key dim for transposed V

// ---- workspace offsets (float slots) ----
#define OFF_S1   0L
#define OFF_S2   12288L
#define OFF_MISC 24576L
#define OFF_SIM  25600L
#define OFF_IMAP 222208L
#define OFF_AC   418816L
#define OFF_X    435200L
#define OFF_PROJ 4060160L
#define OFF_XN   7685120L
#define OFF_Q    11310080L
#define OFF_K    14935040L
#define OFF_V    18560000L
#define OFF_AO   22184960L
#define OFF_XNB  25809920L
// overlays (liveness-checked):
//   silu partials fp32 4x24576 @ OFF_X  [step1 -> step1b; qbb overwrites step7]
//   wqkvT bf16(3072x1024) @ OFF_PROJ   [step2 -> step4]
//   vb    bf16(B,H,64,1792) @ OFF_PROJ [step7b -> step8]
//   qb/kb bf16(B,H,S2,64) @ OFF_X      [step7 -> step8; X overwrites step12]
//   fixup partials fp32 2x(1536x1024) @ OFF_AO [step5 -> step5b; ao written step8b]
//   flash split-S partials: p0 fp32(2,16,1770,64) @ OFF_V  [step8 -> step8b; fw1T overwrites step13]
//                           p1 fp32(2,16,1770,64) @ OFF_XN [step8 -> step8b; proj z1 overwrites step11]
//                           pL fp32(2,2,16,1770)  @ OFF_SIM [step8 -> step8b; sim overwrites step9]
//   woT   bf16(1024x1024) @ OFF_AO+2e6 [step10.5 -> step11]
//   fw1T  bf16(4096x1024) @ OFF_V      [step13+]
//   fw2T  bf16(1024x4096) @ OFF_AO     [step13+]
//   ffh   bf16(3540x4096) @ OFF_Q      [step15+]
//   split-K partials: z0 @ OFF_PROJ, z1 @ OFF_XN (contiguous)

// ---- output offsets (floats) ----
#define O_H    0L
#define O_E    3145728L
#define O_C    3608576L
#define O_SELI 3624960L
#define O_ISUM 3637248L
#define O_CMAP 3649536L
#define O_XMAP 3661824L

// pbuf LDS stride (shorts): 72 -> 144B rows, 16B-aligned (b128 single-op).
// kt/vt: stride 64 (128B rows, linear — global_load_lds writes base+lane*16B)
// with PRE-SWIZZLED GLOBAL SOURCE: LDS slot (row r, chunk j) holds global
// chunk j^(r&7). Reads XOR the chunk index with (row&7): conflict-free
// (2 lanes/bank) and 16B-aligned on both sides.
#define PS_ 72

typedef __bf16 bf16x8_t __attribute__((ext_vector_type(8)));
typedef float  f32x4_t  __attribute__((ext_vector_type(4)));

__device__ __forceinline__ unsigned int pack2bf(float a, float b) {
    unsigned short ua = __builtin_bit_cast(unsigned short, (__bf16)a);
    unsigned short ub = __builtin_bit_cast(unsigned short, (__bf16)b);
    return (unsigned int)ua | ((unsigned int)ub << 16);
}

// async global->LDS 16B copy: per-lane global src, wave-uniform LDS base + lane*16
__device__ __forceinline__ void stage16(const unsigned short* g, unsigned short* l) {
    __builtin_amdgcn_global_load_lds(
        (const __attribute__((address_space(1))) unsigned int*)g,
        (__attribute__((address_space(3))) unsigned int*)l, 16, 0, 0);
}

// XCD-chunked bijective remap of a linear workgroup id (requires nwg % 8 == 0)
__device__ __forceinline__ int xcd_swz(int lin, int nwg) {
    if ((nwg & 7) == 0) { int q = nwg >> 3; lin = (lin & 7) * q + (lin >> 3); }
    return lin;
}

// silu(temb) @ norm_w partials. Grid (24, 2, 4): bx = 256-col chunk, by = which
// (w1/w2), bz = k-chunk of 128. Both batches computed in ONE pass over the
// weights (each weight element read exactly once, float4 / 1KB-per-wave
// coalesced). Per-block k-sub x4 LDS reduce; partials at part + bz*24576.
__global__ __launch_bounds__(256) void k_silu_mod(
    const float* __restrict__ temb, const float* __restrict__ w1,
    const float* __restrict__ w2, float* __restrict__ part)
{
    int bx = blockIdx.x, which = blockIdx.y, kz = blockIdx.z;
    const float* w = which ? w2 : w1;
    int tid = threadIdx.x;
    __shared__ float sv[2][512];
    for (int i = tid; i < 1024; i += 256) {
        int b = i >> 9, k = i & 511;
        float tv = temb[b*TD_ + k];
        sv[b][k] = tv / (1.f + __expf(-tv));
    }
    __syncthreads();
    int n4 = tid & 63;        // float4 column within chunk (wave-contiguous)
    int ksub = tid >> 6;      // 0..3
    int ncol = bx*256 + n4*4;
    int k0 = kz*128 + ksub*32;
    float a0x=0.f,a0y=0.f,a0z=0.f,a0w=0.f, a1x=0.f,a1y=0.f,a1z=0.f,a1w=0.f;
    for (int k = k0; k < k0 + 32; ++k) {
        float4 wv = *(const float4*)(w + (size_t)k*6144 + ncol);
        float s0 = sv[0][k], s1 = sv[1][k];
        a0x += s0*wv.x; a0y += s0*wv.y; a0z += s0*wv.z; a0w += s0*wv.w;
        a1x += s1*wv.x; a1y += s1*wv.y; a1z += s1*wv.z; a1w += s1*wv.w;
    }
    __shared__ float red[2][256][4];
    red[0][tid][0]=a0x; red[0][tid][1]=a0y; red[0][tid][2]=a0z; red[0][tid][3]=a0w;
    red[1][tid][0]=a1x; red[1][tid][1]=a1y; red[1][tid][2]=a1z; red[1][tid][3]=a1w;
    __syncthreads();
    if (ksub == 0) {
        #pragma unroll
        for (int s = 1; s < 4; ++s) {
            a0x += red[0][tid+64*s][0]; a0y += red[0][tid+64*s][1];
            a0z += red[0][tid+64*s][2]; a0w += red[0][tid+64*s][3];
            a1x += red[1][tid+64*s][0]; a1y += red[1][tid+64*s][1];
            a1z += red[1][tid+64*s][2]; a1w += red[1][tid+64*s][3];
        }
        long base = (long)kz*24576 + (long)which*12288;
        *(float4*)(part + base + ncol)        = make_float4(a0x,a0y,a0z,a0w);
        *(float4*)(part + base + 6144 + ncol) = make_float4(a1x,a1y,a1z,a1w);
    }
}

// reduce 4 k-partials + bias -> s1/s2
__global__ __launch_bounds__(256) void k_silu_red(
    const float* __restrict__ part, const float* __restrict__ b1,
    const float* __restrict__ b2, float* __restrict__ s1, float* __restrict__ s2)
{
    int i = blockIdx.x*256 + threadIdx.x;   // < 24576
    float v = part[i] + part[i+24576] + part[i+49152] + part[i+73728];
    int which = i / 12288, r = i % 12288, n = r % 6144;
    v += (which ? b2 : b1)[n];
    (which ? s2 : s1)[r] = v;
}

// transpose + convert: src (K,N) fp32 -> dst (N,K) bf16
__global__ __launch_bounds__(256) void k_tcvt(
    const float* __restrict__ src, unsigned short* __restrict__ dst, int K, int N)
{
    __shared__ float t[32][33];
    int n0 = blockIdx.x * 32, k0 = blockIdx.y * 32;
    int tx = threadIdx.x & 31, ty = threadIdx.x >> 5;
    #pragma unroll
    for (int i = 0; i < 4; ++i)
        t[ty + 8*i][tx] = src[(size_t)(k0 + ty + 8*i) * N + n0 + tx];
    __syncthreads();
    #pragma unroll
    for (int i = 0; i < 4; ++i) {
        float v = t[tx][ty + 8*i];
        dst[(size_t)(n0 + ty + 8*i) * K + k0 + tx] =
            __builtin_bit_cast(unsigned short, (__bf16)v);
    }
}

// batched QKV transpose (z selects wq/wk/wv), 1024x1024 each
__global__ __launch_bounds__(256) void k_tcvt_qkv(
    const float* __restrict__ wq, const float* __restrict__ wk, const float* __restrict__ wv,
    unsigned short* __restrict__ dst)
{
    const float* src = (blockIdx.z == 0) ? wq : (blockIdx.z == 1) ? wk : wv;
    unsigned short* d = dst + (size_t)blockIdx.z * 1024 * 1024;
    __shared__ float t[32][33];
    int n0 = blockIdx.x * 32, k0 = blockIdx.y * 32;
    int tx = threadIdx.x & 31, ty = threadIdx.x >> 5;
    #pragma unroll
    for (int i = 0; i < 4; ++i)
        t[ty + 8*i][tx] = src[(size_t)(k0 + ty + 8*i) * 1024 + n0 + tx];
    __syncthreads();
    #pragma unroll
    for (int i = 0; i < 4; ++i) {
        float v = t[tx][ty + 8*i];
        d[(size_t)(n0 + ty + 8*i) * 1024 + k0 + tx] =
            __builtin_bit_cast(unsigned short, (__bf16)v);
    }
}

// V (B,H,S2,64) fp32 -> vb (B,H,64,VPAD) bf16 transposed
__global__ __launch_bounds__(256) void k_vtrans(
    const float* __restrict__ vh, unsigned short* __restrict__ vb)
{
    int bh = blockIdx.z;
    int d0 = blockIdx.y * 32;
    int s0 = blockIdx.x * 32;
    __shared__ float t[32][33];
    int tx = threadIdx.x & 31, ty = threadIdx.x >> 5;
    const float* src = vh + (size_t)bh * S2_ * 64;
    #pragma unroll
    for (int i = 0; i < 4; ++i) {
        int s = s0 + ty + 8*i; if (s >= S2_) s = S2_ - 1;
        t[ty + 8*i][tx] = src[(size_t)s*64 + d0 + tx];
    }
    __syncthreads();
    unsigned short* dst = vb + (size_t)bh * 64 * VPAD_;
    #pragma unroll
    for (int i = 0; i < 4; ++i) {
        int d = d0 + ty + 8*i;
        dst[(size_t)d * VPAD_ + s0 + tx] =
            __builtin_bit_cast(unsigned short, (__bf16)t[tx][ty + 8*i]);
    }
}

// fused layernorm + adaLN modulation -> optional fp32 out AND bf16 outb
__global__ __launch_bounds__(256) void k_ln_mod(
    const float* pe, long bse, const float* ph, long bsh, const float* pc, long bsc,
    const float* __restrict__ smod, const float* __restrict__ lnw, const float* __restrict__ lnb,
    float* __restrict__ out, unsigned short* __restrict__ outb)
{
    long row = blockIdx.x;
    int b = (int)(row / S2_), s = (int)(row % S2_);
    const float* src; int shiftB, scaleB;
    if (s < TEXT_)       { src = pe + (long)b*bse + (long)s*DIM_;          shiftB = 3072; scaleB = 4096; }
    else if (s < S_MAIN) { src = ph + (long)b*bsh + (long)(s-TEXT_)*DIM_;  shiftB = 0;    scaleB = 1024; }
    else                 { src = pc + (long)b*bsc + (long)(s-S_MAIN)*DIM_; shiftB = 3072; scaleB = 4096; }
    int tid = threadIdx.x;
    int col = tid * 4;
    float4 x = *(const float4*)(src + col);
    float lsum = x.x + x.y + x.z + x.w;
    float lsq  = x.x*x.x + x.y*x.y + x.z*x.z + x.w*x.w;
    __shared__ float r1[256], r2[256];
    r1[tid] = lsum; r2[tid] = lsq; __syncthreads();
    for (int st = 128; st; st >>= 1) {
        if (tid < st) { r1[tid] += r1[tid+st]; r2[tid] += r2[tid+st]; }
        __syncthreads();
    }
    float mu = r1[0] * (1.f / DIM_);
    float var = r2[0] * (1.f / DIM_) - mu * mu;
    float rstd = rsqrtf(var + 1e-5f);
    const float* sb = smod + (long)b * 6144;
    float xs[4] = {x.x, x.y, x.z, x.w};
    float res[4];
    #pragma unroll
    for (int i = 0; i < 4; ++i) {
        int cc = col + i;
        float yy = (xs[i] - mu) * rstd * lnw[cc] + lnb[cc];
        res[i] = yy * (1.f + sb[scaleB + cc]) + sb[shiftB + cc];
    }
    if (out)
        *(float4*)(out + row * DIM_ + col) = make_float4(res[0], res[1], res[2], res[3]);
    uint2 pk;
    pk.x = pack2bf(res[0], res[1]); pk.y = pack2bf(res[2], res[3]);
    *(uint2*)(outb + row * DIM_ + col) = pk;
}

// bf16 MFMA GEMM, double-buffered LDS staged via global_load_lds (16B, async),
// optional split-K via gridDim.z. Linear LDS [128][32] per tile (no pad).
// XCD-chunked tile remap for L2 locality.
__global__ __launch_bounds__(256, 4) void k_bgemm(
    const unsigned short* __restrict__ A, const unsigned short* __restrict__ Wt,
    const float* __restrict__ bias, float* __restrict__ out_f,
    unsigned short* __restrict__ out_b, int M, int N, int K, int kz_len, int mode,
    float* __restrict__ q_out, float* __restrict__ k_out, float* __restrict__ v_out)
{
    __shared__ unsigned short at[2][128*32];
    __shared__ unsigned short bt[2][128*32];
    int tid = threadIdx.x;
    int w = tid >> 6, lane = tid & 63;
    int lr = lane & 15, lh = lane >> 4;
    int wm = w >> 1, wn = w & 1;
    int gx = gridDim.x;
    int lin = xcd_swz(blockIdx.y * gx + blockIdx.x, gx * gridDim.y);
    int m0 = (lin / gx) * 128, n0 = (lin % gx) * 128;
    int kbeg = blockIdx.z * kz_len, kend = kbeg + kz_len;

    f32x4_t acc[4][4];
    #pragma unroll
    for (int i = 0; i < 4; ++i)
        #pragma unroll
        for (int j = 0; j < 4; ++j) { acc[i][j][0]=0.f; acc[i][j][1]=0.f; acc[i][j][2]=0.f; acc[i][j][3]=0.f; }

    // staging geometry: issue i (0,1) covers rows i*64 + (tid>>2), 16B chunk (tid&3)
    int r4 = tid >> 2, c4 = tid & 3;
    int arow0 = m0 + r4;      if (arow0 >= M) arow0 = M - 1;
    int arow1 = m0 + 64 + r4; if (arow1 >= M) arow1 = M - 1;
    const unsigned short* ga0 = A + (size_t)arow0 * K + c4 * 8;
    const unsigned short* ga1 = A + (size_t)arow1 * K + c4 * 8;
    const unsigned short* gb0 = Wt + (size_t)(n0 + r4) * K + c4 * 8;
    const unsigned short* gb1 = Wt + (size_t)(n0 + 64 + r4) * K + c4 * 8;
    int lbase = w * 512;   // shorts; wave-uniform; HW adds lane*16B

    // prologue: stage buf 0
    stage16(ga0 + kbeg, &at[0][lbase]);
    stage16(ga1 + kbeg, &at[0][lbase + 2048]);
    stage16(gb0 + kbeg, &bt[0][lbase]);
    stage16(gb1 + kbeg, &bt[0][lbase + 2048]);
    __syncthreads();
    int buf = 0;
    for (int k0 = kbeg; k0 < kend; k0 += 32) {
        bool more = (k0 + 32) < kend;
        if (more) {
            int nb = buf ^ 1;
            stage16(ga0 + k0 + 32, &at[nb][lbase]);
            stage16(ga1 + k0 + 32, &at[nb][lbase + 2048]);
            stage16(gb0 + k0 + 32, &bt[nb][lbase]);
            stage16(gb1 + k0 + 32, &bt[nb][lbase + 2048]);
        }
        int4 af[4], bf[4];
        #pragma unroll
        for (int tm = 0; tm < 4; ++tm)
            af[tm] = *(const int4*)&at[buf][(wm*64 + tm*16 + lr)*32 + lh*8];
        #pragma unroll
        for (int tn = 0; tn < 4; ++tn)
            bf[tn] = *(const int4*)&bt[buf][(wn*64 + tn*16 + lr)*32 + lh*8];
        #pragma unroll
        for (int tm = 0; tm < 4; ++tm) {
            bf16x8_t av = __builtin_bit_cast(bf16x8_t, af[tm]);
            #pragma unroll
            for (int tn = 0; tn < 4; ++tn)
                acc[tm][tn] = __builtin_amdgcn_mfma_f32_16x16x32_bf16(
                    av, __builtin_bit_cast(bf16x8_t, bf[tn]), acc[tm][tn], 0, 0, 0);
        }
        __syncthreads();
        buf ^= 1;
    }
    float* of = out_f;
    if (mode == 1) of += (size_t)blockIdx.z * M * N;
    #pragma unroll
    for (int tm = 0; tm < 4; ++tm) {
        #pragma unroll
        for (int r = 0; r < 4; ++r) {
            int m = m0 + wm*64 + tm*16 + lh*4 + r;
            if (m >= M) continue;
            int b = m / S2_, s = m % S2_;
            #pragma unroll
            for (int tn = 0; tn < 4; ++tn) {
                int n = n0 + wn*64 + tn*16 + lr;
                float v = acc[tm][tn][r];
                if (mode == 0) {
                    int which = n >> 10, c = n & 1023;
                    int hh = c >> 6, d = c & 63;
                    float* dstp = (which == 0) ? q_out : (which == 1) ? k_out : v_out;
                    dstp[(((size_t)b*HEADS_ + hh)*S2_ + s)*64 + d] = v;
                } else if (mode == 1) {
                    of[(size_t)m * N + n] = v + (bias ? bias[n] : 0.f);
                } else {
                    float x = v + bias[n];
                    float u = 0.7978845608028654f * (x + 0.044715f*x*x*x);
                    float g = x / (1.f + __expf(-2.f*u));
                    out_b[(size_t)m * N + n] = __builtin_bit_cast(unsigned short, (__bf16)g);
                }
            }
        }
    }
}

// fp32 tiled GEMM (argmax fixups). If part != nullptr: write plain partial at
// part + z*M*N (split-K, K range [z*kz, (z+1)*kz)). Else headed/plain store.
__global__ __launch_bounds__(256) void k_gemm(
    const float* __restrict__ A, const float* __restrict__ W,
    float* __restrict__ C, int M, int N, int K, int kz_len, int headed, int row_off,
    float* __restrict__ part)
{
    __shared__ float As[16][68];
    __shared__ float Bs[16][68];
    int tid = threadIdx.x;
    int gx = gridDim.x;
    int lin = xcd_swz(blockIdx.y * gx + blockIdx.x, gx * gridDim.y);
    int bm = (lin / gx) * 64, bn = (lin % gx) * 64;
    int tr = tid >> 4, tc = tid & 15;
    int ar = tid >> 2, akk = (tid & 3) * 4;
    int bkk = tid >> 4, bn4 = (tid & 15) * 4;
    float acc[4][4] = {{0.f}};
    int garow = bm + ar;
    const float* Aptr = A + (size_t)garow * K + akk;
    const float* Wptr = W + (size_t)bkk * N + bn + bn4;
    int kbeg = blockIdx.z * kz_len;
    for (int k0 = kbeg; k0 < kbeg + kz_len; k0 += 16) {
        float4 av = make_float4(0.f, 0.f, 0.f, 0.f);
        if (garow < M) av = *(const float4*)(Aptr + k0);
        As[akk+0][ar] = av.x; As[akk+1][ar] = av.y; As[akk+2][ar] = av.z; As[akk+3][ar] = av.w;
        float4 bv = *(const float4*)(Wptr + (size_t)k0 * N);
        Bs[bkk][bn4+0] = bv.x; Bs[bkk][bn4+1] = bv.y; Bs[bkk][bn4+2] = bv.z; Bs[bkk][bn4+3] = bv.w;
        __syncthreads();
        #pragma unroll
        for (int kk = 0; kk < 16; ++kk) {
            float4 a = *(const float4*)&As[kk][tr*4];
            float4 bq = *(const float4*)&Bs[kk][tc*4];
            float avv[4] = {a.x, a.y, a.z, a.w};
            float bvv[4] = {bq.x, bq.y, bq.z, bq.w};
            #pragma unroll
            for (int i = 0; i < 4; ++i)
                #pragma unroll
                for (int j = 0; j < 4; ++j)
                    acc[i][j] += avv[i] * bvv[j];
        }
        __syncthreads();
    }
    #pragma unroll
    for (int i = 0; i < 4; ++i) {
        int r = bm + tr*4 + i;
        if (r >= M) continue;
        #pragma unroll
        for (int j = 0; j < 4; ++j) {
            int n = bn + tc*4 + j;
            float v = acc[i][j];
            if (part) {
                part[(size_t)blockIdx.z*M*N + (size_t)r*N + n] = v;
            } else if (headed) {
                int rg = r + row_off;
                int b = rg / S2_, s = rg % S2_;
                int hh = n >> 6, d = n & 63;
                C[(((size_t)b*HEADS_ + hh)*S2_ + s)*64 + d] = v;
            } else {
                C[(size_t)(r + row_off) * N + n] = v;
            }
        }
    }
}

// sum 2 fixup partials -> headed fp32 store into qh (batch1 img rows), float4
__global__ __launch_bounds__(256) void k_fixred(
    const float* __restrict__ pa, float* __restrict__ qh_out)
{
    long i = ((long)blockIdx.x*256 + threadIdx.x) * 4;   // < 1536*1024
    int r = (int)(i >> 10), n = (int)(i & 1023);
    float4 a = *(const float4*)(pa + i);
    float4 b = *(const float4*)(pa + i + (long)IMG_*DIM_);
    int hh = n >> 6, d = n & 63;
    *(float4*)(qh_out + (((size_t)HEADS_ + hh)*S2_ + TEXT_ + r)*64 + d) =
        make_float4(a.x + b.x, a.y + b.y, a.z + b.z, a.w + b.w);
}

// per-head layernorm + RoPE: bf16 everywhere; fp32 write-back only for argmax rows
__global__ __launch_bounds__(256) void k_qk_prep(
    float* qh, float* kh, unsigned short* qbb, unsigned short* kbb,
    const float* __restrict__ nqw, const float* __restrict__ nqb,
    const float* __restrict__ nkw, const float* __restrict__ nkb,
    const float* __restrict__ rc, const float* __restrict__ rs)
{
    int which = blockIdx.y;
    int wid = threadIdx.x >> 6;
    int lane = threadIdx.x & 63;
    long row = (long)blockIdx.x * 4 + wid;   // (b*16+h)*S2 + s
    long s = row % S2_;
    bool b1 = row >= (long)HEADS_*S2_;
    float* base = (which ? kh : qh) + row * 64;
    const float* w  = which ? nkw : nqw;
    const float* bb = which ? nkb : nqb;
    float x = base[lane];
    float sum = x;
    for (int off = 1; off < 64; off <<= 1) sum += __shfl_xor(sum, off, 64);
    float mu = sum * (1.f / 64.f);
    float dx = x - mu;
    float v = dx * dx;
    for (int off = 1; off < 64; off <<= 1) v += __shfl_xor(v, off, 64);
    float rstd = rsqrtf(v * (1.f / 64.f) + 1e-6f);
    float y = dx * rstd * w[lane] + bb[lane];
    if (s >= TEXT_ && s < S_MAIN) {
        long p = s - TEXT_;
        float part = __shfl_xor(y, 1, 64);
        float rot = (lane & 1) ? part : -part;
        y = y * rc[p*64 + lane] + rot * rs[p*64 + lane];
    }
    bool needf = b1 && (which ? (s >= S_MAIN) : (s >= TEXT_ && s < S_MAIN));
    if (needf) base[lane] = y;
    (which ? kbb : qbb)[row * 64 + lane] = __builtin_bit_cast(unsigned short, (__bf16)y);
}

// MFMA flash attention with 2-way KV split (split-S). 128-q blocks, 4 waves.
// No-max softmax makes the split exactly associative: each split writes
// unnormalized O and L partials; k_fcomb does (O0+O1)/(L0+L1).
// K/V staged via global_load_lds: linear LDS dest (stride-64 rows, the exact
// wave-uniform+lane*16B layout the DMA writes) + pre-swizzled global source
// (content chunk j^(slot_row&7)); reads XOR the chunk with (row&7) ->
// conflict-free, 16B-aligned, no VGPR round-trip. Full-tile fast path skips
// the tail mask (only ~1 in 14 tiles is partial).
// XCD-chunked remap over the full 960-block grid (4 KV sets per XCD ~1.8MB L2).
__global__ __launch_bounds__(256) void k_flash(
    const unsigned short* __restrict__ qb, const unsigned short* __restrict__ kb,
    const unsigned short* __restrict__ vb,
    float* __restrict__ p0, float* __restrict__ p1, float* __restrict__ pl)
{
    int lin3 = (blockIdx.z * gridDim.y + blockIdx.y) * gridDim.x + blockIdx.x;
    lin3 = xcd_swz(lin3, gridDim.x * gridDim.y * gridDim.z);
    int bx = lin3 % 30;
    int rest = lin3 / 30;
    int h = rest & 15, b = rest >> 4;
    int qt, NQ, q_off, r0s, r0e, r1s, r1e, z;
    if (bx < 28) {
        z = bx & 1; int u = bx >> 1;
        qt = u*128; NQ = S_MAIN; q_off = 0;
        r0s = z ? 896 : 0; r0e = z ? S_MAIN : 896;
        r1s = 0; r1e = 0;
    } else {
        z = bx - 28;
        qt = 0; NQ = NC_; q_off = S_MAIN;
        if (z == 0) { r0s = S_MAIN;      r0e = S2_;    r1s = TEXT_; r1e = TEXT_ + 768; }
        else        { r0s = TEXT_ + 768; r0e = S_MAIN; r1s = 0;     r1e = 0; }
    }
    float* po = z ? p1 : p0;
    int tid = threadIdx.x;
    int w = tid >> 6, lane = tid & 63;
    int lr = lane & 15, lh = lane >> 4;
    int s7 = lr & 7;   // row&7 for all fragment rows 16g+lr
    __shared__ __align__(16) unsigned short kt[64*64];
    __shared__ __align__(16) unsigned short vt[64*64];
    __shared__ __align__(16) unsigned short pbuf[4*32*PS_];
    unsigned short* pw = pbuf + w*32*PS_;
    const unsigned short* qbase = qb + (((size_t)b*HEADS_ + h)*S2_ + q_off)*64;
    const unsigned short* kbase = kb + ((size_t)b*HEADS_ + h)*S2_*64;
    const unsigned short* vbase = vb + (size_t)(b*HEADS_ + h)*64*VPAD_;
    // staging geometry (per issue i=0,1): idx = tid + i*256; slot row idx>>3,
    // chunk idx&7; LDS dest is linear idx*16B (wave-uniform base + lane*16B);
    // global src chunk = (idx&7) ^ (slot_row & 7). srow1&7 == srow0&7.
    int srow0 = tid >> 3, schunk = tid & 7;
    int srow1 = srow0 + 32;
    int sc0 = (schunk ^ (srow0 & 7)) << 3;
    int ldst0 = (w * 64) * 8;                // shorts; wave-uniform
    int ldst1 = (256 + w * 64) * 8;
    bf16x8_t aq[2][2];
    #pragma unroll
    for (int t = 0; t < 2; ++t) {
        int qrow = qt + w*32 + t*16 + lr; if (qrow >= NQ) qrow = NQ - 1;
        const unsigned short* qsrc = qbase + (size_t)qrow*64 + lh*8;
        aq[t][0] = __builtin_bit_cast(bf16x8_t, *(const int4*)qsrc);
        aq[t][1] = __builtin_bit_cast(bf16x8_t, *(const int4*)(qsrc + 32));
    }
    int4 onesi = make_int4(0x3F803F80, 0x3F803F80, 0x3F803F80, 0x3F803F80);
    bf16x8_t bones = __builtin_bit_cast(bf16x8_t, onesi);
    f32x4_t O[2][4];
    f32x4_t Lacc[2];
    #pragma unroll
    for (int t = 0; t < 2; ++t) {
        Lacc[t][0]=0.f; Lacc[t][1]=0.f; Lacc[t][2]=0.f; Lacc[t][3]=0.f;
        #pragma unroll
        for (int g = 0; g < 4; ++g) { O[t][g][0]=0.f; O[t][g][1]=0.f; O[t][g][2]=0.f; O[t][g][3]=0.f; }
    }
    for (int rgi = 0; rgi < 2; ++rgi) {
        int rs = rgi ? r1s : r0s, re = rgi ? r1e : r0e;
        for (int j0 = rs; j0 < re; j0 += 64) {
            int cnt = min(64, re - j0);
            __syncthreads();
            {
                int kr0 = j0 + srow0; if (kr0 > re - 1) kr0 = re - 1;
                int kr1 = j0 + srow1; if (kr1 > re - 1) kr1 = re - 1;
                stage16(kbase + (size_t)kr0*64 + sc0, &kt[ldst0]);
                stage16(kbase + (size_t)kr1*64 + sc0, &kt[ldst1]);
                stage16(vbase + (size_t)srow0*VPAD_ + j0 + sc0, &vt[ldst0]);
                stage16(vbase + (size_t)srow1*VPAD_ + j0 + sc0, &vt[ldst1]);
            }
            __syncthreads();
            f32x4_t S[2][4];
            #pragma unroll
            for (int g = 0; g < 4; ++g) {
                const unsigned short* kr = &kt[(16*g + lr)*64];
                bf16x8_t b0 = __builtin_bit_cast(bf16x8_t, *(const int4*)(kr + ((lh ^ s7) << 3)));
                bf16x8_t b1 = __builtin_bit_cast(bf16x8_t, *(const int4*)(kr + (((lh + 4) ^ s7) << 3)));
                #pragma unroll
                for (int t = 0; t < 2; ++t) {
                    f32x4_t zz; zz[0]=0.f; zz[1]=0.f; zz[2]=0.f; zz[3]=0.f;
                    zz = __builtin_amdgcn_mfma_f32_16x16x32_bf16(aq[t][0], b0, zz, 0, 0, 0);
                    zz = __builtin_amdgcn_mfma_f32_16x16x32_bf16(aq[t][1], b1, zz, 0, 0, 0);
                    S[t][g] = zz;
                }
            }
            if (cnt == 64) {
                #pragma unroll
                for (int t = 0; t < 2; ++t)
                    #pragma unroll
                    for (int g = 0; g < 4; ++g)
                        #pragma unroll
                        for (int r = 0; r < 4; ++r) {
                            float p = __expf(S[t][g][r] * 0.125f);
                            pw[(t*16 + lh*4 + r)*PS_ + 16*g + lr] = __builtin_bit_cast(unsigned short, (__bf16)p);
                        }
            } else {
                #pragma unroll
                for (int t = 0; t < 2; ++t)
                    #pragma unroll
                    for (int g = 0; g < 4; ++g) {
                        bool vld = (16*g + lr) < cnt;
                        #pragma unroll
                        for (int r = 0; r < 4; ++r) {
                            float p = vld ? __expf(S[t][g][r] * 0.125f) : 0.f;
                            pw[(t*16 + lh*4 + r)*PS_ + 16*g + lr] = __builtin_bit_cast(unsigned short, (__bf16)p);
                        }
                    }
            }
            #pragma unroll
            for (int c = 0; c < 2; ++c) {
                bf16x8_t ap[2];
                #pragma unroll
                for (int t = 0; t < 2; ++t) {
                    ap[t] = __builtin_bit_cast(bf16x8_t,
                        *(const int4*)&pw[(t*16 + lr)*PS_ + c*32 + lh*8]);
                    Lacc[t] = __builtin_amdgcn_mfma_f32_16x16x32_bf16(ap[t], bones, Lacc[t], 0, 0, 0);
                }
                #pragma unroll
                for (int g = 0; g < 4; ++g) {
                    const unsigned short* vr = &vt[(16*g + lr)*64];
                    bf16x8_t bv = __builtin_bit_cast(bf16x8_t,
                        *(const int4*)(vr + (((c*4 + lh) ^ s7) << 3)));
                    #pragma unroll
                    for (int t = 0; t < 2; ++t)
                        O[t][g] = __builtin_amdgcn_mfma_f32_16x16x32_bf16(ap[t], bv, O[t][g], 0, 0, 0);
                }
            }
        }
    }
    #pragma unroll
    for (int t = 0; t < 2; ++t)
        #pragma unroll
        for (int r = 0; r < 4; ++r) {
            int gq = qt + w*32 + t*16 + lh*4 + r;
            if (gq < NQ) {
                long rrow = (long)(b*HEADS_ + h)*S2_ + q_off + gq;
                float* o = po + rrow*64 + lr;
                #pragma unroll
                for (int g = 0; g < 4; ++g) o[16*g] = O[t][g][r];
                if (lr == 0) pl[(long)z*(B_*HEADS_*S2_) + rrow] = Lacc[t][r];
            }
        }
}

// combine split-S partials (float4): ao/ac = (p0+p1)/(l0+l1); also emit merged
// bf16 row layout (fuses the old k_merge): xo[(b*S2+s)*1024 + h*64+d]
__global__ __launch_bounds__(256) void k_fcomb(
    const float* __restrict__ p0, const float* __restrict__ p1,
    const float* __restrict__ pl,
    float* __restrict__ ao, float* __restrict__ ac, unsigned short* __restrict__ xo)
{
    long i = ((long)blockIdx.x*256 + threadIdx.x) * 4;   // < 2*16*1770*64
    int d = (int)(i & 63);
    long rrow = i >> 6;                                   // (b*16+h)*S2 + s
    int s = (int)(rrow % S2_);
    int bh = (int)(rrow / S2_);
    int b = bh >> 4, h = bh & 15;
    float l = pl[rrow] + pl[rrow + (long)B_*HEADS_*S2_];
    float4 a = *(const float4*)(p0 + i);
    float4 c = *(const float4*)(p1 + i);
    float4 v = make_float4((a.x+c.x)/l, (a.y+c.y)/l, (a.z+c.z)/l, (a.w+c.w)/l);
    if (s < S_MAIN) *(float4*)(ao + ((long)bh*S_MAIN + s)*64 + d) = v;
    else            *(float4*)(ac + ((long)bh*NC_ + (s - S_MAIN))*64 + d) = v;
    uint2 pk; pk.x = pack2bf(v.x, v.y); pk.y = pack2bf(v.z, v.w);
    *(uint2*)(xo + ((long)b*S2_ + s)*DIM_ + h*64 + d) = pk;
}

__global__ __launch_bounds__(256) void k_head_score(const float* __restrict__ ao, float* __restrict__ score)
{
    int h = blockIdx.x, tid = threadIdx.x;
    const float* base = ao + (((long)HEADS_ + h)*S_MAIN + TEXT_)*64;
    float sA = 0.f, sB = 0.f;
    for (int p = tid; p < IMG_; p += 256) {
        const float* r = base + (long)p*64;
        float mm = 0.f;
        for (int d = 0; d < 64; d += 4) {
            float4 v = *(const float4*)(r + d);
            mm += v.x + v.y + v.z + v.w;
        }
        mm *= (1.f / 64.f);
        sA += mm; sB += mm*mm;
    }
    __shared__ float r1[256], r2[256];
    r1[tid] = sA; r2[tid] = sB; __syncthreads();
    for (int st = 128; st; st >>= 1) {
        if (tid < st) { r1[tid] += r1[tid+st]; r2[tid] += r2[tid+st]; }
        __syncthreads();
    }
    if (tid == 0) {
        float mean = r1[0] / IMG_, ms = r2[0] / IMG_;
        score[h] = sqrtf(fmaxf(ms - mean*mean, 0.f));
    }
}

__global__ void k_top4(const float* __restrict__ score, int* __restrict__ sel)
{
    if (threadIdx.x == 0 && blockIdx.x == 0) {
        int used = 0;
        for (int k = 0; k < 4; ++k) {
            float best = -INFINITY; int bi = 0;
            for (int h2 = 0; h2 < 16; ++h2) {
                if (used & (1 << h2)) continue;
                if (score[h2] > best) { best = score[h2]; bi = h2; }
            }
            used |= 1 << bi; sel[k] = bi;
        }
    }
}

__global__ __launch_bounds__(512) void k_sim(
    const float* __restrict__ qh, const float* __restrict__ kh,
    float* __restrict__ sim, int* __restrict__ selvis)
{
    int blk = blockIdx.x;    // (h*8+t)*4+f
    int h = blk >> 5, t = (blk >> 2) & 7, f = blk & 3;
    int tid = threadIdx.x;
    __shared__ float ckv[64];
    if (tid < 64) ckv[tid] = kh[(((long)HEADS_ + h)*S2_ + S_MAIN + t)*64 + tid];
    __syncthreads();
    float val = -INFINITY; int idx = 0x7fffffff;
    if (tid < PATCHES_) {
        const float* qrow = qh + (((long)HEADS_ + h)*S2_ + TEXT_ + f*PATCHES_ + tid)*64;
        float acc = 0.f;
        for (int d = 0; d < 64; d += 4) {
            float4 qv = *(const float4*)(qrow + d);
            acc += qv.x*ckv[d] + qv.y*ckv[d+1] + qv.z*ckv[d+2] + qv.w*ckv[d+3];
        }
        sim[((long)h*NC_ + t)*IMG_ + f*PATCHES_ + tid] = acc;
        val = acc; idx = tid;
    }
    __shared__ float sv[512]; __shared__ int si[512];
    sv[tid] = val; si[tid] = idx; __syncthreads();
    for (int st = 256; st; st >>= 1) {
        if (tid < st) {
            float v2 = sv[tid+st]; int i2 = si[tid+st];
            if (v2 > sv[tid] || (v2 == sv[tid] && i2 < si[tid])) { sv[tid] = v2; si[tid] = i2; }
        }
        __syncthreads();
    }
    if (tid == 0) selvis[blk] = si[0];
}

__global__ __launch_bounds__(256) void k_cross(const float* __restrict__ sim, float* __restrict__ out)
{
    int i = (blockIdx.x*256 + threadIdx.x) * 4;   // < 12288
    int c = i / IMG_, p = i % IMG_;
    float4 acc = make_float4(0.f, 0.f, 0.f, 0.f);
    for (int h = 0; h < 16; ++h) {
        float4 v = *(const float4*)(sim + ((long)h*NC_ + c)*IMG_ + p);
        acc.x += v.x; acc.y += v.y; acc.z += v.z; acc.w += v.w;
    }
    *(float4*)(out + O_XMAP + i) = make_float4(acc.x*(1.f/16.f), acc.y*(1.f/16.f),
                                               acc.z*(1.f/16.f), acc.w*(1.f/16.f));
}

__global__ __launch_bounds__(256) void k_concept_maps(
    const float* __restrict__ ac, const float* __restrict__ ao, float* __restrict__ out)
{
    int i = blockIdx.x*256 + threadIdx.x;   // < 12288
    int c = i / IMG_, p = i % IMG_;
    float acc = 0.f;
    for (int h = 0; h < 16; ++h) {
        const float* a = ac + (((long)HEADS_ + h)*NC_ + c)*64;
        const float* g = ao + (((long)HEADS_ + h)*S_MAIN + TEXT_ + p)*64;
        for (int d = 0; d < 64; d += 4) {
            float4 av = *(const float4*)(a + d);
            float4 gv = *(const float4*)(g + d);
            acc += av.x*gv.x + av.y*gv.y + av.z*gv.z + av.w*gv.w;
        }
    }
    out[O_CMAP + i] = acc;
}

__global__ void k_imap_raw(const float* __restrict__ ao, const int* __restrict__ selvis,
                           float* __restrict__ imap)
{
    int blk = blockIdx.x;   // (h*8+t)*4+f
    int h = blk >> 5, t = (blk >> 2) & 7, f = blk & 3;
    int tid = threadIdx.x;  // 384
    __shared__ float sel[64];
    int pstar = selvis[blk];
    if (tid < 64) sel[tid] = ao[(((long)HEADS_ + h)*S_MAIN + TEXT_ + f*PATCHES_ + pstar)*64 + tid];
    __syncthreads();
    const float* g = ao + (((long)HEADS_ + h)*S_MAIN + TEXT_ + f*PATCHES_ + tid)*64;
    float acc = 0.f;
    for (int d = 0; d < 64; d += 4) {
        float4 gv = *(const float4*)(g + d);
        acc += gv.x*sel[d] + gv.y*sel[d+1] + gv.z*sel[d+2] + gv.w*sel[d+3];
    }
    imap[((long)h*NC_ + t)*IMG_ + f*PATCHES_ + tid] = acc;
}

__global__ __launch_bounds__(256) void k_imap_norm(float* __restrict__ imap)
{
    int i = (blockIdx.x*256 + threadIdx.x) * 4;   // < 24576
    int h = i / IMG_, fp = i % IMG_;
    float4 v[8]; float4 mu = make_float4(0.f, 0.f, 0.f, 0.f);
    #pragma unroll
    for (int t = 0; t < 8; ++t) {
        v[t] = *(const float4*)(imap + ((long)h*NC_ + t)*IMG_ + fp);
        mu.x += v[t].x; mu.y += v[t].y; mu.z += v[t].z; mu.w += v[t].w;
    }
    mu.x *= 0.125f; mu.y *= 0.125f; mu.z *= 0.125f; mu.w *= 0.125f;
    float4 var = make_float4(0.f, 0.f, 0.f, 0.f);
    #pragma unroll
    for (int t = 0; t < 8; ++t) {
        var.x += (v[t].x-mu.x)*(v[t].x-mu.x); var.y += (v[t].y-mu.y)*(v[t].y-mu.y);
        var.z += (v[t].z-mu.z)*(v[t].z-mu.z); var.w += (v[t].w-mu.w)*(v[t].w-mu.w);
    }
    float4 inv;
    inv.x = 1.f / (sqrtf(var.x * (1.f/7.f)) + 1e-6f);
    inv.y = 1.f / (sqrtf(var.y * (1.f/7.f)) + 1e-6f);
    inv.z = 1.f / (sqrtf(var.z * (1.f/7.f)) + 1e-6f);
    inv.w = 1.f / (sqrtf(var.w * (1.f/7.f)) + 1e-6f);
    #pragma unroll
    for (int t = 0; t < 8; ++t) {
        *(float4*)(imap + ((long)h*NC_ + t)*IMG_ + fp) =
            make_float4((v[t].x-mu.x)*inv.x, (v[t].y-mu.y)*inv.y,
                        (v[t].z-mu.z)*inv.z, (v[t].w-mu.w)*inv.w);
    }
}

__global__ __launch_bounds__(256) void k_imap_reduce(
    const float* __restrict__ imap, const int* __restrict__ sel, float* __restrict__ out)
{
    int i = (blockIdx.x*256 + threadIdx.x) * 4;   // < 12288
    int t = i / IMG_, fp = i % IMG_;
    float4 sum = make_float4(0.f, 0.f, 0.f, 0.f);
    for (int h = 0; h < 16; ++h) {
        float4 v = *(const float4*)(imap + ((long)h*NC_ + t)*IMG_ + fp);
        sum.x += v.x; sum.y += v.y; sum.z += v.z; sum.w += v.w;
    }
    float4 ss = make_float4(0.f, 0.f, 0.f, 0.f);
    for (int k = 0; k < 4; ++k) {
        int h = sel[k];
        float4 v = *(const float4*)(imap + ((long)h*NC_ + t)*IMG_ + fp);
        ss.x += v.x; ss.y += v.y; ss.z += v.z; ss.w += v.w;
    }
    *(float4*)(out + O_ISUM + i) = sum;
    *(float4*)(out + O_SELI + i) = make_float4(ss.x*0.25f, ss.y*0.25f, ss.z*0.25f, ss.w*0.25f);
}

// residual with fused split-K reduce (float4): X = orig + gate * (p0 + p1 + bo)
__global__ __launch_bounds__(256) void k_residual1(
    const float* __restrict__ pe, const float* __restrict__ ph, const float* __restrict__ pc,
    const float* __restrict__ p0, const float* __restrict__ p1, const float* __restrict__ bo,
    const float* __restrict__ s1, float* __restrict__ X)
{
    long i = ((long)blockIdx.x*256 + threadIdx.x) * 4;
    int col = (int)(i & 1023);
    long row = i >> 10;
    int b = (int)(row / S2_), s = (int)(row % S2_);
    const float* sb = s1 + (long)b * 6144;
    float4 orig, gate;
    if (s < TEXT_) {
        orig = *(const float4*)(pe + ((long)b*TEXT_ + s)*DIM_ + col);
        gate = *(const float4*)(sb + 5120 + col);
    } else if (s < S_MAIN) {
        orig = *(const float4*)(ph + ((long)b*IMG_ + (s-TEXT_))*DIM_ + col);
        gate = *(const float4*)(sb + 2048 + col);
    } else {
        orig = *(const float4*)(pc + ((long)b*NC_ + (s-S_MAIN))*DIM_ + col);
        gate = *(const float4*)(sb + 5120 + col);
    }
    float4 a = *(const float4*)(p0 + i);
    float4 c = *(const float4*)(p1 + i);
    float4 bb = *(const float4*)(bo + col);
    *(float4*)(X + i) = make_float4(
        orig.x + gate.x*(a.x + c.x + bb.x), orig.y + gate.y*(a.y + c.y + bb.y),
        orig.z + gate.z*(a.z + c.z + bb.z), orig.w + gate.w*(a.w + c.w + bb.w));
}

// final with fused split-K reduce (float4): out = X + gate * (f0 + f1 + fb2)
__global__ __launch_bounds__(256) void k_final(
    const float* __restrict__ X, const float* __restrict__ f0, const float* __restrict__ f1,
    const float* __restrict__ fb2, const float* __restrict__ s2, float* __restrict__ out)
{
    long i = ((long)blockIdx.x*256 + threadIdx.x) * 4;
    int col = (int)(i & 1023);
    long row = i >> 10;
    int b = (int)(row / S2_), s = (int)(row % S2_);
    const float* sb = s2 + (long)b * 6144;
    float4 gate; float* o;
    if (s < TEXT_) {
        gate = *(const float4*)(sb + 5120 + col);
        o = out + O_E + ((long)b*TEXT_ + s)*DIM_ + col;
    } else if (s < S_MAIN) {
        gate = *(const float4*)(sb + 2048 + col);
        o = out + O_H + ((long)b*IMG_ + (s-TEXT_))*DIM_ + col;
    } else {
        gate = *(const float4*)(sb + 5120 + col);
        o = out + O_C + ((long)b*NC_ + (s-S_MAIN))*DIM_ + col;
    }
    float4 x = *(const float4*)(X + i);
    float4 a = *(const float4*)(f0 + i);
    float4 c = *(const float4*)(f1 + i);
    float4 bb = *(const float4*)(fb2 + col);
    *(float4*)o = make_float4(
        x.x + gate.x*(a.x + c.x + bb.x), x.y + gate.y*(a.y + c.y + bb.y),
        x.z + gate.z*(a.z + c.z + bb.z), x.w + gate.w*(a.w + c.w + bb.w));
}

extern "C" void kernel_launch(void* const* d_in, const int* in_sizes, int n_in,
                              void* d_out, int out_size, void* d_ws, size_t ws_size,
                              hipStream_t stream)
{
    (void)in_sizes; (void)n_in; (void)out_size; (void)ws_size;
    const float* h_in = (const float*)d_in[0];
    const float* e_in = (const float*)d_in[1];
    const float* c_in = (const float*)d_in[2];
    const float* temb = (const float*)d_in[3];
    const float* rcos = (const float*)d_in[4];
    const float* rsin = (const float*)d_in[5];
    const float* n1w  = (const float*)d_in[6];
    const float* n1b  = (const float*)d_in[7];
    const float* ln1w = (const float*)d_in[8];
    const float* ln1b = (const float*)d_in[9];
    const float* n2w  = (const float*)d_in[10];
    const float* n2b  = (const float*)d_in[11];
    const float* ln2w = (const float*)d_in[12];
    const float* ln2b = (const float*)d_in[13];
    const float* wq   = (const float*)d_in[14];
    const float* wk   = (const float*)d_in[15];
    const float* wv   = (const float*)d_in[16];
    const float* nqw  = (const float*)d_in[17];
    const float* nqb  = (const float*)d_in[18];
    const float* nkw  = (const float*)d_in[19];
    const float* nkb  = (const float*)d_in[20];
    const float* wo   = (const float*)d_in[21];
    const float* bo   = (const float*)d_in[22];
    const float* fw1  = (const float*)d_in[23];
    const float* fb1  = (const float*)d_in[24];
    const float* fw2  = (const float*)d_in[25];
    const float* fb2  = (const float*)d_in[26];

    float* ws  = (float*)d_ws;
    float* out = (float*)d_out;
    float* s1   = ws + OFF_S1;
    float* s2   = ws + OFF_S2;
    float* score  = ws + OFF_MISC;
    int*   selh   = (int*)(ws + OFF_MISC + 16);
    int*   selvis = (int*)(ws + OFF_MISC + 32);
    float* sim  = ws + OFF_SIM;
    float* imap = ws + OFF_IMAP;
    float* ac   = ws + OFF_AC;
    float* X    = ws + OFF_X;
    float* proj = ws + OFF_PROJ;
    float* xn   = ws + OFF_XN;
    float* qh   = ws + OFF_Q;
    float* kh   = ws + OFF_K;
    float* vh   = ws + OFF_V;
    float* ao   = ws + OFF_AO;
    float* ffo  = proj;
    float* fixp = ws + OFF_AO;             // fixup split-K partials (2 x 1536x1024)
    float* sp   = ws + OFF_X;              // silu partials (4 x 24576) [step1 -> step1b]
    unsigned short* xnb   = (unsigned short*)(ws + OFF_XNB);
    unsigned short* wqkvT = (unsigned short*)(ws + OFF_PROJ);
    unsigned short* vb    = (unsigned short*)(ws + OFF_PROJ);
    unsigned short* qbb   = (unsigned short*)(ws + OFF_X);
    unsigned short* kbb   = qbb + (size_t)B_*HEADS_*S2_*64;
    unsigned short* woT   = (unsigned short*)(ws + OFF_AO + 2000000);
    unsigned short* fw1T  = (unsigned short*)(ws + OFF_V);
    unsigned short* fw2T  = (unsigned short*)(ws + OFF_AO);
    unsigned short* ffh   = (unsigned short*)(ws + OFF_Q);
    // flash split-S partial overlays (dead regions during step 8):
    float* fp0 = vh;    // OFF_V: vh dead after k_vtrans; fw1T arrives step 13
    float* fp1 = xn;    // OFF_XN: xn dead after step 6; proj z1 arrives step 11
    float* fpl = sim;   // OFF_SIM: sim written at step 9 k_sim (after combine)

    // 1. adaLN modulation vectors (split-K x4 partials + reduce)
    hipLaunchKernelGGL(k_silu_mod, dim3(24, 2, 4), dim3(256), 0, stream, temb, n1w, n2w, sp);
    hipLaunchKernelGGL(k_silu_red, dim3(96), dim3(256), 0, stream, sp, n1b, n2b, s1, s2);
    // 2. QKV weight transposes (batched z=3)
    hipLaunchKernelGGL(k_tcvt_qkv, dim3(32, 32, 3), dim3(256), 0, stream, wq, wk, wv, wqkvT);
    // 3. norm1 + modulation -> xn fp32 + xnb bf16
    hipLaunchKernelGGL(k_ln_mod, dim3(ROWS_), dim3(256), 0, stream,
        e_in, (long)TEXT_*DIM_, h_in, (long)IMG_*DIM_, c_in, (long)NC_*DIM_, s1, ln1w, ln1b, xn, xnb);
    // 4. fused QKV bf16 GEMM, headed fp32 scatter
    hipLaunchKernelGGL(k_bgemm, dim3(24, 28, 1), dim3(256), 0, stream,
        xnb, wqkvT, (const float*)nullptr, (float*)nullptr, (unsigned short*)nullptr,
        ROWS_, 3072, 1024, 1024, 0, qh, kh, vh);
    // 5. fp32 q-fixup split-K x2 -> partials, then reduce into headed qh
    hipLaunchKernelGGL(k_gemm, dim3(16, 24, 2), dim3(256), 0, stream,
        xn + (long)(S2_ + TEXT_)*DIM_, wq, (float*)nullptr, IMG_, DIM_, DIM_, 512, 0, 0, fixp);
    hipLaunchKernelGGL(k_fixred, dim3(1536), dim3(256), 0, stream, fixp, qh);
    // 6. fp32 k-fixup (8 concept rows, batch 1) headed
    hipLaunchKernelGGL(k_gemm, dim3(16, 1, 1), dim3(256), 0, stream,
        xn + (long)(S2_ + S_MAIN)*DIM_, wk, kh, NC_, DIM_, DIM_, 1024, 1, S2_ + S_MAIN, (float*)nullptr);
    // 7. QK layernorm + RoPE; V transpose to bf16
    hipLaunchKernelGGL(k_qk_prep, dim3(14160, 2), dim3(256), 0, stream,
        qh, kh, qbb, kbb, nqw, nqb, nkw, nkb, rcos, rsin);
    hipLaunchKernelGGL(k_vtrans, dim3(56, 2, 32), dim3(256), 0, stream, vh, vb);
    // 8. attention: split-S x2, XCD-chunked (bx<28: main u=bx>>1/z=bx&1; bx 28,29: concept z)
    hipLaunchKernelGGL(k_flash, dim3(30, 16, 2), dim3(256), 0, stream,
        qbb, kbb, vb, fp0, fp1, fpl);
    // 8b. combine partials -> ao/ac + merged bf16 (fused old k_merge), float4
    hipLaunchKernelGGL(k_fcomb, dim3(3540), dim3(256), 0, stream, fp0, fp1, fpl, ao, ac, xnb);
    // 9. maps (batch 1)
    hipLaunchKernelGGL(k_head_score, dim3(16), dim3(256), 0, stream, ao, score);
    hipLaunchKernelGGL(k_top4, dim3(1), dim3(64), 0, stream, score, selh);
    hipLaunchKernelGGL(k_sim, dim3(512), dim3(512), 0, stream, qh, kh, sim, selvis);
    hipLaunchKernelGGL(k_cross, dim3(12), dim3(256), 0, stream, sim, out);
    hipLaunchKernelGGL(k_concept_maps, dim3(48), dim3(256), 0, stream, ac, ao, out);
    hipLaunchKernelGGL(k_imap_raw, dim3(512), dim3(384), 0, stream, ao, selvis, imap);
    hipLaunchKernelGGL(k_imap_norm, dim3(24), dim3(256), 0, stream, imap);
    hipLaunchKernelGGL(k_imap_reduce, dim3(12), dim3(256), 0, stream, imap, selh, out);
    // 10. wo transpose into dead ao region (merge now fused into fcomb)
    hipLaunchKernelGGL(k_tcvt, dim3(32, 32), dim3(256), 0, stream, wo, woT, 1024, 1024);
    // 11. wo GEMM split-K x2 (partials at PROJ / XN)
    hipLaunchKernelGGL(k_bgemm, dim3(8, 28, 2), dim3(256), 0, stream,
        xnb, woT, (const float*)nullptr, proj, (unsigned short*)nullptr, ROWS_, DIM_, 1024, 512, 1,
        (float*)nullptr, (float*)nullptr, (float*)nullptr);
    // 12. residual1 (fused reduce + bias, float4) -> X
    hipLaunchKernelGGL(k_residual1, dim3(3540), dim3(256), 0, stream,
        e_in, h_in, c_in, proj, proj + (size_t)ROWS_*DIM_, bo, s1, X);
    // 13. FF weight transposes
    hipLaunchKernelGGL(k_tcvt, dim3(128, 32), dim3(256), 0, stream, fw1, fw1T, 1024, 4096);
    hipLaunchKernelGGL(k_tcvt, dim3(32, 128), dim3(256), 0, stream, fw2, fw2T, 4096, 1024);
    // 14. norm2 -> xnb bf16 only
    hipLaunchKernelGGL(k_ln_mod, dim3(ROWS_), dim3(256), 0, stream,
        X, (long)S2_*DIM_, X + (long)TEXT_*DIM_, (long)S2_*DIM_, X + (long)S_MAIN*DIM_, (long)S2_*DIM_,
        s2, ln2w, ln2b, (float*)nullptr, xnb);
    // 15. ff1 (gelu fused, bf16 out)
    hipLaunchKernelGGL(k_bgemm, dim3(32, 28, 1), dim3(256), 0, stream,
        xnb, fw1T, fb1, (float*)nullptr, ffh, ROWS_, FF_, 1024, 1024, 2,
        (float*)nullptr, (float*)nullptr, (float*)nullptr);
    // 16. ff2 split-K x2 (partials at PROJ / XN)
    hipLaunchKernelGGL(k_bgemm, dim3(8, 28, 2), dim3(256), 0, stream,
        ffh, fw2T, (const float*)nullptr, ffo, (unsigned short*)nullptr, ROWS_, DIM_, FF_, 2048, 1,
        (float*)nullptr, (float*)nullptr, (float*)nullptr);
    // 17. final (fused reduce + bias, float4) -> outputs
    hipLaunchKernelGGL(k_final, dim3(3540), dim3(256), 0, stream,
        X, ffo, ffo + (size_t)ROWS_*DIM_, fb2, s2, out);
}

// Round 13
// 655.618 us; speedup vs baseline: 1.1126x; 1.0306x over previous
//
#include <hip/hip_runtime.h>
#include <hip/hip_bf16.h>
#include <math.h>

#define B_ 2
#define HEADS_ 16
#define HD_ 64
#define DIM_ 1024
#define TEXT_ 226
#define NC_ 8
#define FRAMES_ 4
#define PATCHES_ 384
#define IMG_ 1536
#define S_MAIN 1762
#define S2_ 1770
#define TD_ 512
#define FF_ 4096
#define ROWS_ (B_*S2_)   // 3540
#define VPAD_ 1792       // padded key dim for transposed V

// ---- workspace offsets (float slots) ----
#define OFF_S1   0L
#define OFF_S2   12288L
#define OFF_MISC 24576L
#define OFF_SIM  25600L
#define OFF_IMAP 222208L
#define OFF_AC   418816L
#define OFF_X    435200L
#define OFF_PROJ 4060160L
#define OFF_XN   7685120L
#define OFF_Q    11310080L
#define OFF_K    14935040L
#define OFF_V    18560000L
#define OFF_AO   22184960L
#define OFF_XNB  25809920L
// overlays (liveness-checked):
//   silu partials fp32 4x24576 @ OFF_X  [step1 -> step1b; qbb overwrites step7]
//   wqkvT bf16(3072x1024) @ OFF_PROJ   [step2 -> step4]
//   vb    bf16(B,H,64,1792) @ OFF_PROJ [step7b -> step8]
//   qb/kb bf16(B,H,S2,64) @ OFF_X      [step7 -> step8; X overwrites step12]
//   fixup partials fp32 2x(1536x1024) @ OFF_AO [step5 -> step5b; ao written step8b]
//   flash split-S partials: p0 fp32(2,16,1770,64) @ OFF_V  [step8 -> step8b; fw1T overwrites step13]
//                           p1 fp32(2,16,1770,64) @ OFF_XN [step8 -> step8b; proj z1 overwrites step11]
//                           pL fp32(2,2,16,1770)  @ OFF_SIM [step8 -> step8b; sim overwrites step9]
//   woT   bf16(1024x1024) @ OFF_AO+2e6 [step10.5 -> step11]
//   fw1T  bf16(4096x1024) @ OFF_V      [step13+]
//   fw2T  bf16(1024x4096) @ OFF_AO     [step13+]
//   ffh   bf16(3540x4096) @ OFF_Q      [step15+]
//   split-K partials: z0 @ OFF_PROJ, z1 @ OFF_XN (contiguous)

// ---- output offsets (floats) ----
#define O_H    0L
#define O_E    3145728L
#define O_C    3608576L
#define O_SELI 3624960L
#define O_ISUM 3637248L
#define O_CMAP 3649536L
#define O_XMAP 3661824L

// pbuf LDS stride (shorts): 72 -> 144B rows, 16B-aligned (b128 single-op).
// kt/vt: stride 64 (128B rows, linear — global_load_lds writes base+lane*16B)
// with PRE-SWIZZLED GLOBAL SOURCE: LDS slot (row r, chunk j) holds global
// chunk j^(r&7). Reads XOR the chunk index with (row&7): conflict-free
// (2 lanes/bank) and 16B-aligned on both sides.
#define PS_ 72

typedef __bf16 bf16x8_t __attribute__((ext_vector_type(8)));
typedef float  f32x4_t  __attribute__((ext_vector_type(4)));

__device__ __forceinline__ unsigned int pack2bf(float a, float b) {
    unsigned short ua = __builtin_bit_cast(unsigned short, (__bf16)a);
    unsigned short ub = __builtin_bit_cast(unsigned short, (__bf16)b);
    return (unsigned int)ua | ((unsigned int)ub << 16);
}

// async global->LDS 16B copy: per-lane global src, wave-uniform LDS base + lane*16
__device__ __forceinline__ void stage16(const unsigned short* g, unsigned short* l) {
    __builtin_amdgcn_global_load_lds(
        (const __attribute__((address_space(1))) unsigned int*)g,
        (__attribute__((address_space(3))) unsigned int*)l, 16, 0, 0);
}

// XCD-chunked bijective remap of a linear workgroup id (requires nwg % 8 == 0)
__device__ __forceinline__ int xcd_swz(int lin, int nwg) {
    if ((nwg & 7) == 0) { int q = nwg >> 3; lin = (lin & 7) * q + (lin >> 3); }
    return lin;
}

// silu(temb) @ norm_w partials. Grid (24, 2, 4): bx = 256-col chunk, by = which
// (w1/w2), bz = k-chunk of 128. Both batches computed in ONE pass over the
// weights (each weight element read exactly once, float4 / 1KB-per-wave
// coalesced). Per-block k-sub x4 LDS reduce; partials at part + bz*24576.
__global__ __launch_bounds__(256) void k_silu_mod(
    const float* __restrict__ temb, const float* __restrict__ w1,
    const float* __restrict__ w2, float* __restrict__ part)
{
    int bx = blockIdx.x, which = blockIdx.y, kz = blockIdx.z;
    const float* w = which ? w2 : w1;
    int tid = threadIdx.x;
    __shared__ float sv[2][512];
    for (int i = tid; i < 1024; i += 256) {
        int b = i >> 9, k = i & 511;
        float tv = temb[b*TD_ + k];
        sv[b][k] = tv / (1.f + __expf(-tv));
    }
    __syncthreads();
    int n4 = tid & 63;        // float4 column within chunk (wave-contiguous)
    int ksub = tid >> 6;      // 0..3
    int ncol = bx*256 + n4*4;
    int k0 = kz*128 + ksub*32;
    float a0x=0.f,a0y=0.f,a0z=0.f,a0w=0.f, a1x=0.f,a1y=0.f,a1z=0.f,a1w=0.f;
    for (int k = k0; k < k0 + 32; ++k) {
        float4 wv = *(const float4*)(w + (size_t)k*6144 + ncol);
        float s0 = sv[0][k], s1 = sv[1][k];
        a0x += s0*wv.x; a0y += s0*wv.y; a0z += s0*wv.z; a0w += s0*wv.w;
        a1x += s1*wv.x; a1y += s1*wv.y; a1z += s1*wv.z; a1w += s1*wv.w;
    }
    __shared__ float red[2][256][4];
    red[0][tid][0]=a0x; red[0][tid][1]=a0y; red[0][tid][2]=a0z; red[0][tid][3]=a0w;
    red[1][tid][0]=a1x; red[1][tid][1]=a1y; red[1][tid][2]=a1z; red[1][tid][3]=a1w;
    __syncthreads();
    if (ksub == 0) {
        #pragma unroll
        for (int s = 1; s < 4; ++s) {
            a0x += red[0][tid+64*s][0]; a0y += red[0][tid+64*s][1];
            a0z += red[0][tid+64*s][2]; a0w += red[0][tid+64*s][3];
            a1x += red[1][tid+64*s][0]; a1y += red[1][tid+64*s][1];
            a1z += red[1][tid+64*s][2]; a1w += red[1][tid+64*s][3];
        }
        long base = (long)kz*24576 + (long)which*12288;
        *(float4*)(part + base + ncol)        = make_float4(a0x,a0y,a0z,a0w);
        *(float4*)(part + base + 6144 + ncol) = make_float4(a1x,a1y,a1z,a1w);
    }
}

// reduce 4 k-partials + bias -> s1/s2
__global__ __launch_bounds__(256) void k_silu_red(
    const float* __restrict__ part, const float* __restrict__ b1,
    const float* __restrict__ b2, float* __restrict__ s1, float* __restrict__ s2)
{
    int i = blockIdx.x*256 + threadIdx.x;   // < 24576
    float v = part[i] + part[i+24576] + part[i+49152] + part[i+73728];
    int which = i / 12288, r = i % 12288, n = r % 6144;
    v += (which ? b2 : b1)[n];
    (which ? s2 : s1)[r] = v;
}

// transpose + convert: src (K,N) fp32 -> dst (N,K) bf16
__global__ __launch_bounds__(256) void k_tcvt(
    const float* __restrict__ src, unsigned short* __restrict__ dst, int K, int N)
{
    __shared__ float t[32][33];
    int n0 = blockIdx.x * 32, k0 = blockIdx.y * 32;
    int tx = threadIdx.x & 31, ty = threadIdx.x >> 5;
    #pragma unroll
    for (int i = 0; i < 4; ++i)
        t[ty + 8*i][tx] = src[(size_t)(k0 + ty + 8*i) * N + n0 + tx];
    __syncthreads();
    #pragma unroll
    for (int i = 0; i < 4; ++i) {
        float v = t[tx][ty + 8*i];
        dst[(size_t)(n0 + ty + 8*i) * K + k0 + tx] =
            __builtin_bit_cast(unsigned short, (__bf16)v);
    }
}

// batched QKV transpose (z selects wq/wk/wv), 1024x1024 each
__global__ __launch_bounds__(256) void k_tcvt_qkv(
    const float* __restrict__ wq, const float* __restrict__ wk, const float* __restrict__ wv,
    unsigned short* __restrict__ dst)
{
    const float* src = (blockIdx.z == 0) ? wq : (blockIdx.z == 1) ? wk : wv;
    unsigned short* d = dst + (size_t)blockIdx.z * 1024 * 1024;
    __shared__ float t[32][33];
    int n0 = blockIdx.x * 32, k0 = blockIdx.y * 32;
    int tx = threadIdx.x & 31, ty = threadIdx.x >> 5;
    #pragma unroll
    for (int i = 0; i < 4; ++i)
        t[ty + 8*i][tx] = src[(size_t)(k0 + ty + 8*i) * 1024 + n0 + tx];
    __syncthreads();
    #pragma unroll
    for (int i = 0; i < 4; ++i) {
        float v = t[tx][ty + 8*i];
        d[(size_t)(n0 + ty + 8*i) * 1024 + k0 + tx] =
            __builtin_bit_cast(unsigned short, (__bf16)v);
    }
}

// V (B,H,S2,64) fp32 -> vb (B,H,64,VPAD) bf16 transposed
__global__ __launch_bounds__(256) void k_vtrans(
    const float* __restrict__ vh, unsigned short* __restrict__ vb)
{
    int bh = blockIdx.z;
    int d0 = blockIdx.y * 32;
    int s0 = blockIdx.x * 32;
    __shared__ float t[32][33];
    int tx = threadIdx.x & 31, ty = threadIdx.x >> 5;
    const float* src = vh + (size_t)bh * S2_ * 64;
    #pragma unroll
    for (int i = 0; i < 4; ++i) {
        int s = s0 + ty + 8*i; if (s >= S2_) s = S2_ - 1;
        t[ty + 8*i][tx] = src[(size_t)s*64 + d0 + tx];
    }
    __syncthreads();
    unsigned short* dst = vb + (size_t)bh * 64 * VPAD_;
    #pragma unroll
    for (int i = 0; i < 4; ++i) {
        int d = d0 + ty + 8*i;
        dst[(size_t)d * VPAD_ + s0 + tx] =
            __builtin_bit_cast(unsigned short, (__bf16)t[tx][ty + 8*i]);
    }
}

// fused layernorm + adaLN modulation -> optional fp32 out AND bf16 outb
__global__ __launch_bounds__(256) void k_ln_mod(
    const float* pe, long bse, const float* ph, long bsh, const float* pc, long bsc,
    const float* __restrict__ smod, const float* __restrict__ lnw, const float* __restrict__ lnb,
    float* __restrict__ out, unsigned short* __restrict__ outb)
{
    long row = blockIdx.x;
    int b = (int)(row / S2_), s = (int)(row % S2_);
    const float* src; int shiftB, scaleB;
    if (s < TEXT_)       { src = pe + (long)b*bse + (long)s*DIM_;          shiftB = 3072; scaleB = 4096; }
    else if (s < S_MAIN) { src = ph + (long)b*bsh + (long)(s-TEXT_)*DIM_;  shiftB = 0;    scaleB = 1024; }
    else                 { src = pc + (long)b*bsc + (long)(s-S_MAIN)*DIM_; shiftB = 3072; scaleB = 4096; }
    int tid = threadIdx.x;
    int col = tid * 4;
    float4 x = *(const float4*)(src + col);
    float lsum = x.x + x.y + x.z + x.w;
    float lsq  = x.x*x.x + x.y*x.y + x.z*x.z + x.w*x.w;
    __shared__ float r1[256], r2[256];
    r1[tid] = lsum; r2[tid] = lsq; __syncthreads();
    for (int st = 128; st; st >>= 1) {
        if (tid < st) { r1[tid] += r1[tid+st]; r2[tid] += r2[tid+st]; }
        __syncthreads();
    }
    float mu = r1[0] * (1.f / DIM_);
    float var = r2[0] * (1.f / DIM_) - mu * mu;
    float rstd = rsqrtf(var + 1e-5f);
    const float* sb = smod + (long)b * 6144;
    float xs[4] = {x.x, x.y, x.z, x.w};
    float res[4];
    #pragma unroll
    for (int i = 0; i < 4; ++i) {
        int cc = col + i;
        float yy = (xs[i] - mu) * rstd * lnw[cc] + lnb[cc];
        res[i] = yy * (1.f + sb[scaleB + cc]) + sb[shiftB + cc];
    }
    if (out)
        *(float4*)(out + row * DIM_ + col) = make_float4(res[0], res[1], res[2], res[3]);
    uint2 pk;
    pk.x = pack2bf(res[0], res[1]); pk.y = pack2bf(res[2], res[3]);
    *(uint2*)(outb + row * DIM_ + col) = pk;
}

// bf16 MFMA GEMM, double-buffered LDS staged via global_load_lds (16B, async),
// optional split-K via gridDim.z. Linear LDS [128][32] per tile (no pad).
// XCD-chunked tile remap for L2 locality.
__global__ __launch_bounds__(256, 4) void k_bgemm(
    const unsigned short* __restrict__ A, const unsigned short* __restrict__ Wt,
    const float* __restrict__ bias, float* __restrict__ out_f,
    unsigned short* __restrict__ out_b, int M, int N, int K, int kz_len, int mode,
    float* __restrict__ q_out, float* __restrict__ k_out, float* __restrict__ v_out)
{
    __shared__ unsigned short at[2][128*32];
    __shared__ unsigned short bt[2][128*32];
    int tid = threadIdx.x;
    int w = tid >> 6, lane = tid & 63;
    int lr = lane & 15, lh = lane >> 4;
    int wm = w >> 1, wn = w & 1;
    int gx = gridDim.x;
    int lin = xcd_swz(blockIdx.y * gx + blockIdx.x, gx * gridDim.y);
    int m0 = (lin / gx) * 128, n0 = (lin % gx) * 128;
    int kbeg = blockIdx.z * kz_len, kend = kbeg + kz_len;

    f32x4_t acc[4][4];
    #pragma unroll
    for (int i = 0; i < 4; ++i)
        #pragma unroll
        for (int j = 0; j < 4; ++j) { acc[i][j][0]=0.f; acc[i][j][1]=0.f; acc[i][j][2]=0.f; acc[i][j][3]=0.f; }

    // staging geometry: issue i (0,1) covers rows i*64 + (tid>>2), 16B chunk (tid&3)
    int r4 = tid >> 2, c4 = tid & 3;
    int arow0 = m0 + r4;      if (arow0 >= M) arow0 = M - 1;
    int arow1 = m0 + 64 + r4; if (arow1 >= M) arow1 = M - 1;
    const unsigned short* ga0 = A + (size_t)arow0 * K + c4 * 8;
    const unsigned short* ga1 = A + (size_t)arow1 * K + c4 * 8;
    const unsigned short* gb0 = Wt + (size_t)(n0 + r4) * K + c4 * 8;
    const unsigned short* gb1 = Wt + (size_t)(n0 + 64 + r4) * K + c4 * 8;
    int lbase = w * 512;   // shorts; wave-uniform; HW adds lane*16B

    // prologue: stage buf 0
    stage16(ga0 + kbeg, &at[0][lbase]);
    stage16(ga1 + kbeg, &at[0][lbase + 2048]);
    stage16(gb0 + kbeg, &bt[0][lbase]);
    stage16(gb1 + kbeg, &bt[0][lbase + 2048]);
    __syncthreads();
    int buf = 0;
    for (int k0 = kbeg; k0 < kend; k0 += 32) {
        bool more = (k0 + 32) < kend;
        if (more) {
            int nb = buf ^ 1;
            stage16(ga0 + k0 + 32, &at[nb][lbase]);
            stage16(ga1 + k0 + 32, &at[nb][lbase + 2048]);
            stage16(gb0 + k0 + 32, &bt[nb][lbase]);
            stage16(gb1 + k0 + 32, &bt[nb][lbase + 2048]);
        }
        int4 af[4], bf[4];
        #pragma unroll
        for (int tm = 0; tm < 4; ++tm)
            af[tm] = *(const int4*)&at[buf][(wm*64 + tm*16 + lr)*32 + lh*8];
        #pragma unroll
        for (int tn = 0; tn < 4; ++tn)
            bf[tn] = *(const int4*)&bt[buf][(wn*64 + tn*16 + lr)*32 + lh*8];
        #pragma unroll
        for (int tm = 0; tm < 4; ++tm) {
            bf16x8_t av = __builtin_bit_cast(bf16x8_t, af[tm]);
            #pragma unroll
            for (int tn = 0; tn < 4; ++tn)
                acc[tm][tn] = __builtin_amdgcn_mfma_f32_16x16x32_bf16(
                    av, __builtin_bit_cast(bf16x8_t, bf[tn]), acc[tm][tn], 0, 0, 0);
        }
        __syncthreads();
        buf ^= 1;
    }
    float* of = out_f;
    if (mode == 1) of += (size_t)blockIdx.z * M * N;
    #pragma unroll
    for (int tm = 0; tm < 4; ++tm) {
        #pragma unroll
        for (int r = 0; r < 4; ++r) {
            int m = m0 + wm*64 + tm*16 + lh*4 + r;
            if (m >= M) continue;
            int b = m / S2_, s = m % S2_;
            #pragma unroll
            for (int tn = 0; tn < 4; ++tn) {
                int n = n0 + wn*64 + tn*16 + lr;
                float v = acc[tm][tn][r];
                if (mode == 0) {
                    int which = n >> 10, c = n & 1023;
                    int hh = c >> 6, d = c & 63;
                    float* dstp = (which == 0) ? q_out : (which == 1) ? k_out : v_out;
                    dstp[(((size_t)b*HEADS_ + hh)*S2_ + s)*64 + d] = v;
                } else if (mode == 1) {
                    of[(size_t)m * N + n] = v + (bias ? bias[n] : 0.f);
                } else {
                    float x = v + bias[n];
                    float u = 0.7978845608028654f * (x + 0.044715f*x*x*x);
                    float g = x / (1.f + __expf(-2.f*u));
                    out_b[(size_t)m * N + n] = __builtin_bit_cast(unsigned short, (__bf16)g);
                }
            }
        }
    }
}

// fp32 tiled GEMM (argmax fixups). If part != nullptr: write plain partial at
// part + z*M*N (split-K, K range [z*kz, (z+1)*kz)). Else headed/plain store.
__global__ __launch_bounds__(256) void k_gemm(
    const float* __restrict__ A, const float* __restrict__ W,
    float* __restrict__ C, int M, int N, int K, int kz_len, int headed, int row_off,
    float* __restrict__ part)
{
    __shared__ float As[16][68];
    __shared__ float Bs[16][68];
    int tid = threadIdx.x;
    int gx = gridDim.x;
    int lin = xcd_swz(blockIdx.y * gx + blockIdx.x, gx * gridDim.y);
    int bm = (lin / gx) * 64, bn = (lin % gx) * 64;
    int tr = tid >> 4, tc = tid & 15;
    int ar = tid >> 2, akk = (tid & 3) * 4;
    int bkk = tid >> 4, bn4 = (tid & 15) * 4;
    float acc[4][4] = {{0.f}};
    int garow = bm + ar;
    const float* Aptr = A + (size_t)garow * K + akk;
    const float* Wptr = W + (size_t)bkk * N + bn + bn4;
    int kbeg = blockIdx.z * kz_len;
    for (int k0 = kbeg; k0 < kbeg + kz_len; k0 += 16) {
        float4 av = make_float4(0.f, 0.f, 0.f, 0.f);
        if (garow < M) av = *(const float4*)(Aptr + k0);
        As[akk+0][ar] = av.x; As[akk+1][ar] = av.y; As[akk+2][ar] = av.z; As[akk+3][ar] = av.w;
        float4 bv = *(const float4*)(Wptr + (size_t)k0 * N);
        Bs[bkk][bn4+0] = bv.x; Bs[bkk][bn4+1] = bv.y; Bs[bkk][bn4+2] = bv.z; Bs[bkk][bn4+3] = bv.w;
        __syncthreads();
        #pragma unroll
        for (int kk = 0; kk < 16; ++kk) {
            float4 a = *(const float4*)&As[kk][tr*4];
            float4 bq = *(const float4*)&Bs[kk][tc*4];
            float avv[4] = {a.x, a.y, a.z, a.w};
            float bvv[4] = {bq.x, bq.y, bq.z, bq.w};
            #pragma unroll
            for (int i = 0; i < 4; ++i)
                #pragma unroll
                for (int j = 0; j < 4; ++j)
                    acc[i][j] += avv[i] * bvv[j];
        }
        __syncthreads();
    }
    #pragma unroll
    for (int i = 0; i < 4; ++i) {
        int r = bm + tr*4 + i;
        if (r >= M) continue;
        #pragma unroll
        for (int j = 0; j < 4; ++j) {
            int n = bn + tc*4 + j;
            float v = acc[i][j];
            if (part) {
                part[(size_t)blockIdx.z*M*N + (size_t)r*N + n] = v;
            } else if (headed) {
                int rg = r + row_off;
                int b = rg / S2_, s = rg % S2_;
                int hh = n >> 6, d = n & 63;
                C[(((size_t)b*HEADS_ + hh)*S2_ + s)*64 + d] = v;
            } else {
                C[(size_t)(r + row_off) * N + n] = v;
            }
        }
    }
}

// sum 2 fixup partials -> headed fp32 store into qh (batch1 img rows), float4
__global__ __launch_bounds__(256) void k_fixred(
    const float* __restrict__ pa, float* __restrict__ qh_out)
{
    long i = ((long)blockIdx.x*256 + threadIdx.x) * 4;   // < 1536*1024
    int r = (int)(i >> 10), n = (int)(i & 1023);
    float4 a = *(const float4*)(pa + i);
    float4 b = *(const float4*)(pa + i + (long)IMG_*DIM_);
    int hh = n >> 6, d = n & 63;
    *(float4*)(qh_out + (((size_t)HEADS_ + hh)*S2_ + TEXT_ + r)*64 + d) =
        make_float4(a.x + b.x, a.y + b.y, a.z + b.z, a.w + b.w);
}

// per-head layernorm + RoPE, float4: 4 rows/wave, 16 lanes/row, lane holds
// d in [4*l16, 4*l16+4). LN reduce = 4-wide local + 16-lane shfl_xor tree
// (offsets 1..8 stay within the 16-lane group). RoPE pair rotation is
// intra-float4: rot = (-y.y, y.x, -y.w, y.z). bf16 write 8B, fp32 writeback
// 16B, all aligned. Grid (3540, 2).
__global__ __launch_bounds__(256) void k_qk_prep(
    float* qh, float* kh, unsigned short* qbb, unsigned short* kbb,
    const float* __restrict__ nqw, const float* __restrict__ nqb,
    const float* __restrict__ nkw, const float* __restrict__ nkb,
    const float* __restrict__ rc, const float* __restrict__ rs)
{
    int which = blockIdx.y;
    int tid = threadIdx.x;
    int w = tid >> 6, lane = tid & 63;
    int sub = lane >> 4, l16 = lane & 15;
    long row = (long)blockIdx.x * 16 + w * 4 + sub;   // (b*16+h)*S2 + s
    long s = row % S2_;
    bool b1 = row >= (long)HEADS_*S2_;
    float* base = (which ? kh : qh) + row * 64;
    const float* wv = which ? nkw : nqw;
    const float* bb = which ? nkb : nqb;
    int d0 = l16 * 4;
    float4 x = *(const float4*)(base + d0);
    float sum = x.x + x.y + x.z + x.w;
    for (int off = 1; off < 16; off <<= 1) sum += __shfl_xor(sum, off, 64);
    float mu = sum * (1.f / 64.f);
    float4 dx = make_float4(x.x - mu, x.y - mu, x.z - mu, x.w - mu);
    float v = dx.x*dx.x + dx.y*dx.y + dx.z*dx.z + dx.w*dx.w;
    for (int off = 1; off < 16; off <<= 1) v += __shfl_xor(v, off, 64);
    float rstd = rsqrtf(v * (1.f / 64.f) + 1e-6f);
    float4 w4 = *(const float4*)(wv + d0);
    float4 b4 = *(const float4*)(bb + d0);
    float4 y = make_float4(dx.x*rstd*w4.x + b4.x, dx.y*rstd*w4.y + b4.y,
                           dx.z*rstd*w4.z + b4.z, dx.w*rstd*w4.w + b4.w);
    if (s >= TEXT_ && s < S_MAIN) {
        long p = s - TEXT_;
        float4 c4 = *(const float4*)(rc + p*64 + d0);
        float4 s4 = *(const float4*)(rs + p*64 + d0);
        float4 rot = make_float4(-y.y, y.x, -y.w, y.z);
        y = make_float4(y.x*c4.x + rot.x*s4.x, y.y*c4.y + rot.y*s4.y,
                        y.z*c4.z + rot.z*s4.z, y.w*c4.w + rot.w*s4.w);
    }
    bool needf = b1 && (which ? (s >= S_MAIN) : (s >= TEXT_ && s < S_MAIN));
    if (needf) *(float4*)(base + d0) = y;
    uint2 pk; pk.x = pack2bf(y.x, y.y); pk.y = pack2bf(y.z, y.w);
    *(uint2*)((which ? kbb : qbb) + row * 64 + d0) = pk;
}

// MFMA flash attention with 2-way KV split (split-S). 128-q blocks, 4 waves.
// No-max softmax makes the split exactly associative: each split writes
// unnormalized O and L partials; k_fcomb does (O0+O1)/(L0+L1).
// K/V staged via global_load_lds: linear LDS dest (stride-64 rows, the exact
// wave-uniform+lane*16B layout the DMA writes) + pre-swizzled global source
// (content chunk j^(slot_row&7)); reads XOR the chunk with (row&7) ->
// conflict-free, 16B-aligned, no VGPR round-trip. Full-tile fast path skips
// the tail mask (only ~1 in 14 tiles is partial).
// XCD-chunked remap over the full 960-block grid (4 KV sets per XCD ~1.8MB L2).
__global__ __launch_bounds__(256) void k_flash(
    const unsigned short* __restrict__ qb, const unsigned short* __restrict__ kb,
    const unsigned short* __restrict__ vb,
    float* __restrict__ p0, float* __restrict__ p1, float* __restrict__ pl)
{
    int lin3 = (blockIdx.z * gridDim.y + blockIdx.y) * gridDim.x + blockIdx.x;
    lin3 = xcd_swz(lin3, gridDim.x * gridDim.y * gridDim.z);
    int bx = lin3 % 30;
    int rest = lin3 / 30;
    int h = rest & 15, b = rest >> 4;
    int qt, NQ, q_off, r0s, r0e, r1s, r1e, z;
    if (bx < 28) {
        z = bx & 1; int u = bx >> 1;
        qt = u*128; NQ = S_MAIN; q_off = 0;
        r0s = z ? 896 : 0; r0e = z ? S_MAIN : 896;
        r1s = 0; r1e = 0;
    } else {
        z = bx - 28;
        qt = 0; NQ = NC_; q_off = S_MAIN;
        if (z == 0) { r0s = S_MAIN;      r0e = S2_;    r1s = TEXT_; r1e = TEXT_ + 768; }
        else        { r0s = TEXT_ + 768; r0e = S_MAIN; r1s = 0;     r1e = 0; }
    }
    float* po = z ? p1 : p0;
    int tid = threadIdx.x;
    int w = tid >> 6, lane = tid & 63;
    int lr = lane & 15, lh = lane >> 4;
    int s7 = lr & 7;   // row&7 for all fragment rows 16g+lr
    __shared__ __align__(16) unsigned short kt[64*64];
    __shared__ __align__(16) unsigned short vt[64*64];
    __shared__ __align__(16) unsigned short pbuf[4*32*PS_];
    unsigned short* pw = pbuf + w*32*PS_;
    const unsigned short* qbase = qb + (((size_t)b*HEADS_ + h)*S2_ + q_off)*64;
    const unsigned short* kbase = kb + ((size_t)b*HEADS_ + h)*S2_*64;
    const unsigned short* vbase = vb + (size_t)(b*HEADS_ + h)*64*VPAD_;
    // staging geometry (per issue i=0,1): idx = tid + i*256; slot row idx>>3,
    // chunk idx&7; LDS dest is linear idx*16B (wave-uniform base + lane*16B);
    // global src chunk = (idx&7) ^ (slot_row & 7). srow1&7 == srow0&7.
    int srow0 = tid >> 3, schunk = tid & 7;
    int srow1 = srow0 + 32;
    int sc0 = (schunk ^ (srow0 & 7)) << 3;
    int ldst0 = (w * 64) * 8;                // shorts; wave-uniform
    int ldst1 = (256 + w * 64) * 8;
    bf16x8_t aq[2][2];
    #pragma unroll
    for (int t = 0; t < 2; ++t) {
        int qrow = qt + w*32 + t*16 + lr; if (qrow >= NQ) qrow = NQ - 1;
        const unsigned short* qsrc = qbase + (size_t)qrow*64 + lh*8;
        aq[t][0] = __builtin_bit_cast(bf16x8_t, *(const int4*)qsrc);
        aq[t][1] = __builtin_bit_cast(bf16x8_t, *(const int4*)(qsrc + 32));
    }
    int4 onesi = make_int4(0x3F803F80, 0x3F803F80, 0x3F803F80, 0x3F803F80);
    bf16x8_t bones = __builtin_bit_cast(bf16x8_t, onesi);
    f32x4_t O[2][4];
    f32x4_t Lacc[2];
    #pragma unroll
    for (int t = 0; t < 2; ++t) {
        Lacc[t][0]=0.f; Lacc[t][1]=0.f; Lacc[t][2]=0.f; Lacc[t][3]=0.f;
        #pragma unroll
        for (int g = 0; g < 4; ++g) { O[t][g][0]=0.f; O[t][g][1]=0.f; O[t][g][2]=0.f; O[t][g][3]=0.f; }
    }
    for (int rgi = 0; rgi < 2; ++rgi) {
        int rs = rgi ? r1s : r0s, re = rgi ? r1e : r0e;
        for (int j0 = rs; j0 < re; j0 += 64) {
            int cnt = min(64, re - j0);
            __syncthreads();
            {
                int kr0 = j0 + srow0; if (kr0 > re - 1) kr0 = re - 1;
                int kr1 = j0 + srow1; if (kr1 > re - 1) kr1 = re - 1;
                stage16(kbase + (size_t)kr0*64 + sc0, &kt[ldst0]);
                stage16(kbase + (size_t)kr1*64 + sc0, &kt[ldst1]);
                stage16(vbase + (size_t)srow0*VPAD_ + j0 + sc0, &vt[ldst0]);
                stage16(vbase + (size_t)srow1*VPAD_ + j0 + sc0, &vt[ldst1]);
            }
            __syncthreads();
            f32x4_t S[2][4];
            #pragma unroll
            for (int g = 0; g < 4; ++g) {
                const unsigned short* kr = &kt[(16*g + lr)*64];
                bf16x8_t b0 = __builtin_bit_cast(bf16x8_t, *(const int4*)(kr + ((lh ^ s7) << 3)));
                bf16x8_t b1 = __builtin_bit_cast(bf16x8_t, *(const int4*)(kr + (((lh + 4) ^ s7) << 3)));
                #pragma unroll
                for (int t = 0; t < 2; ++t) {
                    f32x4_t zz; zz[0]=0.f; zz[1]=0.f; zz[2]=0.f; zz[3]=0.f;
                    zz = __builtin_amdgcn_mfma_f32_16x16x32_bf16(aq[t][0], b0, zz, 0, 0, 0);
                    zz = __builtin_amdgcn_mfma_f32_16x16x32_bf16(aq[t][1], b1, zz, 0, 0, 0);
                    S[t][g] = zz;
                }
            }
            if (cnt == 64) {
                #pragma unroll
                for (int t = 0; t < 2; ++t)
                    #pragma unroll
                    for (int g = 0; g < 4; ++g)
                        #pragma unroll
                        for (int r = 0; r < 4; ++r) {
                            float p = __expf(S[t][g][r] * 0.125f);
                            pw[(t*16 + lh*4 + r)*PS_ + 16*g + lr] = __builtin_bit_cast(unsigned short, (__bf16)p);
                        }
            } else {
                #pragma unroll
                for (int t = 0; t < 2; ++t)
                    #pragma unroll
                    for (int g = 0; g < 4; ++g) {
                        bool vld = (16*g + lr) < cnt;
                        #pragma unroll
                        for (int r = 0; r < 4; ++r) {
                            float p = vld ? __expf(S[t][g][r] * 0.125f) : 0.f;
                            pw[(t*16 + lh*4 + r)*PS_ + 16*g + lr] = __builtin_bit_cast(unsigned short, (__bf16)p);
                        }
                    }
            }
            #pragma unroll
            for (int c = 0; c < 2; ++c) {
                bf16x8_t ap[2];
                #pragma unroll
                for (int t = 0; t < 2; ++t) {
                    ap[t] = __builtin_bit_cast(bf16x8_t,
                        *(const int4*)&pw[(t*16 + lr)*PS_ + c*32 + lh*8]);
                    Lacc[t] = __builtin_amdgcn_mfma_f32_16x16x32_bf16(ap[t], bones, Lacc[t], 0, 0, 0);
                }
                #pragma unroll
                for (int g = 0; g < 4; ++g) {
                    const unsigned short* vr = &vt[(16*g + lr)*64];
                    bf16x8_t bv = __builtin_bit_cast(bf16x8_t,
                        *(const int4*)(vr + (((c*4 + lh) ^ s7) << 3)));
                    #pragma unroll
                    for (int t = 0; t < 2; ++t)
                        O[t][g] = __builtin_amdgcn_mfma_f32_16x16x32_bf16(ap[t], bv, O[t][g], 0, 0, 0);
                }
            }
        }
    }
    #pragma unroll
    for (int t = 0; t < 2; ++t)
        #pragma unroll
        for (int r = 0; r < 4; ++r) {
            int gq = qt + w*32 + t*16 + lh*4 + r;
            if (gq < NQ) {
                long rrow = (long)(b*HEADS_ + h)*S2_ + q_off + gq;
                float* o = po + rrow*64 + lr;
                #pragma unroll
                for (int g = 0; g < 4; ++g) o[16*g] = O[t][g][r];
                if (lr == 0) pl[(long)z*(B_*HEADS_*S2_) + rrow] = Lacc[t][r];
            }
        }
}

// combine split-S partials (float4): ao/ac = (p0+p1)/(l0+l1); also emit merged
// bf16 row layout (fuses the old k_merge): xo[(b*S2+s)*1024 + h*64+d]
__global__ __launch_bounds__(256) void k_fcomb(
    const float* __restrict__ p0, const float* __restrict__ p1,
    const float* __restrict__ pl,
    float* __restrict__ ao, float* __restrict__ ac, unsigned short* __restrict__ xo)
{
    long i = ((long)blockIdx.x*256 + threadIdx.x) * 4;   // < 2*16*1770*64
    int d = (int)(i & 63);
    long rrow = i >> 6;                                   // (b*16+h)*S2 + s
    int s = (int)(rrow % S2_);
    int bh = (int)(rrow / S2_);
    int b = bh >> 4, h = bh & 15;
    float l = pl[rrow] + pl[rrow + (long)B_*HEADS_*S2_];
    float4 a = *(const float4*)(p0 + i);
    float4 c = *(const float4*)(p1 + i);
    float4 v = make_float4((a.x+c.x)/l, (a.y+c.y)/l, (a.z+c.z)/l, (a.w+c.w)/l);
    if (s < S_MAIN) *(float4*)(ao + ((long)bh*S_MAIN + s)*64 + d) = v;
    else            *(float4*)(ac + ((long)bh*NC_ + (s - S_MAIN))*64 + d) = v;
    uint2 pk; pk.x = pack2bf(v.x, v.y); pk.y = pack2bf(v.z, v.w);
    *(uint2*)(xo + ((long)b*S2_ + s)*DIM_ + h*64 + d) = pk;
}

__global__ __launch_bounds__(256) void k_head_score(const float* __restrict__ ao, float* __restrict__ score)
{
    int h = blockIdx.x, tid = threadIdx.x;
    const float* base = ao + (((long)HEADS_ + h)*S_MAIN + TEXT_)*64;
    float sA = 0.f, sB = 0.f;
    for (int p = tid; p < IMG_; p += 256) {
        const float* r = base + (long)p*64;
        float mm = 0.f;
        for (int d = 0; d < 64; d += 4) {
            float4 v = *(const float4*)(r + d);
            mm += v.x + v.y + v.z + v.w;
        }
        mm *= (1.f / 64.f);
        sA += mm; sB += mm*mm;
    }
    __shared__ float r1[256], r2[256];
    r1[tid] = sA; r2[tid] = sB; __syncthreads();
    for (int st = 128; st; st >>= 1) {
        if (tid < st) { r1[tid] += r1[tid+st]; r2[tid] += r2[tid+st]; }
        __syncthreads();
    }
    if (tid == 0) {
        float mean = r1[0] / IMG_, ms = r2[0] / IMG_;
        score[h] = sqrtf(fmaxf(ms - mean*mean, 0.f));
    }
}

__global__ void k_top4(const float* __restrict__ score, int* __restrict__ sel)
{
    if (threadIdx.x == 0 && blockIdx.x == 0) {
        int used = 0;
        for (int k = 0; k < 4; ++k) {
            float best = -INFINITY; int bi = 0;
            for (int h2 = 0; h2 < 16; ++h2) {
                if (used & (1 << h2)) continue;
                if (score[h2] > best) { best = score[h2]; bi = h2; }
            }
            used |= 1 << bi; sel[k] = bi;
        }
    }
}

__global__ __launch_bounds__(512) void k_sim(
    const float* __restrict__ qh, const float* __restrict__ kh,
    float* __restrict__ sim, int* __restrict__ selvis)
{
    int blk = blockIdx.x;    // (h*8+t)*4+f
    int h = blk >> 5, t = (blk >> 2) & 7, f = blk & 3;
    int tid = threadIdx.x;
    __shared__ float ckv[64];
    if (tid < 64) ckv[tid] = kh[(((long)HEADS_ + h)*S2_ + S_MAIN + t)*64 + tid];
    __syncthreads();
    float val = -INFINITY; int idx = 0x7fffffff;
    if (tid < PATCHES_) {
        const float* qrow = qh + (((long)HEADS_ + h)*S2_ + TEXT_ + f*PATCHES_ + tid)*64;
        float acc = 0.f;
        for (int d = 0; d < 64; d += 4) {
            float4 qv = *(const float4*)(qrow + d);
            acc += qv.x*ckv[d] + qv.y*ckv[d+1] + qv.z*ckv[d+2] + qv.w*ckv[d+3];
        }
        sim[((long)h*NC_ + t)*IMG_ + f*PATCHES_ + tid] = acc;
        val = acc; idx = tid;
    }
    __shared__ float sv[512]; __shared__ int si[512];
    sv[tid] = val; si[tid] = idx; __syncthreads();
    for (int st = 256; st; st >>= 1) {
        if (tid < st) {
            float v2 = sv[tid+st]; int i2 = si[tid+st];
            if (v2 > sv[tid] || (v2 == sv[tid] && i2 < si[tid])) { sv[tid] = v2; si[tid] = i2; }
        }
        __syncthreads();
    }
    if (tid == 0) selvis[blk] = si[0];
}

__global__ __launch_bounds__(256) void k_cross(const float* __restrict__ sim, float* __restrict__ out)
{
    int i = (blockIdx.x*256 + threadIdx.x) * 4;   // < 12288
    int c = i / IMG_, p = i % IMG_;
    float4 acc = make_float4(0.f, 0.f, 0.f, 0.f);
    for (int h = 0; h < 16; ++h) {
        float4 v = *(const float4*)(sim + ((long)h*NC_ + c)*IMG_ + p);
        acc.x += v.x; acc.y += v.y; acc.z += v.z; acc.w += v.w;
    }
    *(float4*)(out + O_XMAP + i) = make_float4(acc.x*(1.f/16.f), acc.y*(1.f/16.f),
                                               acc.z*(1.f/16.f), acc.w*(1.f/16.f));
}

__global__ __launch_bounds__(256) void k_concept_maps(
    const float* __restrict__ ac, const float* __restrict__ ao, float* __restrict__ out)
{
    int i = blockIdx.x*256 + threadIdx.x;   // < 12288
    int c = i / IMG_, p = i % IMG_;
    float acc = 0.f;
    for (int h = 0; h < 16; ++h) {
        const float* a = ac + (((long)HEADS_ + h)*NC_ + c)*64;
        const float* g = ao + (((long)HEADS_ + h)*S_MAIN + TEXT_ + p)*64;
        for (int d = 0; d < 64; d += 4) {
            float4 av = *(const float4*)(a + d);
            float4 gv = *(const float4*)(g + d);
            acc += av.x*gv.x + av.y*gv.y + av.z*gv.z + av.w*gv.w;
        }
    }
    out[O_CMAP + i] = acc;
}

__global__ void k_imap_raw(const float* __restrict__ ao, const int* __restrict__ selvis,
                           float* __restrict__ imap)
{
    int blk = blockIdx.x;   // (h*8+t)*4+f
    int h = blk >> 5, t = (blk >> 2) & 7, f = blk & 3;
    int tid = threadIdx.x;  // 384
    __shared__ float sel[64];
    int pstar = selvis[blk];
    if (tid < 64) sel[tid] = ao[(((long)HEADS_ + h)*S_MAIN + TEXT_ + f*PATCHES_ + pstar)*64 + tid];
    __syncthreads();
    const float* g = ao + (((long)HEADS_ + h)*S_MAIN + TEXT_ + f*PATCHES_ + tid)*64;
    float acc = 0.f;
    for (int d = 0; d < 64; d += 4) {
        float4 gv = *(const float4*)(g + d);
        acc += gv.x*sel[d] + gv.y*sel[d+1] + gv.z*sel[d+2] + gv.w*sel[d+3];
    }
    imap[((long)h*NC_ + t)*IMG_ + f*PATCHES_ + tid] = acc;
}

__global__ __launch_bounds__(256) void k_imap_norm(float* __restrict__ imap)
{
    int i = (blockIdx.x*256 + threadIdx.x) * 4;   // < 24576
    int h = i / IMG_, fp = i % IMG_;
    float4 v[8]; float4 mu = make_float4(0.f, 0.f, 0.f, 0.f);
    #pragma unroll
    for (int t = 0; t < 8; ++t) {
        v[t] = *(const float4*)(imap + ((long)h*NC_ + t)*IMG_ + fp);
        mu.x += v[t].x; mu.y += v[t].y; mu.z += v[t].z; mu.w += v[t].w;
    }
    mu.x *= 0.125f; mu.y *= 0.125f; mu.z *= 0.125f; mu.w *= 0.125f;
    float4 var = make_float4(0.f, 0.f, 0.f, 0.f);
    #pragma unroll
    for (int t = 0; t < 8; ++t) {
        var.x += (v[t].x-mu.x)*(v[t].x-mu.x); var.y += (v[t].y-mu.y)*(v[t].y-mu.y);
        var.z += (v[t].z-mu.z)*(v[t].z-mu.z); var.w += (v[t].w-mu.w)*(v[t].w-mu.w);
    }
    float4 inv;
    inv.x = 1.f / (sqrtf(var.x * (1.f/7.f)) + 1e-6f);
    inv.y = 1.f / (sqrtf(var.y * (1.f/7.f)) + 1e-6f);
    inv.z = 1.f / (sqrtf(var.z * (1.f/7.f)) + 1e-6f);
    inv.w = 1.f / (sqrtf(var.w * (1.f/7.f)) + 1e-6f);
    #pragma unroll
    for (int t = 0; t < 8; ++t) {
        *(float4*)(imap + ((long)h*NC_ + t)*IMG_ + fp) =
            make_float4((v[t].x-mu.x)*inv.x, (v[t].y-mu.y)*inv.y,
                        (v[t].z-mu.z)*inv.z, (v[t].w-mu.w)*inv.w);
    }
}

__global__ __launch_bounds__(256) void k_imap_reduce(
    const float* __restrict__ imap, const int* __restrict__ sel, float* __restrict__ out)
{
    int i = (blockIdx.x*256 + threadIdx.x) * 4;   // < 12288
    int t = i / IMG_, fp = i % IMG_;
    float4 sum = make_float4(0.f, 0.f, 0.f, 0.f);
    for (int h = 0; h < 16; ++h) {
        float4 v = *(const float4*)(imap + ((long)h*NC_ + t)*IMG_ + fp);
        sum.x += v.x; sum.y += v.y; sum.z += v.z; sum.w += v.w;
    }
    float4 ss = make_float4(0.f, 0.f, 0.f, 0.f);
    for (int k = 0; k < 4; ++k) {
        int h = sel[k];
        float4 v = *(const float4*)(imap + ((long)h*NC_ + t)*IMG_ + fp);
        ss.x += v.x; ss.y += v.y; ss.z += v.z; ss.w += v.w;
    }
    *(float4*)(out + O_ISUM + i) = sum;
    *(float4*)(out + O_SELI + i) = make_float4(ss.x*0.25f, ss.y*0.25f, ss.z*0.25f, ss.w*0.25f);
}

// residual with fused split-K reduce (float4): X = orig + gate * (p0 + p1 + bo)
__global__ __launch_bounds__(256) void k_residual1(
    const float* __restrict__ pe, const float* __restrict__ ph, const float* __restrict__ pc,
    const float* __restrict__ p0, const float* __restrict__ p1, const float* __restrict__ bo,
    const float* __restrict__ s1, float* __restrict__ X)
{
    long i = ((long)blockIdx.x*256 + threadIdx.x) * 4;
    int col = (int)(i & 1023);
    long row = i >> 10;
    int b = (int)(row / S2_), s = (int)(row % S2_);
    const float* sb = s1 + (long)b * 6144;
    float4 orig, gate;
    if (s < TEXT_) {
        orig = *(const float4*)(pe + ((long)b*TEXT_ + s)*DIM_ + col);
        gate = *(const float4*)(sb + 5120 + col);
    } else if (s < S_MAIN) {
        orig = *(const float4*)(ph + ((long)b*IMG_ + (s-TEXT_))*DIM_ + col);
        gate = *(const float4*)(sb + 2048 + col);
    } else {
        orig = *(const float4*)(pc + ((long)b*NC_ + (s-S_MAIN))*DIM_ + col);
        gate = *(const float4*)(sb + 5120 + col);
    }
    float4 a = *(const float4*)(p0 + i);
    float4 c = *(const float4*)(p1 + i);
    float4 bb = *(const float4*)(bo + col);
    *(float4*)(X + i) = make_float4(
        orig.x + gate.x*(a.x + c.x + bb.x), orig.y + gate.y*(a.y + c.y + bb.y),
        orig.z + gate.z*(a.z + c.z + bb.z), orig.w + gate.w*(a.w + c.w + bb.w));
}

// final with fused split-K reduce (float4): out = X + gate * (f0 + f1 + fb2)
__global__ __launch_bounds__(256) void k_final(
    const float* __restrict__ X, const float* __restrict__ f0, const float* __restrict__ f1,
    const float* __restrict__ fb2, const float* __restrict__ s2, float* __restrict__ out)
{
    long i = ((long)blockIdx.x*256 + threadIdx.x) * 4;
    int col = (int)(i & 1023);
    long row = i >> 10;
    int b = (int)(row / S2_), s = (int)(row % S2_);
    const float* sb = s2 + (long)b * 6144;
    float4 gate; float* o;
    if (s < TEXT_) {
        gate = *(const float4*)(sb + 5120 + col);
        o = out + O_E + ((long)b*TEXT_ + s)*DIM_ + col;
    } else if (s < S_MAIN) {
        gate = *(const float4*)(sb + 2048 + col);
        o = out + O_H + ((long)b*IMG_ + (s-TEXT_))*DIM_ + col;
    } else {
        gate = *(const float4*)(sb + 5120 + col);
        o = out + O_C + ((long)b*NC_ + (s-S_MAIN))*DIM_ + col;
    }
    float4 x = *(const float4*)(X + i);
    float4 a = *(const float4*)(f0 + i);
    float4 c = *(const float4*)(f1 + i);
    float4 bb = *(const float4*)(fb2 + col);
    *(float4*)o = make_float4(
        x.x + gate.x*(a.x + c.x + bb.x), x.y + gate.y*(a.y + c.y + bb.y),
        x.z + gate.z*(a.z + c.z + bb.z), x.w + gate.w*(a.w + c.w + bb.w));
}

extern "C" void kernel_launch(void* const* d_in, const int* in_sizes, int n_in,
                              void* d_out, int out_size, void* d_ws, size_t ws_size,
                              hipStream_t stream)
{
    (void)in_sizes; (void)n_in; (void)out_size; (void)ws_size;
    const float* h_in = (const float*)d_in[0];
    const float* e_in = (const float*)d_in[1];
    const float* c_in = (const float*)d_in[2];
    const float* temb = (const float*)d_in[3];
    const float* rcos = (const float*)d_in[4];
    const float* rsin = (const float*)d_in[5];
    const float* n1w  = (const float*)d_in[6];
    const float* n1b  = (const float*)d_in[7];
    const float* ln1w = (const float*)d_in[8];
    const float* ln1b = (const float*)d_in[9];
    const float* n2w  = (const float*)d_in[10];
    const float* n2b  = (const float*)d_in[11];
    const float* ln2w = (const float*)d_in[12];
    const float* ln2b = (const float*)d_in[13];
    const float* wq   = (const float*)d_in[14];
    const float* wk   = (const float*)d_in[15];
    const float* wv   = (const float*)d_in[16];
    const float* nqw  = (const float*)d_in[17];
    const float* nqb  = (const float*)d_in[18];
    const float* nkw  = (const float*)d_in[19];
    const float* nkb  = (const float*)d_in[20];
    const float* wo   = (const float*)d_in[21];
    const float* bo   = (const float*)d_in[22];
    const float* fw1  = (const float*)d_in[23];
    const float* fb1  = (const float*)d_in[24];
    const float* fw2  = (const float*)d_in[25];
    const float* fb2  = (const float*)d_in[26];

    float* ws  = (float*)d_ws;
    float* out = (float*)d_out;
    float* s1   = ws + OFF_S1;
    float* s2   = ws + OFF_S2;
    float* score  = ws + OFF_MISC;
    int*   selh   = (int*)(ws + OFF_MISC + 16);
    int*   selvis = (int*)(ws + OFF_MISC + 32);
    float* sim  = ws + OFF_SIM;
    float* imap = ws + OFF_IMAP;
    float* ac   = ws + OFF_AC;
    float* X    = ws + OFF_X;
    float* proj = ws + OFF_PROJ;
    float* xn   = ws + OFF_XN;
    float* qh   = ws + OFF_Q;
    float* kh   = ws + OFF_K;
    float* vh   = ws + OFF_V;
    float* ao   = ws + OFF_AO;
    float* ffo  = proj;
    float* fixp = ws + OFF_AO;             // fixup split-K partials (2 x 1536x1024)
    float* sp   = ws + OFF_X;              // silu partials (4 x 24576) [step1 -> step1b]
    unsigned short* xnb   = (unsigned short*)(ws + OFF_XNB);
    unsigned short* wqkvT = (unsigned short*)(ws + OFF_PROJ);
    unsigned short* vb    = (unsigned short*)(ws + OFF_PROJ);
    unsigned short* qbb   = (unsigned short*)(ws + OFF_X);
    unsigned short* kbb   = qbb + (size_t)B_*HEADS_*S2_*64;
    unsigned short* woT   = (unsigned short*)(ws + OFF_AO + 2000000);
    unsigned short* fw1T  = (unsigned short*)(ws + OFF_V);
    unsigned short* fw2T  = (unsigned short*)(ws + OFF_AO);
    unsigned short* ffh   = (unsigned short*)(ws + OFF_Q);
    // flash split-S partial overlays (dead regions during step 8):
    float* fp0 = vh;    // OFF_V: vh dead after k_vtrans; fw1T arrives step 13
    float* fp1 = xn;    // OFF_XN: xn dead after step 6; proj z1 arrives step 11
    float* fpl = sim;   // OFF_SIM: sim written at step 9 k_sim (after combine)

    // 1. adaLN modulation vectors (split-K x4 partials + reduce)
    hipLaunchKernelGGL(k_silu_mod, dim3(24, 2, 4), dim3(256), 0, stream, temb, n1w, n2w, sp);
    hipLaunchKernelGGL(k_silu_red, dim3(96), dim3(256), 0, stream, sp, n1b, n2b, s1, s2);
    // 2. QKV weight transposes (batched z=3)
    hipLaunchKernelGGL(k_tcvt_qkv, dim3(32, 32, 3), dim3(256), 0, stream, wq, wk, wv, wqkvT);
    // 3. norm1 + modulation -> xn fp32 + xnb bf16
    hipLaunchKernelGGL(k_ln_mod, dim3(ROWS_), dim3(256), 0, stream,
        e_in, (long)TEXT_*DIM_, h_in, (long)IMG_*DIM_, c_in, (long)NC_*DIM_, s1, ln1w, ln1b, xn, xnb);
    // 4. fused QKV bf16 GEMM, headed fp32 scatter
    hipLaunchKernelGGL(k_bgemm, dim3(24, 28, 1), dim3(256), 0, stream,
        xnb, wqkvT, (const float*)nullptr, (float*)nullptr, (unsigned short*)nullptr,
        ROWS_, 3072, 1024, 1024, 0, qh, kh, vh);
    // 5. fp32 q-fixup split-K x2 -> partials, then reduce into headed qh
    hipLaunchKernelGGL(k_gemm, dim3(16, 24, 2), dim3(256), 0, stream,
        xn + (long)(S2_ + TEXT_)*DIM_, wq, (float*)nullptr, IMG_, DIM_, DIM_, 512, 0, 0, fixp);
    hipLaunchKernelGGL(k_fixred, dim3(1536), dim3(256), 0, stream, fixp, qh);
    // 6. fp32 k-fixup (8 concept rows, batch 1) headed
    hipLaunchKernelGGL(k_gemm, dim3(16, 1, 1), dim3(256), 0, stream,
        xn + (long)(S2_ + S_MAIN)*DIM_, wk, kh, NC_, DIM_, DIM_, 1024, 1, S2_ + S_MAIN, (float*)nullptr);
    // 7. QK layernorm + RoPE (float4, 4 rows/wave); V transpose to bf16
    hipLaunchKernelGGL(k_qk_prep, dim3(3540, 2), dim3(256), 0, stream,
        qh, kh, qbb, kbb, nqw, nqb, nkw, nkb, rcos, rsin);
    hipLaunchKernelGGL(k_vtrans, dim3(56, 2, 32), dim3(256), 0, stream, vh, vb);
    // 8. attention: split-S x2, XCD-chunked (bx<28: main u=bx>>1/z=bx&1; bx 28,29: concept z)
    hipLaunchKernelGGL(k_flash, dim3(30, 16, 2), dim3(256), 0, stream,
        qbb, kbb, vb, fp0, fp1, fpl);
    // 8b. combine partials -> ao/ac + merged bf16 (fused old k_merge), float4
    hipLaunchKernelGGL(k_fcomb, dim3(3540), dim3(256), 0, stream, fp0, fp1, fpl, ao, ac, xnb);
    // 9. maps (batch 1)
    hipLaunchKernelGGL(k_head_score, dim3(16), dim3(256), 0, stream, ao, score);
    hipLaunchKernelGGL(k_top4, dim3(1), dim3(64), 0, stream, score, selh);
    hipLaunchKernelGGL(k_sim, dim3(512), dim3(512), 0, stream, qh, kh, sim, selvis);
    hipLaunchKernelGGL(k_cross, dim3(12), dim3(256), 0, stream, sim, out);
    hipLaunchKernelGGL(k_concept_maps, dim3(48), dim3(256), 0, stream, ac, ao, out);
    hipLaunchKernelGGL(k_imap_raw, dim3(512), dim3(384), 0, stream, ao, selvis, imap);
    hipLaunchKernelGGL(k_imap_norm, dim3(24), dim3(256), 0, stream, imap);
    hipLaunchKernelGGL(k_imap_reduce, dim3(12), dim3(256), 0, stream, imap, selh, out);
    // 10. wo transpose into dead ao region (merge now fused into fcomb)
    hipLaunchKernelGGL(k_tcvt, dim3(32, 32), dim3(256), 0, stream, wo, woT, 1024, 1024);
    // 11. wo GEMM split-K x2 (partials at PROJ / XN)
    hipLaunchKernelGGL(k_bgemm, dim3(8, 28, 2), dim3(256), 0, stream,
        xnb, woT, (const float*)nullptr, proj, (unsigned short*)nullptr, ROWS_, DIM_, 1024, 512, 1,
        (float*)nullptr, (float*)nullptr, (float*)nullptr);
    // 12. residual1 (fused reduce + bias, float4) -> X
    hipLaunchKernelGGL(k_residual1, dim3(3540), dim3(256), 0, stream,
        e_in, h_in, c_in, proj, proj + (size_t)ROWS_*DIM_, bo, s1, X);
    // 13. FF weight transposes
    hipLaunchKernelGGL(k_tcvt, dim3(128, 32), dim3(256), 0, stream, fw1, fw1T, 1024, 4096);
    hipLaunchKernelGGL(k_tcvt, dim3(32, 128), dim3(256), 0, stream, fw2, fw2T, 4096, 1024);
    // 14. norm2 -> xnb bf16 only
    hipLaunchKernelGGL(k_ln_mod, dim3(ROWS_), dim3(256), 0, stream,
        X, (long)S2_*DIM_, X + (long)TEXT_*DIM_, (long)S2_*DIM_, X + (long)S_MAIN*DIM_, (long)S2_*DIM_,
        s2, ln2w, ln2b, (float*)nullptr, xnb);
    // 15. ff1 (gelu fused, bf16 out)
    hipLaunchKernelGGL(k_bgemm, dim3(32, 28, 1), dim3(256), 0, stream,
        xnb, fw1T, fb1, (float*)nullptr, ffh, ROWS_, FF_, 1024, 1024, 2,
        (float*)nullptr, (float*)nullptr, (float*)nullptr);
    // 16. ff2 split-K x2 (partials at PROJ / XN)
    hipLaunchKernelGGL(k_bgemm, dim3(8, 28, 2), dim3(256), 0, stream,
        ffh, fw2T, (const float*)nullptr, ffo, (unsigned short*)nullptr, ROWS_, DIM_, FF_, 2048, 1,
        (float*)nullptr, (float*)nullptr, (float*)nullptr);
    // 17. final (fused reduce + bias, float4) -> outputs
    hipLaunchKernelGGL(k_final, dim3(3540), dim3(256), 0, stream,
        X, ffo, ffo + (size_t)ROWS_*DIM_, fb2, s2, out);
}